// Round 17
// baseline (385.944 us; speedup 1.0000x reference)
//
#include <hip/hip_runtime.h>
#include <hip/hip_bf16.h>
#include <stdint.h>

#define N_NODES 50000
#define N_EDGES 800000
#define K_KEEP  40000
#define BKT     196        // ceil(N_NODES/256) dst-range buckets
#define BCAP    6144       // per-bucket capacity (mean 4081, +32 sigma)

typedef unsigned long long u64;
typedef unsigned int u32;
typedef unsigned short u16;
typedef __hip_bfloat16 bf16;
typedef __hip_bfloat162 bf16x2;
typedef __attribute__((ext_vector_type(8))) short short8;
typedef __attribute__((ext_vector_type(8))) unsigned short ushort8;
typedef __attribute__((ext_vector_type(4))) float f32x4;

struct Ctl {
  u64 prefix;
  u32 kremain;
  u32 cnt;
  float inv_norm;
  u32 isfp32;
  u32 done;         // radix pass arrival counter (reset by picker each pass)
  u32 pad;          // csr2 edge cursor
  u32 gen;          // 0 = unresolved; else (resolution pass + 1); pass==gen does marking
  u32 done2;        // (unused; layout keep)
  u32 hist[256];    // radix histogram (LDS-aggregated flushes only)
};

__device__ __forceinline__ float bf2f(bf16 v) { return __bfloat162float(v); }
__device__ __forceinline__ float bfbits2f(unsigned short u) {
  return __uint_as_float(((u32)u) << 16);
}
__device__ __forceinline__ float loadF(const void* p, size_t i, bool f32) {
  return f32 ? ((const float*)p)[i] : bf2f(((const bf16*)p)[i]);
}
__device__ __forceinline__ short f2bf_bits(float f) {
  bf16 t = __float2bfloat16(f);
  return *(const short*)&t;
}

// Prescaled gather (R9) with ILP-8 (R11), 8-lanes/node layout (used inside fused GEMMs)
__device__ __forceinline__ void gather_row8_pre(const ushort8* __restrict__ H, int d, int lane,
                                                const int* __restrict__ rowstart,
                                                const int* __restrict__ len,
                                                const int* __restrict__ csr,
                                                float* acc)
{
  ushort8 v = H[(size_t)d * 8 + lane];
  #pragma unroll
  for (int c = 0; c < 8; ++c) acc[c] = bfbits2f(v[c]);
  int i = rowstart[d];
  int i1 = len ? (i + len[d]) : rowstart[d + 1];
  for (; i + 8 <= i1; i += 8) {
    int s0 = csr[i],     s1 = csr[i + 1], s2 = csr[i + 2], s3 = csr[i + 3];
    int s4 = csr[i + 4], s5 = csr[i + 5], s6 = csr[i + 6], s7 = csr[i + 7];
    ushort8 v0 = H[(size_t)s0 * 8 + lane];
    ushort8 v1 = H[(size_t)s1 * 8 + lane];
    ushort8 v2 = H[(size_t)s2 * 8 + lane];
    ushort8 v3 = H[(size_t)s3 * 8 + lane];
    ushort8 v4 = H[(size_t)s4 * 8 + lane];
    ushort8 v5 = H[(size_t)s5 * 8 + lane];
    ushort8 v6 = H[(size_t)s6 * 8 + lane];
    ushort8 v7 = H[(size_t)s7 * 8 + lane];
    #pragma unroll
    for (int c = 0; c < 8; ++c) {
      acc[c] += (bfbits2f(v0[c]) + bfbits2f(v1[c]))
              + (bfbits2f(v2[c]) + bfbits2f(v3[c]));
      acc[c] += (bfbits2f(v4[c]) + bfbits2f(v5[c]))
              + (bfbits2f(v6[c]) + bfbits2f(v7[c]));
    }
  }
  for (; i + 4 <= i1; i += 4) {
    int s0 = csr[i], s1 = csr[i + 1], s2 = csr[i + 2], s3 = csr[i + 3];
    ushort8 v0 = H[(size_t)s0 * 8 + lane];
    ushort8 v1 = H[(size_t)s1 * 8 + lane];
    ushort8 v2 = H[(size_t)s2 * 8 + lane];
    ushort8 v3 = H[(size_t)s3 * 8 + lane];
    #pragma unroll
    for (int c = 0; c < 8; ++c) {
      acc[c] += (bfbits2f(v0[c]) + bfbits2f(v1[c]))
              + (bfbits2f(v2[c]) + bfbits2f(v3[c]));
    }
  }
  for (; i < i1; ++i) {
    int s = csr[i];
    ushort8 vv = H[(size_t)s * 8 + lane];
    #pragma unroll
    for (int c = 0; c < 8; ++c) acc[c] += bfbits2f(vv[c]);
  }
}

// R12 wave-per-node gather core with optional reverse-weight scatter (R16):
// slot = lane>>3 walks edges stride-8; unit = lane&7 reads contiguous 128B rows.
// cvec!=null: unit==0 lane fires atomicAdd(&cvec[s], dd) per edge (hidden under load latency).
__device__ __forceinline__ void gather_wave_partial(const ushort8* __restrict__ H, int d,
                                                    int slot, int unit,
                                                    const int* __restrict__ rowstart,
                                                    const int* __restrict__ len,
                                                    const int* __restrict__ csr,
                                                    float* acc,
                                                    float* __restrict__ cvec, float dd)
{
  #pragma unroll
  for (int c = 0; c < 8; ++c) acc[c] = 0.f;
  if (slot == 0) {
    ushort8 v = H[(size_t)d * 8 + unit];
    #pragma unroll
    for (int c = 0; c < 8; ++c) acc[c] = bfbits2f(v[c]);
  }
  int i0 = rowstart[d];
  int i1 = i0 + len[d];
  int i = i0 + slot;
  for (; i + 8 < i1; i += 16) {
    int sa = csr[i], sb = csr[i + 8];
    if (cvec && unit == 0) {
      atomicAdd(&cvec[sa], dd);
      atomicAdd(&cvec[sb], dd);
    }
    ushort8 va = H[(size_t)sa * 8 + unit];
    ushort8 vb = H[(size_t)sb * 8 + unit];
    #pragma unroll
    for (int c = 0; c < 8; ++c) acc[c] += bfbits2f(va[c]) + bfbits2f(vb[c]);
  }
  if (i < i1) {
    int s = csr[i];
    if (cvec && unit == 0) atomicAdd(&cvec[s], dd);
    ushort8 vv = H[(size_t)s * 8 + unit];
    #pragma unroll
    for (int c = 0; c < 8; ++c) acc[c] += bfbits2f(vv[c]);
  }
}

// ---------------- init (+parallel dtype detect, proven R5-R8) ----------------

__global__ void init_kernel(const unsigned short* __restrict__ x16,
                            int* __restrict__ bucket_cur, int* __restrict__ detcnt,
                            Ctl* ctl, float* __restrict__ cvec) {
  __shared__ u32 dsh[256];
  int i = blockIdx.x * 256 + threadIdx.x;
  if (i < BKT) bucket_cur[i] = i * BCAP;
  if (i < K_KEEP) cvec[i] = 0.f;
  if (blockIdx.x == 0) {
    ctl->hist[threadIdx.x] = 0u;
    if (threadIdx.x == 0) {
      ctl->prefix = 0ull; ctl->kremain = K_KEEP; ctl->cnt = 0u;
      ctl->done = 0u; ctl->pad = 0u; ctl->gen = 0u; ctl->done2 = 0u;
    }
  }
  if (blockIdx.x < 64) {
    int base = blockIdx.x * 2048;
    u32 c = 0;
    for (int j = threadIdx.x; j < 2048; j += 256) {
      u32 h = x16[base + j];
      if ((h & 0x7F80u) == 0x7F80u) c++;
    }
    dsh[threadIdx.x] = c;
    __syncthreads();
    for (int s = 128; s > 0; s >>= 1) {
      if (threadIdx.x < s) dsh[threadIdx.x] += dsh[threadIdx.x + s];
      __syncthreads();
    }
    if (threadIdx.x == 0) detcnt[blockIdx.x] = (int)dsh[0];
  }
}

// ------- CSR1 bucket scatter (int4 edge loads, R13) + fused dtype/norm -------

__global__ void bucket_scatter_kernel(const int* __restrict__ src, const int* __restrict__ dst,
                                      int* __restrict__ bucket_cur, u32* __restrict__ bucketbuf,
                                      const int* __restrict__ detcnt, const void* __restrict__ pw,
                                      Ctl* ctl)
{
  __shared__ u32 hist[BKT];
  __shared__ u32 base[BKT];
  __shared__ int f32sh;
  __shared__ float ns[128];
  const int tid = threadIdx.x;
  const int e0 = blockIdx.x * 2048;

  // dtype detect from detcnt (written by init, prior dispatch)
  if (tid < 64) {
    int dc = detcnt[tid];
    for (int off = 32; off; off >>= 1) dc += __shfl_down(dc, off);
    if (tid == 0) f32sh = (dc >= 16) ? 1 : 0;
  }
  for (int t = tid; t < BKT; t += 256) hist[t] = 0;
  __syncthreads();
  const bool f32in = f32sh != 0;

  // 8 contiguous edges/thread via int4 loads (fast path when block fully in range)
  int dreg[8], sreg[8];
  const int eb = e0 + tid * 8;
  if (e0 + 2048 <= N_EDGES) {
    const int4* d4 = (const int4*)(dst + eb);
    const int4* s4 = (const int4*)(src + eb);
    int4 da = d4[0], db = d4[1];
    int4 sa = s4[0], sb = s4[1];
    dreg[0] = da.x; dreg[1] = da.y; dreg[2] = da.z; dreg[3] = da.w;
    dreg[4] = db.x; dreg[5] = db.y; dreg[6] = db.z; dreg[7] = db.w;
    sreg[0] = sa.x; sreg[1] = sa.y; sreg[2] = sa.z; sreg[3] = sa.w;
    sreg[4] = sb.x; sreg[5] = sb.y; sreg[6] = sb.z; sreg[7] = sb.w;
  } else {
    #pragma unroll
    for (int j = 0; j < 8; ++j) {
      int e = eb + j;
      if (e < N_EDGES) { dreg[j] = dst[e]; sreg[j] = src[e]; }
      else             { dreg[j] = -1;     sreg[j] = 0;      }
    }
  }
  #pragma unroll
  for (int j = 0; j < 8; ++j)
    if (dreg[j] >= 0) atomicAdd(&hist[dreg[j] >> 8], 1u);
  __syncthreads();
  for (int t = tid; t < BKT; t += 256) {
    u32 c = hist[t];
    base[t] = c ? (u32)atomicAdd(&bucket_cur[t], (int)c) : 0u;
    hist[t] = 0;
  }
  __syncthreads();
  #pragma unroll
  for (int j = 0; j < 8; ++j) {
    if (dreg[j] >= 0) {
      int d = dreg[j];
      int b = d >> 8;
      u32 pos = base[b] + atomicAdd(&hist[b], 1u);
      bucketbuf[pos] = ((u32)sreg[j] << 8) | (u32)(d & 255);
    }
  }
  // fused norm: block 0 computes inv_norm + publishes isfp32
  if (blockIdx.x == 0) {
    if (tid < 128) { float v = loadF(pw, tid, f32in); ns[tid] = v * v; }
    __syncthreads();
    for (int s = 64; s > 0; s >>= 1) {
      if (tid < s) ns[tid] += ns[tid + s];
      __syncthreads();
    }
    if (tid == 0) {
      ctl->inv_norm = 1.0f / sqrtf(ns[0]);
      ctl->isfp32 = f32in ? 1u : 0u;
    }
  }
}

// ------- CSR1 from buckets (inline bucket scan) + fused x -> xbf = dis1*x (bf16) -------

__global__ void csr_from_buckets_kernel(const u32* __restrict__ bucketbuf, const int* __restrict__ bucket_cur,
                                        int* __restrict__ rowstart, float* __restrict__ dis,
                                        int* __restrict__ csr,
                                        const void* __restrict__ x, ushort8* __restrict__ xbf,
                                        const Ctl* __restrict__ ctl)
{
  __shared__ u32 cnt[256];
  __shared__ u32 loc[256];
  __shared__ u32 cur[256];
  __shared__ float disS[256];
  const int b = blockIdx.x;
  const int tid = threadIdx.x;

  // inline scan of all bucket sizes -> off0 for this bucket
  int v = (tid < BKT) ? (bucket_cur[tid] - tid * BCAP) : 0;
  loc[tid] = (u32)v;
  __syncthreads();
  for (int off = 1; off < 256; off <<= 1) {
    u32 t = (tid >= off) ? loc[tid - off] : 0;
    __syncthreads();
    loc[tid] += t;
    __syncthreads();
  }
  const int bc = bucket_cur[b] - b * BCAP;
  const int off0 = (int)loc[b] - bc;
  if (b == BKT - 1 && tid == 0) rowstart[N_NODES] = (int)loc[BKT - 1];
  __syncthreads();

  const u32* buf = bucketbuf + (size_t)b * BCAP;
  cnt[tid] = 0;
  __syncthreads();
  for (int i = tid; i < bc; i += 256) atomicAdd(&cnt[buf[i] & 255u], 1u);
  __syncthreads();
  u32 c = cnt[tid];
  loc[tid] = c;
  __syncthreads();
  for (int off = 1; off < 256; off <<= 1) {
    u32 t = (tid >= off) ? loc[tid - off] : 0;
    __syncthreads();
    loc[tid] += t;
    __syncthreads();
  }
  int node = b * 256 + tid;
  u32 excl = loc[tid] - c;
  float ddv = rsqrtf(1.0f + (float)c);
  disS[tid] = ddv;
  if (node < N_NODES) {
    rowstart[node] = off0 + (int)excl;
    dis[node] = ddv;
  }
  cur[tid] = off0 + excl;
  __syncthreads();
  for (int i = tid; i < bc; i += 256) {
    u32 p = buf[i];
    u32 pos = atomicAdd(&cur[p & 255u], 1u);
    csr[pos] = (int)(p >> 8);
  }
  // fused prescaled conversion: xbf[node] = bf16(dis1[node] * x[node]), 64 ch
  {
    const bool f32in = ctl->isfp32 != 0;
    if (f32in) {
      const float* xf = (const float*)x;
      for (int u = tid; u < 2048; u += 256) {
        int r = u >> 3, lane = u & 7;
        int d = b * 256 + r;
        if (d < N_NODES) {
          float sc = disS[r];
          ushort8 o;
          #pragma unroll
          for (int c2 = 0; c2 < 8; ++c2)
            o[c2] = (u16)f2bf_bits(xf[(size_t)d * 64 + lane * 8 + c2] * sc);
          xbf[(size_t)d * 8 + lane] = o;
        }
      }
    } else {
      const ushort8* xi = (const ushort8*)x;
      for (int u = tid; u < 2048; u += 256) {
        int r = u >> 3, lane = u & 7;
        int d = b * 256 + r;
        if (d < N_NODES) {
          float sc = disS[r];
          ushort8 vv = xi[(size_t)d * 8 + lane];
          ushort8 o;
          #pragma unroll
          for (int c2 = 0; c2 < 8; ++c2)
            o[c2] = (u16)f2bf_bits(bfbits2f(vv[c2]) * sc);
          xbf[(size_t)d * 8 + lane] = o;
        }
      }
    }
  }
}

// ------- conv2 gather (R12 wave-per-node) + R16 fused cvec reverse-weight scatter -------

__global__ void gather_h2_kernel(const bf16* __restrict__ P, const int* __restrict__ rowstart,
                                 const int* __restrict__ len, const int* __restrict__ csr,
                                 const float* __restrict__ dis,
                                 const void* __restrict__ b, const Ctl* __restrict__ ctl,
                                 bf16* __restrict__ P2, float* __restrict__ cvec, int M)
{
  const bool f32 = ctl->isfp32 != 0;
  const int tid = threadIdx.x;
  const int d = blockIdx.x * 4 + (tid >> 6);   // one wave per node; grid = M/4 exactly
  const int lane = tid & 63;
  const int slot = lane >> 3, unit = lane & 7;
  const ushort8* H = (const ushort8*)P;
  const float dd = dis[d];
  float acc[8];
  gather_wave_partial(H, d, slot, unit, rowstart, len, csr, acc, cvec, dd);
  // butterfly reduce across slots (same unit): xor 8,16,32
  #pragma unroll
  for (int m = 8; m < 64; m <<= 1)
    #pragma unroll
    for (int c = 0; c < 8; ++c) acc[c] += __shfl_xor(acc[c], m);
  if (slot == 0) {
    ushort8 outv;
    #pragma unroll
    for (int c = 0; c < 8; ++c) {
      float h = acc[c] * dd + loadF(b, 8 * unit + c, f32);
      outv[c] = (u16)f2bf_bits(fmaxf(h, 0.f) * dd);
    }
    ((ushort8*)P2)[(size_t)d * 8 + unit] = outv;
  }
}

// ---------------- MFMA GEMMs (16x16x32 bf16, fp32 acc) ----------------

// conv1 FUSED: gather(xbf prescaled, graph1) -> LDS, then Y = G @ W1 + b1 (+score/keys)
__global__ void gemm_in_kernel(const ushort8* __restrict__ xbf,
                               const int* __restrict__ rowstart, const int* __restrict__ csr,
                               const float* __restrict__ dis,
                               const void* __restrict__ W, const void* __restrict__ b,
                               const void* __restrict__ pw,
                               bf16* __restrict__ Y, const Ctl* __restrict__ ctl,
                               float* __restrict__ score, u64* __restrict__ keys)
{
  __shared__ short Xs[64 * 72];
  __shared__ short Wt[128 * 72];
  __shared__ float bs[128];
  __shared__ float ps[128];
  const bool f32 = ctl->isfp32 != 0;
  const int tid = threadIdx.x;
  const int row0 = blockIdx.x * 64;

  if (!f32) {
    const short8* W8 = (const short8*)W;
    for (int i = tid; i < 1024; i += 256) {       // 64x128 shorts = 1024 short8
      int k = i >> 4, nb = i & 15;
      short8 v = W8[i];
      #pragma unroll
      for (int j = 0; j < 8; ++j) Wt[(nb * 8 + j) * 72 + k] = v[j];
    }
  } else {
    for (int i = tid; i < 64 * 128; i += 256) {
      int k = i >> 7, n = i & 127;
      Wt[n * 72 + k] = f2bf_bits(((const float*)W)[i]);
    }
  }
  // fused gather: 64 rows x 8 lane-units, 2 units/thread, straight into Xs
  for (int u = tid; u < 512; u += 256) {
    int r = u >> 3, lane = u & 7;
    int d = row0 + r;
    float acc[8];
    short8 outv;
    if (d < N_NODES) {
      gather_row8_pre(xbf, d, lane, rowstart, nullptr, csr, acc);
      float dd = dis[d];
      #pragma unroll
      for (int c = 0; c < 8; ++c) outv[c] = f2bf_bits(acc[c] * dd);
    } else {
      #pragma unroll
      for (int c = 0; c < 8; ++c) outv[c] = 0;
    }
    *(short8*)&Xs[r * 72 + lane * 8] = outv;
  }
  for (int i = tid; i < 128; i += 256) { bs[i] = loadF(b, i, f32); ps[i] = loadF(pw, i, f32); }
  __syncthreads();

  const int lane = tid & 63;
  const int w = tid >> 6;
  const int l16 = lane & 15;
  const int quad = lane >> 4;
  f32x4 acc[8];
  #pragma unroll
  for (int ct = 0; ct < 8; ++ct) acc[ct] = (f32x4){0.f, 0.f, 0.f, 0.f};
  const int arow = w * 16 + l16;
  #pragma unroll
  for (int kc = 0; kc < 2; ++kc) {
    short8 a = *(short8*)&Xs[arow * 72 + kc * 32 + quad * 8];
    #pragma unroll
    for (int ct = 0; ct < 8; ++ct) {
      short8 bb = *(short8*)&Wt[(ct * 16 + l16) * 72 + kc * 32 + quad * 8];
      acc[ct] = __builtin_amdgcn_mfma_f32_16x16x32_bf16(a, bb, acc[ct], 0, 0, 0);
    }
  }
  float inv_norm = ctl->inv_norm;
  #pragma unroll
  for (int r = 0; r < 4; ++r) {
    int gr = row0 + w * 16 + quad * 4 + r;
    float p = 0.f;
    #pragma unroll
    for (int ct = 0; ct < 8; ++ct) {
      int col = ct * 16 + l16;
      float h = acc[ct][r] + bs[col];
      if (gr < N_NODES) Y[(size_t)gr * 128 + col] = __float2bfloat16(h);
      p += fmaxf(h, 0.f) * ps[col];
    }
    p += __shfl_down(p, 8, 16);
    p += __shfl_down(p, 4, 16);
    p += __shfl_down(p, 2, 16);
    p += __shfl_down(p, 1, 16);
    if (l16 == 0 && gr < N_NODES) {
      float sc = tanhf(p * inv_norm);
      score[gr] = sc;
      u32 u = __float_as_uint(sc);
      u = (u & 0x80000000u) ? ~u : (u | 0x80000000u);
      keys[gr] = (((u64)u) << 16) | (u64)(0xFFFFu - (u32)gr);
    }
  }
}

// Y[M,64] = (relu?)X[M,128] @ W[128,64]; M multiple of 64
// kept!=null: X row = kept[row], apply relu*score[kept[row]] (fused TopK hp)
// prescale!=null: Y row *= prescale[row] (dis2, for gather-consumed outputs)
__global__ void gemm_128_64_kernel(const bf16* __restrict__ X, const void* __restrict__ W,
                                   bf16* __restrict__ Y, const Ctl* __restrict__ ctl,
                                   int M, int relu_x,
                                   const int* __restrict__ kept, const float* __restrict__ score,
                                   const float* __restrict__ prescale)
{
  __shared__ short Xs[64 * 136];
  __shared__ short Wt[64 * 136];
  __shared__ int keptS[64];
  __shared__ float scS[64];
  const bool f32 = ctl->isfp32 != 0;
  const int tid = threadIdx.x;
  const int row0 = blockIdx.x * 64;

  if (kept) {
    for (int i = tid; i < 64; i += 256) {
      int o = kept[row0 + i];
      keptS[i] = o;
      scS[i] = score[o];
    }
  }
  __syncthreads();

  if (!f32) {
    const short8* W8 = (const short8*)W;
    for (int i = tid; i < 1024; i += 256) {       // 128x64 shorts = 1024 short8
      int k = i >> 3, nb = i & 7;
      short8 v = W8[i];
      #pragma unroll
      for (int j = 0; j < 8; ++j) Wt[(nb * 8 + j) * 136 + k] = v[j];
    }
  } else {
    for (int i = tid; i < 128 * 64; i += 256) {
      int k = i >> 6, n = i & 63;
      Wt[n * 136 + k] = f2bf_bits(((const float*)W)[i]);
    }
  }
  const u32* X2 = (const u32*)X;
  for (int p = tid; p < 64 * 64; p += 256) {
    int r = p >> 6, kp = p & 63;
    int srow = kept ? keptS[r] : (row0 + r);
    u32 v = X2[(size_t)srow * 64 + kp];
    if (relu_x) {
      if (v & 0x8000u) v &= 0xFFFF0000u;
      if (v & 0x80000000u) v &= 0x0000FFFFu;
    }
    if (kept) {
      bf16x2 h = *(bf16x2*)&v;
      float s = scS[r];
      bf16x2 o;
      o.x = __float2bfloat16(fmaxf(bf2f(h.x), 0.f) * s);
      o.y = __float2bfloat16(fmaxf(bf2f(h.y), 0.f) * s);
      v = *(u32*)&o;
    }
    *(u32*)&Xs[r * 136 + 2 * kp] = v;
  }
  __syncthreads();

  const int lane = tid & 63;
  const int w = tid >> 6;
  const int l16 = lane & 15;
  const int quad = lane >> 4;
  f32x4 acc[4];
  #pragma unroll
  for (int ct = 0; ct < 4; ++ct) acc[ct] = (f32x4){0.f, 0.f, 0.f, 0.f};
  const int arow = w * 16 + l16;
  #pragma unroll
  for (int kc = 0; kc < 4; ++kc) {
    short8 a = *(short8*)&Xs[arow * 136 + kc * 32 + quad * 8];
    #pragma unroll
    for (int ct = 0; ct < 4; ++ct) {
      short8 bb = *(short8*)&Wt[(ct * 16 + l16) * 136 + kc * 32 + quad * 8];
      acc[ct] = __builtin_amdgcn_mfma_f32_16x16x32_bf16(a, bb, acc[ct], 0, 0, 0);
    }
  }
  #pragma unroll
  for (int ct = 0; ct < 4; ++ct)
    #pragma unroll
    for (int r = 0; r < 4; ++r) {
      int gr = row0 + w * 16 + quad * 4 + r;
      float val = acc[ct][r];
      if (prescale) val *= prescale[gr];
      Y[(size_t)gr * 64 + ct * 16 + l16] = __float2bfloat16(val);
    }
}

// conv3 FUSED (R17): gather(P2, graph2) -> LDS -> h3 = G @ W3 + b3, then
// weighted-sum epilogue: partial[ch][blk] = Σ_{rows in blk} wgt[row]·relu(h3[row][ch])
// (h3 never hits global memory; wgt = dis2·cvec)
__global__ void gemm_64_128_kernel(const bf16* __restrict__ P2,
                                   const int* __restrict__ rowstart, const int* __restrict__ len,
                                   const int* __restrict__ csr, const float* __restrict__ dis,
                                   const void* __restrict__ W, const void* __restrict__ b,
                                   const float* __restrict__ cvec,
                                   float* __restrict__ partial,
                                   const Ctl* __restrict__ ctl, int M, int nblk)
{
  __shared__ short Xs[64 * 72];
  __shared__ short Wt[128 * 72];
  __shared__ float bs[128];
  __shared__ float wgtS[64];
  __shared__ float cs[128];
  const bool f32 = ctl->isfp32 != 0;
  const int tid = threadIdx.x;
  const int row0 = blockIdx.x * 64;

  if (tid < 128) cs[tid] = 0.f;
  if (tid < 64) {
    int gr = row0 + tid;
    wgtS[tid] = dis[gr] * cvec[gr];
  }
  if (!f32) {
    const short8* W8 = (const short8*)W;
    for (int i = tid; i < 1024; i += 256) {       // 64x128 shorts = 1024 short8
      int k = i >> 4, nb = i & 15;
      short8 v = W8[i];
      #pragma unroll
      for (int j = 0; j < 8; ++j) Wt[(nb * 8 + j) * 72 + k] = v[j];
    }
  } else {
    for (int i = tid; i < 64 * 128; i += 256) {
      int k = i >> 7, n = i & 127;
      Wt[n * 72 + k] = f2bf_bits(((const float*)W)[i]);
    }
  }
  // fused gather (relu baked into P2 at conv2 write)
  {
    const ushort8* H = (const ushort8*)P2;
    for (int u = tid; u < 512; u += 256) {
      int r = u >> 3, lane = u & 7;
      int d = row0 + r;           // M multiple of 64 -> always < M
      float acc[8];
      gather_row8_pre(H, d, lane, rowstart, len, csr, acc);
      float dd = dis[d];
      short8 outv;
      #pragma unroll
      for (int c = 0; c < 8; ++c) outv[c] = f2bf_bits(acc[c] * dd);
      *(short8*)&Xs[r * 72 + lane * 8] = outv;
    }
  }
  for (int i = tid; i < 128; i += 256) bs[i] = loadF(b, i, f32);
  __syncthreads();

  const int lane = tid & 63;
  const int w = tid >> 6;
  const int l16 = lane & 15;
  const int quad = lane >> 4;
  f32x4 acc[8];
  #pragma unroll
  for (int ct = 0; ct < 8; ++ct) acc[ct] = (f32x4){0.f, 0.f, 0.f, 0.f};
  const int arow = w * 16 + l16;
  #pragma unroll
  for (int kc = 0; kc < 2; ++kc) {
    short8 a = *(short8*)&Xs[arow * 72 + kc * 32 + quad * 8];
    #pragma unroll
    for (int ct = 0; ct < 8; ++ct) {
      short8 bb = *(short8*)&Wt[(ct * 16 + l16) * 72 + kc * 32 + quad * 8];
      acc[ct] = __builtin_amdgcn_mfma_f32_16x16x32_bf16(a, bb, acc[ct], 0, 0, 0);
    }
  }
  // weighted-sum epilogue: per thread, 8 cols x 4 rows; sum rows then one LDS atomic/col
  #pragma unroll
  for (int ct = 0; ct < 8; ++ct) {
    int col = ct * 16 + l16;
    float s = 0.f;
    #pragma unroll
    for (int r = 0; r < 4; ++r) {
      int lr = w * 16 + quad * 4 + r;
      float h = acc[ct][r] + bs[col];
      float hb = bfbits2f((u16)f2bf_bits(h));   // keep R16 numerics (bf16 round)
      s += fmaxf(hb, 0.f) * wgtS[lr];
    }
    atomicAdd(&cs[col], s);
  }
  __syncthreads();
  if (tid < 128) partial[(size_t)tid * nblk + blockIdx.x] = cs[tid];
}

// R15: fully parallel final reduce + matvec (512 threads, LDS trees)
__global__ void final_out_kernel(const float* __restrict__ partial, const void* __restrict__ W4,
                                 const void* __restrict__ b4, const Ctl* __restrict__ ctl,
                                 void* __restrict__ out, int nblk)
{
  __shared__ float red[512];
  __shared__ float S[128];
  const int tid = threadIdx.x;
  // stage 1: sum partials; 4 threads/channel, ceil(nblk/4) entries each
  {
    const int ch = tid >> 2, chunk = tid & 3;
    const int per = (nblk + 3) / 4;
    float s = 0.f;
    const float* p = partial + (size_t)ch * nblk;
    for (int j = chunk * per; j < (chunk + 1) * per && j < nblk; ++j) s += p[j];
    red[tid] = s;
  }
  __syncthreads();
  if (tid < 128) S[tid] = (red[4 * tid] + red[4 * tid + 1]) + (red[4 * tid + 2] + red[4 * tid + 3]);
  __syncthreads();
  // stage 2: matvec out[c] = sum_k S[k]*W4[k][c]; 8 threads/output, 16 k each
  {
    const bool f32 = ctl->isfp32 != 0;
    const int c = tid >> 3, chunk = tid & 7;
    float o = 0.f;
    #pragma unroll
    for (int j = 0; j < 16; ++j) {
      int k = chunk * 16 + j;
      o += S[k] * loadF(W4, (size_t)k * 64 + c, f32);
    }
    red[tid] = o;
    __syncthreads();
    if (tid < 64) {
      float acc = 0.f;
      #pragma unroll
      for (int j = 0; j < 8; ++j) acc += red[tid * 8 + j];
      float val = acc / (float)K_KEEP + loadF(b4, tid, f32);
      if (f32) ((float*)out)[tid] = val;
      else     ((bf16*)out)[tid] = __float2bfloat16(val);
    }
  }
}

// ------- TopK select: 8-bit x 6 radix hist+pick (R12-proven); fused mark on pass==gen -------

__device__ __forceinline__ void mark_slice(const u64* __restrict__ keys, Ctl* ctl,
                                           int* __restrict__ new_idx, int* __restrict__ kept,
                                           int i)
{
  if (i >= N_NODES) return;
  if (keys[i] >= ctl->prefix) {
    int pos = (int)atomicAdd(&ctl->cnt, 1u);
    new_idx[i] = pos;
    kept[pos] = i;
  } else {
    new_idx[i] = -1;
  }
}

__global__ void histpick_kernel(const u64* __restrict__ keys, Ctl* ctl, int shift, int pass,
                                int nblocks, int* __restrict__ new_idx, int* __restrict__ kept) {
  __shared__ u32 lh[256];
  __shared__ u32 sfx[256];
  __shared__ int lastflag;
  __shared__ int selsh;
  const int tid = threadIdx.x;
  const u32 g = ctl->gen;
  if (g != 0u) {
    // resolved at pass (g-1); pass q==g performs the fused marking, later passes no-op
    if ((u32)pass == g)
      mark_slice(keys, ctl, new_idx, kept, blockIdx.x * 256 + tid);
    return;
  }
  lh[tid] = 0;
  __syncthreads();
  u64 prefix = ctl->prefix;
  int i = blockIdx.x * 256 + tid;
  if (i < N_NODES) {
    u64 key = keys[i];
    if ((key >> (shift + 8)) == (prefix >> (shift + 8)))
      atomicAdd(&lh[(u32)((key >> shift) & 0xFF)], 1u);
  }
  __syncthreads();
  u32 c = lh[tid];
  if (c) atomicAdd(&ctl->hist[tid], c);
  __syncthreads();
  if (tid == 0) {
    __threadfence();
    u32 old = atomicAdd(&ctl->done, 1u);
    lastflag = (old == (u32)(nblocks - 1));
  }
  __syncthreads();
  if (!lastflag) return;
  // last block: parallel pick via suffix scan
  u32 cc = atomicExch(&ctl->hist[tid], 0u);   // coherent read + zero for next pass
  sfx[tid] = cc;
  __syncthreads();
  for (int off = 1; off < 256; off <<= 1) {
    u32 t = (tid + off < 256) ? sfx[tid + off] : 0u;
    __syncthreads();
    sfx[tid] += t;
    __syncthreads();
  }
  u32 kr = ctl->kremain;
  u32 above = (tid < 255) ? sfx[tid + 1] : 0u;
  if (sfx[tid] >= kr && above < kr) selsh = tid;   // unique (sfx non-increasing)
  __syncthreads();
  if (tid == 0) {
    int sel = selsh;
    u32 ab = (sel < 255) ? sfx[sel + 1] : 0u;
    u32 newkr = kr - ab;
    u32 bucketcnt = sfx[sel] - ab;
    ctl->kremain = newkr;
    ctl->prefix = prefix | (((u64)(u32)sel) << shift);
    if (newkr == bucketcnt) ctl->gen = (u32)(pass + 1);  // resolved; pass+1 marks
    ctl->done = 0u;
  }
}

// fallback mark: only runs if not already marked by a fused pass (gen==0 or gen==6)
__global__ void mark_kernel(const u64* __restrict__ keys, Ctl* ctl,
                            int* __restrict__ new_idx, int* __restrict__ kept)
{
  u32 g = ctl->gen;
  if (g >= 1u && g <= 5u) return;   // marked by histpick pass q==g
  mark_slice(keys, ctl, new_idx, kept, blockIdx.x * 256 + (int)threadIdx.x);
}

// ------- CSR2 (R17): 8 lanes/row — group count, wave-scan alloc, ballot-rank fill -------

__global__ void csr2_build_kernel(const int* __restrict__ kept, const int* __restrict__ rowstart1,
                                  const int* __restrict__ csr1, const int* __restrict__ new_idx,
                                  Ctl* ctl, int* __restrict__ rowstart2, int* __restrict__ len2,
                                  float* __restrict__ dis2, int* __restrict__ csr2,
                                  float* __restrict__ cvec)
{
  const int gid = blockIdx.x * 256 + threadIdx.x;
  const int kp = gid >> 3;
  const int lane = threadIdx.x & 63;
  const int grp = lane >> 3, l8 = lane & 7;
  int c = 0;
  int i0 = 0, i1 = 0;
  if (kp < K_KEEP) {
    int o = kept[kp];
    i0 = rowstart1[o]; i1 = rowstart1[o + 1];
    for (int i = i0 + l8; i < i1; i += 8) c += (new_idx[csr1[i]] >= 0);
  }
  // group total (xor within 8-lane group)
  c += __shfl_xor(c, 1);
  c += __shfl_xor(c, 2);
  c += __shfl_xor(c, 4);
  // wave prefix over 8 groups + single cursor atomic per wave
  int pre = 0, wtot = 0;
  #pragma unroll
  for (int g = 0; g < 8; ++g) {
    int tg = __shfl(c, g * 8);
    if (g < grp) pre += tg;
    wtot += tg;
  }
  int wbase = 0;
  if (lane == 0) wbase = (int)atomicAdd(&ctl->pad, (u32)wtot);
  wbase = __shfl(wbase, 0);
  int w = wbase + pre;
  if (kp < K_KEEP) {
    if (l8 == 0) {
      rowstart2[kp] = w;
      len2[kp] = c;
      float ddv = rsqrtf(1.0f + (float)c);
      dis2[kp] = ddv;
      cvec[kp] = ddv;                          // self term (plain store; unique index)
    }
    // ballot-rank compaction fill
    for (int ib = i0; ib < i1; ib += 8) {
      int i = ib + l8;
      int ns = (i < i1) ? new_idx[csr1[i]] : -1;
      u64 bal = __ballot(ns >= 0);
      u32 m8 = (u32)((bal >> (grp * 8)) & 0xFFull);
      if (ns >= 0) {
        int rank = __popc(m8 & ((1u << l8) - 1u));
        csr2[w + rank] = ns;
      }
      w += __popc(m8);
    }
  }
}

// ---------------- launch ----------------

extern "C" void kernel_launch(void* const* d_in, const int* in_sizes, int n_in,
                              void* d_out, int out_size, void* d_ws, size_t ws_size,
                              hipStream_t stream)
{
  const void* x  = d_in[0];
  const int*  ei = (const int*)d_in[1];
  const void* W1 = d_in[3];
  const void* b1 = d_in[4];
  const void* pw = d_in[5];
  const void* W2 = d_in[6];
  const void* b2 = d_in[7];
  const void* W3 = d_in[8];
  const void* b3 = d_in[9];
  const void* W4 = d_in[10];
  const void* b4 = d_in[11];

  const int* src = ei;
  const int* dst = ei + N_EDGES;

  float* F = (float*)d_ws;
  bf16*  A16       = (bf16*)F;               // N x 128 bf16 (conv2 output)
  bf16*  B16       = (bf16*)(F + 3200000);   // N x 128 bf16
  bf16*  C16       = (bf16*)(F + 6400000);   // K x 128 bf16
  u32*   xbf       = (u32*)(F + 9000000);    // N x 32 u32 (xbf = dis1*x as bf16 pairs)
  float* dis1      = F + 10600000;           // 50000
  float* dis2      = F + 10650000;           // 40000
  float* score     = F + 10690000;           // 50000
  u64*   keys      = (u64*)(F + 10740000);   // 50000 u64
  int*   new_idx   = (int*)(F + 10840000);   // 50000
  int*   kept      = (int*)(F + 10890000);   // 40000
  int*   len2      = (int*)(F + 10930000);   // 40000
  int*   rowstart1 = (int*)(F + 10970000);   // 50001
  int*   rowstart2 = (int*)(F + 11020004);   // 40000
  int*   csr1      = (int*)(F + 11060008);   // 800000
  int*   csr2      = (int*)(F + 11860008);   // 800000
  Ctl*   ctl       = (Ctl*)(F + 12660008);   // ~1.1 KB
  int*   detcnt    = (int*)(F + 12660856);   // 64
  int*   bucket_cur= (int*)(F + 12660920);   // 196
  float* cvec      = F + 12665216;           // 40000 (reverse weights)
  u32*   bucketbuf = (u32*)(F + 12726908);   // 196*6144
  float* partial   = F + 13931132;           // 128 x 625

  const int NB1 = (N_NODES + 255) / 256;     // 196
  const int EB2 = (N_EDGES + 2047) / 2048;   // 391
  const int GB1 = (N_NODES + 63) / 64;       // 782
  const int WBK = K_KEEP / 4;                // 10000 (wave-per-node)
  const int CB8 = K_KEEP * 8 / 256;          // 1250 (8 lanes/row)
  const int GB3 = K_KEEP / 64;               // 625 (conv3 blocks = partial cols)

  init_kernel<<<NB1, 256, 0, stream>>>((const unsigned short*)x, bucket_cur, detcnt, ctl, cvec);

  // CSR graph 1 via bucket sort (+fused dtype/norm)
  bucket_scatter_kernel<<<EB2, 256, 0, stream>>>(src, dst, bucket_cur, bucketbuf,
                                                 detcnt, pw, ctl);
  // CSR1 build + fused xbf = dis1*x prescale-convert
  csr_from_buckets_kernel<<<BKT, 256, 0, stream>>>(bucketbuf, bucket_cur, rowstart1, dis1, csr1,
                                                   x, (ushort8*)xbf, ctl);

  // conv1 FUSED: gather(xbf) -> LDS -> h1 = G @ W1 + b1 (+fused score/keys)
  gemm_in_kernel<<<GB1, 256, 0, stream>>>((const ushort8*)xbf, rowstart1, csr1, dis1,
                                          W1, b1, pw, B16, ctl, score, keys);

  // top-K select (6 x 8-bit radix; early-exit; first post-resolution pass marks)
  for (int p = 0; p < 6; ++p)
    histpick_kernel<<<NB1, 256, 0, stream>>>(keys, ctl, 40 - 8 * p, p, NB1, new_idx, kept);
  mark_kernel<<<NB1, 256, 0, stream>>>(keys, ctl, new_idx, kept);

  // CSR graph 2 (8 lanes/row; cvec self-term; reverse weights fused into gather_h2)
  csr2_build_kernel<<<CB8, 256, 0, stream>>>(kept, rowstart1, csr1, new_idx, ctl,
                                             rowstart2, len2, dis2, csr2, cvec);

  // conv2: A = dis2*(hp @ W2) ; P2 = dis2*relu(dd*sum(A) + b2)  [+fused cvec scatter]
  gemm_128_64_kernel<<<K_KEEP / 64, 256, 0, stream>>>(B16, W2, A16, ctl, K_KEEP, 0, kept, score, dis2);
  gather_h2_kernel<<<WBK, 256, 0, stream>>>(A16, rowstart2, len2, csr2, dis2, b2, ctl, C16, cvec, K_KEEP);

  // conv3 FUSED + weighted-sum epilogue (h3 never materialized)
  gemm_64_128_kernel<<<GB3, 256, 0, stream>>>(C16, rowstart2, len2, csr2, dis2,
                                              W3, b3, cvec, partial, ctl, K_KEEP, GB3);

  // out = S@W4/K + b4 (parallel reduce over 625 partials)
  final_out_kernel<<<1, 512, 0, stream>>>(partial, W4, b4, ctl, d_out, GB3);
}

// Round 18
// 327.947 us; speedup vs baseline: 1.1768x; 1.1768x over previous
//
#include <hip/hip_runtime.h>
#include <hip/hip_bf16.h>
#include <stdint.h>

#define N_NODES 50000
#define N_EDGES 800000
#define K_KEEP  40000
#define BKT     196        // ceil(N_NODES/256) dst-range buckets
#define BCAP    6144       // per-bucket capacity (mean 4081, +32 sigma)

typedef unsigned long long u64;
typedef unsigned int u32;
typedef unsigned short u16;
typedef __hip_bfloat16 bf16;
typedef __hip_bfloat162 bf16x2;
typedef __attribute__((ext_vector_type(8))) short short8;
typedef __attribute__((ext_vector_type(8))) unsigned short ushort8;
typedef __attribute__((ext_vector_type(4))) float f32x4;

struct Ctl {
  u64 prefix;
  u32 kremain;
  u32 cnt;
  float inv_norm;
  u32 isfp32;
  u32 done;         // radix pass arrival counter (reset by picker each pass)
  u32 pad;          // csr2 edge cursor
  u32 gen;          // 0 = unresolved; else (resolution pass + 1); pass==gen does marking
  u32 done2;        // (unused; layout keep)
  u32 hist[256];    // radix histogram (LDS-aggregated flushes only)
};

__device__ __forceinline__ float bf2f(bf16 v) { return __bfloat162float(v); }
__device__ __forceinline__ float bfbits2f(unsigned short u) {
  return __uint_as_float(((u32)u) << 16);
}
__device__ __forceinline__ float loadF(const void* p, size_t i, bool f32) {
  return f32 ? ((const float*)p)[i] : bf2f(((const bf16*)p)[i]);
}
__device__ __forceinline__ short f2bf_bits(float f) {
  bf16 t = __float2bfloat16(f);
  return *(const short*)&t;
}

// Prescaled gather (R9) with ILP-8 (R11), 8-lanes/node layout (used inside fused GEMMs)
__device__ __forceinline__ void gather_row8_pre(const ushort8* __restrict__ H, int d, int lane,
                                                const int* __restrict__ rowstart,
                                                const int* __restrict__ len,
                                                const int* __restrict__ csr,
                                                float* acc)
{
  ushort8 v = H[(size_t)d * 8 + lane];
  #pragma unroll
  for (int c = 0; c < 8; ++c) acc[c] = bfbits2f(v[c]);
  int i = rowstart[d];
  int i1 = len ? (i + len[d]) : rowstart[d + 1];
  for (; i + 8 <= i1; i += 8) {
    int s0 = csr[i],     s1 = csr[i + 1], s2 = csr[i + 2], s3 = csr[i + 3];
    int s4 = csr[i + 4], s5 = csr[i + 5], s6 = csr[i + 6], s7 = csr[i + 7];
    ushort8 v0 = H[(size_t)s0 * 8 + lane];
    ushort8 v1 = H[(size_t)s1 * 8 + lane];
    ushort8 v2 = H[(size_t)s2 * 8 + lane];
    ushort8 v3 = H[(size_t)s3 * 8 + lane];
    ushort8 v4 = H[(size_t)s4 * 8 + lane];
    ushort8 v5 = H[(size_t)s5 * 8 + lane];
    ushort8 v6 = H[(size_t)s6 * 8 + lane];
    ushort8 v7 = H[(size_t)s7 * 8 + lane];
    #pragma unroll
    for (int c = 0; c < 8; ++c) {
      acc[c] += (bfbits2f(v0[c]) + bfbits2f(v1[c]))
              + (bfbits2f(v2[c]) + bfbits2f(v3[c]));
      acc[c] += (bfbits2f(v4[c]) + bfbits2f(v5[c]))
              + (bfbits2f(v6[c]) + bfbits2f(v7[c]));
    }
  }
  for (; i + 4 <= i1; i += 4) {
    int s0 = csr[i], s1 = csr[i + 1], s2 = csr[i + 2], s3 = csr[i + 3];
    ushort8 v0 = H[(size_t)s0 * 8 + lane];
    ushort8 v1 = H[(size_t)s1 * 8 + lane];
    ushort8 v2 = H[(size_t)s2 * 8 + lane];
    ushort8 v3 = H[(size_t)s3 * 8 + lane];
    #pragma unroll
    for (int c = 0; c < 8; ++c) {
      acc[c] += (bfbits2f(v0[c]) + bfbits2f(v1[c]))
              + (bfbits2f(v2[c]) + bfbits2f(v3[c]));
    }
  }
  for (; i < i1; ++i) {
    int s = csr[i];
    ushort8 vv = H[(size_t)s * 8 + lane];
    #pragma unroll
    for (int c = 0; c < 8; ++c) acc[c] += bfbits2f(vv[c]);
  }
}

// R12 wave-per-node gather core with optional reverse-weight scatter (R16):
// slot = lane>>3 walks edges stride-8; unit = lane&7 reads contiguous 128B rows.
// cvec!=null: unit==0 lane fires atomicAdd(&cvec[s], dd) per edge (hidden under load latency).
__device__ __forceinline__ void gather_wave_partial(const ushort8* __restrict__ H, int d,
                                                    int slot, int unit,
                                                    const int* __restrict__ rowstart,
                                                    const int* __restrict__ len,
                                                    const int* __restrict__ csr,
                                                    float* acc,
                                                    float* __restrict__ cvec, float dd)
{
  #pragma unroll
  for (int c = 0; c < 8; ++c) acc[c] = 0.f;
  if (slot == 0) {
    ushort8 v = H[(size_t)d * 8 + unit];
    #pragma unroll
    for (int c = 0; c < 8; ++c) acc[c] = bfbits2f(v[c]);
  }
  int i0 = rowstart[d];
  int i1 = i0 + len[d];
  int i = i0 + slot;
  for (; i + 8 < i1; i += 16) {
    int sa = csr[i], sb = csr[i + 8];
    if (cvec && unit == 0) {
      atomicAdd(&cvec[sa], dd);
      atomicAdd(&cvec[sb], dd);
    }
    ushort8 va = H[(size_t)sa * 8 + unit];
    ushort8 vb = H[(size_t)sb * 8 + unit];
    #pragma unroll
    for (int c = 0; c < 8; ++c) acc[c] += bfbits2f(va[c]) + bfbits2f(vb[c]);
  }
  if (i < i1) {
    int s = csr[i];
    if (cvec && unit == 0) atomicAdd(&cvec[s], dd);
    ushort8 vv = H[(size_t)s * 8 + unit];
    #pragma unroll
    for (int c = 0; c < 8; ++c) acc[c] += bfbits2f(vv[c]);
  }
}

// ---------------- init (+parallel dtype detect, proven R5-R8) ----------------

__global__ void init_kernel(const unsigned short* __restrict__ x16,
                            int* __restrict__ bucket_cur, int* __restrict__ detcnt,
                            Ctl* ctl, float* __restrict__ cvec) {
  __shared__ u32 dsh[256];
  int i = blockIdx.x * 256 + threadIdx.x;
  if (i < BKT) bucket_cur[i] = i * BCAP;
  if (i < K_KEEP) cvec[i] = 0.f;
  if (blockIdx.x == 0) {
    ctl->hist[threadIdx.x] = 0u;
    if (threadIdx.x == 0) {
      ctl->prefix = 0ull; ctl->kremain = K_KEEP; ctl->cnt = 0u;
      ctl->done = 0u; ctl->pad = 0u; ctl->gen = 0u; ctl->done2 = 0u;
    }
  }
  if (blockIdx.x < 64) {
    int base = blockIdx.x * 2048;
    u32 c = 0;
    for (int j = threadIdx.x; j < 2048; j += 256) {
      u32 h = x16[base + j];
      if ((h & 0x7F80u) == 0x7F80u) c++;
    }
    dsh[threadIdx.x] = c;
    __syncthreads();
    for (int s = 128; s > 0; s >>= 1) {
      if (threadIdx.x < s) dsh[threadIdx.x] += dsh[threadIdx.x + s];
      __syncthreads();
    }
    if (threadIdx.x == 0) detcnt[blockIdx.x] = (int)dsh[0];
  }
}

// ------- CSR1 bucket scatter (int4 edge loads, R13) + fused dtype/norm -------

__global__ void bucket_scatter_kernel(const int* __restrict__ src, const int* __restrict__ dst,
                                      int* __restrict__ bucket_cur, u32* __restrict__ bucketbuf,
                                      const int* __restrict__ detcnt, const void* __restrict__ pw,
                                      Ctl* ctl)
{
  __shared__ u32 hist[BKT];
  __shared__ u32 base[BKT];
  __shared__ int f32sh;
  __shared__ float ns[128];
  const int tid = threadIdx.x;
  const int e0 = blockIdx.x * 2048;

  // dtype detect from detcnt (written by init, prior dispatch)
  if (tid < 64) {
    int dc = detcnt[tid];
    for (int off = 32; off; off >>= 1) dc += __shfl_down(dc, off);
    if (tid == 0) f32sh = (dc >= 16) ? 1 : 0;
  }
  for (int t = tid; t < BKT; t += 256) hist[t] = 0;
  __syncthreads();
  const bool f32in = f32sh != 0;

  // 8 contiguous edges/thread via int4 loads (fast path when block fully in range)
  int dreg[8], sreg[8];
  const int eb = e0 + tid * 8;
  if (e0 + 2048 <= N_EDGES) {
    const int4* d4 = (const int4*)(dst + eb);
    const int4* s4 = (const int4*)(src + eb);
    int4 da = d4[0], db = d4[1];
    int4 sa = s4[0], sb = s4[1];
    dreg[0] = da.x; dreg[1] = da.y; dreg[2] = da.z; dreg[3] = da.w;
    dreg[4] = db.x; dreg[5] = db.y; dreg[6] = db.z; dreg[7] = db.w;
    sreg[0] = sa.x; sreg[1] = sa.y; sreg[2] = sa.z; sreg[3] = sa.w;
    sreg[4] = sb.x; sreg[5] = sb.y; sreg[6] = sb.z; sreg[7] = sb.w;
  } else {
    #pragma unroll
    for (int j = 0; j < 8; ++j) {
      int e = eb + j;
      if (e < N_EDGES) { dreg[j] = dst[e]; sreg[j] = src[e]; }
      else             { dreg[j] = -1;     sreg[j] = 0;      }
    }
  }
  #pragma unroll
  for (int j = 0; j < 8; ++j)
    if (dreg[j] >= 0) atomicAdd(&hist[dreg[j] >> 8], 1u);
  __syncthreads();
  for (int t = tid; t < BKT; t += 256) {
    u32 c = hist[t];
    base[t] = c ? (u32)atomicAdd(&bucket_cur[t], (int)c) : 0u;
    hist[t] = 0;
  }
  __syncthreads();
  #pragma unroll
  for (int j = 0; j < 8; ++j) {
    if (dreg[j] >= 0) {
      int d = dreg[j];
      int b = d >> 8;
      u32 pos = base[b] + atomicAdd(&hist[b], 1u);
      bucketbuf[pos] = ((u32)sreg[j] << 8) | (u32)(d & 255);
    }
  }
  // fused norm: block 0 computes inv_norm + publishes isfp32
  if (blockIdx.x == 0) {
    if (tid < 128) { float v = loadF(pw, tid, f32in); ns[tid] = v * v; }
    __syncthreads();
    for (int s = 64; s > 0; s >>= 1) {
      if (tid < s) ns[tid] += ns[tid + s];
      __syncthreads();
    }
    if (tid == 0) {
      ctl->inv_norm = 1.0f / sqrtf(ns[0]);
      ctl->isfp32 = f32in ? 1u : 0u;
    }
  }
}

// ------- CSR1 from buckets (inline bucket scan) + fused x -> xbf = dis1*x (bf16) -------

__global__ void csr_from_buckets_kernel(const u32* __restrict__ bucketbuf, const int* __restrict__ bucket_cur,
                                        int* __restrict__ rowstart, float* __restrict__ dis,
                                        int* __restrict__ csr,
                                        const void* __restrict__ x, ushort8* __restrict__ xbf,
                                        const Ctl* __restrict__ ctl)
{
  __shared__ u32 cnt[256];
  __shared__ u32 loc[256];
  __shared__ u32 cur[256];
  __shared__ float disS[256];
  const int b = blockIdx.x;
  const int tid = threadIdx.x;

  // inline scan of all bucket sizes -> off0 for this bucket
  int v = (tid < BKT) ? (bucket_cur[tid] - tid * BCAP) : 0;
  loc[tid] = (u32)v;
  __syncthreads();
  for (int off = 1; off < 256; off <<= 1) {
    u32 t = (tid >= off) ? loc[tid - off] : 0;
    __syncthreads();
    loc[tid] += t;
    __syncthreads();
  }
  const int bc = bucket_cur[b] - b * BCAP;
  const int off0 = (int)loc[b] - bc;
  if (b == BKT - 1 && tid == 0) rowstart[N_NODES] = (int)loc[BKT - 1];
  __syncthreads();

  const u32* buf = bucketbuf + (size_t)b * BCAP;
  cnt[tid] = 0;
  __syncthreads();
  for (int i = tid; i < bc; i += 256) atomicAdd(&cnt[buf[i] & 255u], 1u);
  __syncthreads();
  u32 c = cnt[tid];
  loc[tid] = c;
  __syncthreads();
  for (int off = 1; off < 256; off <<= 1) {
    u32 t = (tid >= off) ? loc[tid - off] : 0;
    __syncthreads();
    loc[tid] += t;
    __syncthreads();
  }
  int node = b * 256 + tid;
  u32 excl = loc[tid] - c;
  float ddv = rsqrtf(1.0f + (float)c);
  disS[tid] = ddv;
  if (node < N_NODES) {
    rowstart[node] = off0 + (int)excl;
    dis[node] = ddv;
  }
  cur[tid] = off0 + excl;
  __syncthreads();
  for (int i = tid; i < bc; i += 256) {
    u32 p = buf[i];
    u32 pos = atomicAdd(&cur[p & 255u], 1u);
    csr[pos] = (int)(p >> 8);
  }
  // fused prescaled conversion: xbf[node] = bf16(dis1[node] * x[node]), 64 ch
  {
    const bool f32in = ctl->isfp32 != 0;
    if (f32in) {
      const float* xf = (const float*)x;
      for (int u = tid; u < 2048; u += 256) {
        int r = u >> 3, lane = u & 7;
        int d = b * 256 + r;
        if (d < N_NODES) {
          float sc = disS[r];
          ushort8 o;
          #pragma unroll
          for (int c2 = 0; c2 < 8; ++c2)
            o[c2] = (u16)f2bf_bits(xf[(size_t)d * 64 + lane * 8 + c2] * sc);
          xbf[(size_t)d * 8 + lane] = o;
        }
      }
    } else {
      const ushort8* xi = (const ushort8*)x;
      for (int u = tid; u < 2048; u += 256) {
        int r = u >> 3, lane = u & 7;
        int d = b * 256 + r;
        if (d < N_NODES) {
          float sc = disS[r];
          ushort8 vv = xi[(size_t)d * 8 + lane];
          ushort8 o;
          #pragma unroll
          for (int c2 = 0; c2 < 8; ++c2)
            o[c2] = (u16)f2bf_bits(bfbits2f(vv[c2]) * sc);
          xbf[(size_t)d * 8 + lane] = o;
        }
      }
    }
  }
}

// ------- conv2 gather (R12 wave-per-node) + R16 fused cvec reverse-weight scatter -------

__global__ void gather_h2_kernel(const bf16* __restrict__ P, const int* __restrict__ rowstart,
                                 const int* __restrict__ len, const int* __restrict__ csr,
                                 const float* __restrict__ dis,
                                 const void* __restrict__ b, const Ctl* __restrict__ ctl,
                                 bf16* __restrict__ P2, float* __restrict__ cvec, int M)
{
  const bool f32 = ctl->isfp32 != 0;
  const int tid = threadIdx.x;
  const int d = blockIdx.x * 4 + (tid >> 6);   // one wave per node; grid = M/4 exactly
  const int lane = tid & 63;
  const int slot = lane >> 3, unit = lane & 7;
  const ushort8* H = (const ushort8*)P;
  const float dd = dis[d];
  float acc[8];
  gather_wave_partial(H, d, slot, unit, rowstart, len, csr, acc, cvec, dd);
  // butterfly reduce across slots (same unit): xor 8,16,32
  #pragma unroll
  for (int m = 8; m < 64; m <<= 1)
    #pragma unroll
    for (int c = 0; c < 8; ++c) acc[c] += __shfl_xor(acc[c], m);
  if (slot == 0) {
    ushort8 outv;
    #pragma unroll
    for (int c = 0; c < 8; ++c) {
      float h = acc[c] * dd + loadF(b, 8 * unit + c, f32);
      outv[c] = (u16)f2bf_bits(fmaxf(h, 0.f) * dd);
    }
    ((ushort8*)P2)[(size_t)d * 8 + unit] = outv;
  }
}

// ---------------- MFMA GEMMs (16x16x32 bf16, fp32 acc) ----------------

// conv1 FUSED: gather(xbf prescaled, graph1) -> LDS, then Y = G @ W1 + b1 (+score/keys)
__global__ void gemm_in_kernel(const ushort8* __restrict__ xbf,
                               const int* __restrict__ rowstart, const int* __restrict__ csr,
                               const float* __restrict__ dis,
                               const void* __restrict__ W, const void* __restrict__ b,
                               const void* __restrict__ pw,
                               bf16* __restrict__ Y, const Ctl* __restrict__ ctl,
                               float* __restrict__ score, u64* __restrict__ keys)
{
  __shared__ short Xs[64 * 72];
  __shared__ short Wt[128 * 72];
  __shared__ float bs[128];
  __shared__ float ps[128];
  const bool f32 = ctl->isfp32 != 0;
  const int tid = threadIdx.x;
  const int row0 = blockIdx.x * 64;

  if (!f32) {
    const short8* W8 = (const short8*)W;
    for (int i = tid; i < 1024; i += 256) {       // 64x128 shorts = 1024 short8
      int k = i >> 4, nb = i & 15;
      short8 v = W8[i];
      #pragma unroll
      for (int j = 0; j < 8; ++j) Wt[(nb * 8 + j) * 72 + k] = v[j];
    }
  } else {
    for (int i = tid; i < 64 * 128; i += 256) {
      int k = i >> 7, n = i & 127;
      Wt[n * 72 + k] = f2bf_bits(((const float*)W)[i]);
    }
  }
  // fused gather: 64 rows x 8 lane-units, 2 units/thread, straight into Xs
  for (int u = tid; u < 512; u += 256) {
    int r = u >> 3, lane = u & 7;
    int d = row0 + r;
    float acc[8];
    short8 outv;
    if (d < N_NODES) {
      gather_row8_pre(xbf, d, lane, rowstart, nullptr, csr, acc);
      float dd = dis[d];
      #pragma unroll
      for (int c = 0; c < 8; ++c) outv[c] = f2bf_bits(acc[c] * dd);
    } else {
      #pragma unroll
      for (int c = 0; c < 8; ++c) outv[c] = 0;
    }
    *(short8*)&Xs[r * 72 + lane * 8] = outv;
  }
  for (int i = tid; i < 128; i += 256) { bs[i] = loadF(b, i, f32); ps[i] = loadF(pw, i, f32); }
  __syncthreads();

  const int lane = tid & 63;
  const int w = tid >> 6;
  const int l16 = lane & 15;
  const int quad = lane >> 4;
  f32x4 acc[8];
  #pragma unroll
  for (int ct = 0; ct < 8; ++ct) acc[ct] = (f32x4){0.f, 0.f, 0.f, 0.f};
  const int arow = w * 16 + l16;
  #pragma unroll
  for (int kc = 0; kc < 2; ++kc) {
    short8 a = *(short8*)&Xs[arow * 72 + kc * 32 + quad * 8];
    #pragma unroll
    for (int ct = 0; ct < 8; ++ct) {
      short8 bb = *(short8*)&Wt[(ct * 16 + l16) * 72 + kc * 32 + quad * 8];
      acc[ct] = __builtin_amdgcn_mfma_f32_16x16x32_bf16(a, bb, acc[ct], 0, 0, 0);
    }
  }
  float inv_norm = ctl->inv_norm;
  #pragma unroll
  for (int r = 0; r < 4; ++r) {
    int gr = row0 + w * 16 + quad * 4 + r;
    float p = 0.f;
    #pragma unroll
    for (int ct = 0; ct < 8; ++ct) {
      int col = ct * 16 + l16;
      float h = acc[ct][r] + bs[col];
      if (gr < N_NODES) Y[(size_t)gr * 128 + col] = __float2bfloat16(h);
      p += fmaxf(h, 0.f) * ps[col];
    }
    p += __shfl_down(p, 8, 16);
    p += __shfl_down(p, 4, 16);
    p += __shfl_down(p, 2, 16);
    p += __shfl_down(p, 1, 16);
    if (l16 == 0 && gr < N_NODES) {
      float sc = tanhf(p * inv_norm);
      score[gr] = sc;
      u32 u = __float_as_uint(sc);
      u = (u & 0x80000000u) ? ~u : (u | 0x80000000u);
      keys[gr] = (((u64)u) << 16) | (u64)(0xFFFFu - (u32)gr);
    }
  }
}

// Y[M,64] = (relu?)X[M,128] @ W[128,64]; M multiple of 64
// kept!=null: X row = kept[row], apply relu*score[kept[row]] (fused TopK hp)
// prescale!=null: Y row *= prescale[row] (dis2, for gather-consumed outputs)
__global__ void gemm_128_64_kernel(const bf16* __restrict__ X, const void* __restrict__ W,
                                   bf16* __restrict__ Y, const Ctl* __restrict__ ctl,
                                   int M, int relu_x,
                                   const int* __restrict__ kept, const float* __restrict__ score,
                                   const float* __restrict__ prescale)
{
  __shared__ short Xs[64 * 136];
  __shared__ short Wt[64 * 136];
  __shared__ int keptS[64];
  __shared__ float scS[64];
  const bool f32 = ctl->isfp32 != 0;
  const int tid = threadIdx.x;
  const int row0 = blockIdx.x * 64;

  if (kept) {
    for (int i = tid; i < 64; i += 256) {
      int o = kept[row0 + i];
      keptS[i] = o;
      scS[i] = score[o];
    }
  }
  __syncthreads();

  if (!f32) {
    const short8* W8 = (const short8*)W;
    for (int i = tid; i < 1024; i += 256) {       // 128x64 shorts = 1024 short8
      int k = i >> 3, nb = i & 7;
      short8 v = W8[i];
      #pragma unroll
      for (int j = 0; j < 8; ++j) Wt[(nb * 8 + j) * 136 + k] = v[j];
    }
  } else {
    for (int i = tid; i < 128 * 64; i += 256) {
      int k = i >> 6, n = i & 63;
      Wt[n * 136 + k] = f2bf_bits(((const float*)W)[i]);
    }
  }
  const u32* X2 = (const u32*)X;
  for (int p = tid; p < 64 * 64; p += 256) {
    int r = p >> 6, kp = p & 63;
    int srow = kept ? keptS[r] : (row0 + r);
    u32 v = X2[(size_t)srow * 64 + kp];
    if (relu_x) {
      if (v & 0x8000u) v &= 0xFFFF0000u;
      if (v & 0x80000000u) v &= 0x0000FFFFu;
    }
    if (kept) {
      bf16x2 h = *(bf16x2*)&v;
      float s = scS[r];
      bf16x2 o;
      o.x = __float2bfloat16(fmaxf(bf2f(h.x), 0.f) * s);
      o.y = __float2bfloat16(fmaxf(bf2f(h.y), 0.f) * s);
      v = *(u32*)&o;
    }
    *(u32*)&Xs[r * 136 + 2 * kp] = v;
  }
  __syncthreads();

  const int lane = tid & 63;
  const int w = tid >> 6;
  const int l16 = lane & 15;
  const int quad = lane >> 4;
  f32x4 acc[4];
  #pragma unroll
  for (int ct = 0; ct < 4; ++ct) acc[ct] = (f32x4){0.f, 0.f, 0.f, 0.f};
  const int arow = w * 16 + l16;
  #pragma unroll
  for (int kc = 0; kc < 4; ++kc) {
    short8 a = *(short8*)&Xs[arow * 136 + kc * 32 + quad * 8];
    #pragma unroll
    for (int ct = 0; ct < 4; ++ct) {
      short8 bb = *(short8*)&Wt[(ct * 16 + l16) * 136 + kc * 32 + quad * 8];
      acc[ct] = __builtin_amdgcn_mfma_f32_16x16x32_bf16(a, bb, acc[ct], 0, 0, 0);
    }
  }
  #pragma unroll
  for (int ct = 0; ct < 4; ++ct)
    #pragma unroll
    for (int r = 0; r < 4; ++r) {
      int gr = row0 + w * 16 + quad * 4 + r;
      float val = acc[ct][r];
      if (prescale) val *= prescale[gr];
      Y[(size_t)gr * 64 + ct * 16 + l16] = __float2bfloat16(val);
    }
}

// conv3 FUSED: gather(P2 prescaled, graph2) -> LDS, then Y[M,128] = G @ W3 + b3
__global__ void gemm_64_128_kernel(const bf16* __restrict__ P2,
                                   const int* __restrict__ rowstart, const int* __restrict__ len,
                                   const int* __restrict__ csr, const float* __restrict__ dis,
                                   const void* __restrict__ W, const void* __restrict__ b,
                                   bf16* __restrict__ Y, const Ctl* __restrict__ ctl, int M)
{
  __shared__ short Xs[64 * 72];
  __shared__ short Wt[128 * 72];
  __shared__ float bs[128];
  const bool f32 = ctl->isfp32 != 0;
  const int tid = threadIdx.x;
  const int row0 = blockIdx.x * 64;

  if (!f32) {
    const short8* W8 = (const short8*)W;
    for (int i = tid; i < 1024; i += 256) {       // 64x128 shorts = 1024 short8
      int k = i >> 4, nb = i & 15;
      short8 v = W8[i];
      #pragma unroll
      for (int j = 0; j < 8; ++j) Wt[(nb * 8 + j) * 72 + k] = v[j];
    }
  } else {
    for (int i = tid; i < 64 * 128; i += 256) {
      int k = i >> 7, n = i & 127;
      Wt[n * 72 + k] = f2bf_bits(((const float*)W)[i]);
    }
  }
  // fused gather (relu baked into P2 at conv2 write)
  {
    const ushort8* H = (const ushort8*)P2;
    for (int u = tid; u < 512; u += 256) {
      int r = u >> 3, lane = u & 7;
      int d = row0 + r;           // M multiple of 64 -> always < M
      float acc[8];
      gather_row8_pre(H, d, lane, rowstart, len, csr, acc);
      float dd = dis[d];
      short8 outv;
      #pragma unroll
      for (int c = 0; c < 8; ++c) outv[c] = f2bf_bits(acc[c] * dd);
      *(short8*)&Xs[r * 72 + lane * 8] = outv;
    }
  }
  for (int i = tid; i < 128; i += 256) bs[i] = loadF(b, i, f32);
  __syncthreads();

  const int lane = tid & 63;
  const int w = tid >> 6;
  const int l16 = lane & 15;
  const int quad = lane >> 4;
  f32x4 acc[8];
  #pragma unroll
  for (int ct = 0; ct < 8; ++ct) acc[ct] = (f32x4){0.f, 0.f, 0.f, 0.f};
  const int arow = w * 16 + l16;
  #pragma unroll
  for (int kc = 0; kc < 2; ++kc) {
    short8 a = *(short8*)&Xs[arow * 72 + kc * 32 + quad * 8];
    #pragma unroll
    for (int ct = 0; ct < 8; ++ct) {
      short8 bb = *(short8*)&Wt[(ct * 16 + l16) * 72 + kc * 32 + quad * 8];
      acc[ct] = __builtin_amdgcn_mfma_f32_16x16x32_bf16(a, bb, acc[ct], 0, 0, 0);
    }
  }
  #pragma unroll
  for (int ct = 0; ct < 8; ++ct)
    #pragma unroll
    for (int r = 0; r < 4; ++r) {
      int gr = row0 + w * 16 + quad * 4 + r;
      int col = ct * 16 + l16;
      Y[(size_t)gr * 128 + col] = __float2bfloat16(acc[ct][r] + bs[col]);
    }
}

// conv4 ALGEBRAIC (R14): out = (Σ_s c'_s·relu(h3_s)) @ W4 / K + b4,
// c'_s = dis_s·cvec[s], cvec[s] = dis_s + Σ_{d: s∈N2(d)} dis_d.

__global__ void weighted_sum_kernel(const bf16* __restrict__ H3, const float* __restrict__ cvec,
                                    const float* __restrict__ dis,
                                    float* __restrict__ partial, int M, int nblk)
{
  __shared__ float cs[128];
  const int tid = threadIdx.x;
  if (tid < 128) cs[tid] = 0.f;
  __syncthreads();
  const int lane = tid & 15;                 // 16 lanes/row, 8 ch each = 128 ch
  const ushort8* H = (const ushort8*)H3;     // row = 16 x ushort8
  float acc[8];
  #pragma unroll
  for (int c = 0; c < 8; ++c) acc[c] = 0.f;
  for (int r = (blockIdx.x * 256 + tid) >> 4; r < M; r += nblk * 16) {
    float wgt = dis[r] * cvec[r];
    ushort8 v = H[(size_t)r * 16 + lane];
    #pragma unroll
    for (int c = 0; c < 8; ++c) acc[c] += wgt * fmaxf(bfbits2f(v[c]), 0.f);
  }
  #pragma unroll
  for (int c = 0; c < 8; ++c) atomicAdd(&cs[8 * lane + c], acc[c]);
  __syncthreads();
  if (tid < 128) partial[(size_t)tid * nblk + blockIdx.x] = cs[tid];
}

// R15: fully parallel final reduce + matvec (512 threads, LDS trees; nblk = 128)
__global__ void final_out_kernel(const float* __restrict__ partial, const void* __restrict__ W4,
                                 const void* __restrict__ b4, const Ctl* __restrict__ ctl,
                                 void* __restrict__ out, int nblk)
{
  __shared__ float red[512];
  __shared__ float S[128];
  const int tid = threadIdx.x;
  // stage 1: sum partials; 4 threads/channel, 32 entries each (nblk = 128)
  {
    const int ch = tid >> 2, chunk = tid & 3;
    const int per = nblk / 4;               // 32
    float s = 0.f;
    const float* p = partial + (size_t)ch * nblk + chunk * per;
    for (int j = 0; j < per; j += 4)
      s += (p[j] + p[j + 1]) + (p[j + 2] + p[j + 3]);
    red[tid] = s;
  }
  __syncthreads();
  if (tid < 128) S[tid] = (red[4 * tid] + red[4 * tid + 1]) + (red[4 * tid + 2] + red[4 * tid + 3]);
  __syncthreads();
  // stage 2: matvec out[c] = sum_k S[k]*W4[k][c]; 8 threads/output, 16 k each
  {
    const bool f32 = ctl->isfp32 != 0;
    const int c = tid >> 3, chunk = tid & 7;
    float o = 0.f;
    #pragma unroll
    for (int j = 0; j < 16; ++j) {
      int k = chunk * 16 + j;
      o += S[k] * loadF(W4, (size_t)k * 64 + c, f32);
    }
    red[tid] = o;
    __syncthreads();
    if (tid < 64) {
      float acc = 0.f;
      #pragma unroll
      for (int j = 0; j < 8; ++j) acc += red[tid * 8 + j];
      float val = acc / (float)K_KEEP + loadF(b4, tid, f32);
      if (f32) ((float*)out)[tid] = val;
      else     ((bf16*)out)[tid] = __float2bfloat16(val);
    }
  }
}

// ------- TopK select: 8-bit x 6 radix hist+pick (R12-proven); fused mark on pass==gen -------

__device__ __forceinline__ void mark_slice(const u64* __restrict__ keys, Ctl* ctl,
                                           int* __restrict__ new_idx, int* __restrict__ kept,
                                           int i)
{
  if (i >= N_NODES) return;
  if (keys[i] >= ctl->prefix) {
    int pos = (int)atomicAdd(&ctl->cnt, 1u);
    new_idx[i] = pos;
    kept[pos] = i;
  } else {
    new_idx[i] = -1;
  }
}

__global__ void histpick_kernel(const u64* __restrict__ keys, Ctl* ctl, int shift, int pass,
                                int nblocks, int* __restrict__ new_idx, int* __restrict__ kept) {
  __shared__ u32 lh[256];
  __shared__ u32 sfx[256];
  __shared__ int lastflag;
  __shared__ int selsh;
  const int tid = threadIdx.x;
  const u32 g = ctl->gen;
  if (g != 0u) {
    // resolved at pass (g-1); pass q==g performs the fused marking, later passes no-op
    if ((u32)pass == g)
      mark_slice(keys, ctl, new_idx, kept, blockIdx.x * 256 + tid);
    return;
  }
  lh[tid] = 0;
  __syncthreads();
  u64 prefix = ctl->prefix;
  int i = blockIdx.x * 256 + tid;
  if (i < N_NODES) {
    u64 key = keys[i];
    if ((key >> (shift + 8)) == (prefix >> (shift + 8)))
      atomicAdd(&lh[(u32)((key >> shift) & 0xFF)], 1u);
  }
  __syncthreads();
  u32 c = lh[tid];
  if (c) atomicAdd(&ctl->hist[tid], c);
  __syncthreads();
  if (tid == 0) {
    __threadfence();
    u32 old = atomicAdd(&ctl->done, 1u);
    lastflag = (old == (u32)(nblocks - 1));
  }
  __syncthreads();
  if (!lastflag) return;
  // last block: parallel pick via suffix scan
  u32 cc = atomicExch(&ctl->hist[tid], 0u);   // coherent read + zero for next pass
  sfx[tid] = cc;
  __syncthreads();
  for (int off = 1; off < 256; off <<= 1) {
    u32 t = (tid + off < 256) ? sfx[tid + off] : 0u;
    __syncthreads();
    sfx[tid] += t;
    __syncthreads();
  }
  u32 kr = ctl->kremain;
  u32 above = (tid < 255) ? sfx[tid + 1] : 0u;
  if (sfx[tid] >= kr && above < kr) selsh = tid;   // unique (sfx non-increasing)
  __syncthreads();
  if (tid == 0) {
    int sel = selsh;
    u32 ab = (sel < 255) ? sfx[sel + 1] : 0u;
    u32 newkr = kr - ab;
    u32 bucketcnt = sfx[sel] - ab;
    ctl->kremain = newkr;
    ctl->prefix = prefix | (((u64)(u32)sel) << shift);
    if (newkr == bucketcnt) ctl->gen = (u32)(pass + 1);  // resolved; pass+1 marks
    ctl->done = 0u;
  }
}

// fallback mark: only runs if not already marked by a fused pass (gen==0 or gen==6)
__global__ void mark_kernel(const u64* __restrict__ keys, Ctl* ctl,
                            int* __restrict__ new_idx, int* __restrict__ kept)
{
  u32 g = ctl->gen;
  if (g >= 1u && g <= 5u) return;   // marked by histpick pass q==g
  mark_slice(keys, ctl, new_idx, kept, blockIdx.x * 256 + (int)threadIdx.x);
}

// ------- CSR2 (R18): 8 lanes/row — group count, wave-scan alloc, ballot-rank fill -------

__global__ void csr2_build_kernel(const int* __restrict__ kept, const int* __restrict__ rowstart1,
                                  const int* __restrict__ csr1, const int* __restrict__ new_idx,
                                  Ctl* ctl, int* __restrict__ rowstart2, int* __restrict__ len2,
                                  float* __restrict__ dis2, int* __restrict__ csr2,
                                  float* __restrict__ cvec)
{
  const int gid = blockIdx.x * 256 + threadIdx.x;
  const int kp = gid >> 3;
  const int lane = threadIdx.x & 63;
  const int grp = lane >> 3, l8 = lane & 7;
  int c = 0;
  int i0 = 0, i1 = 0;
  if (kp < K_KEEP) {
    int o = kept[kp];
    i0 = rowstart1[o]; i1 = rowstart1[o + 1];
    for (int i = i0 + l8; i < i1; i += 8) c += (new_idx[csr1[i]] >= 0);
  }
  // group total (xor within 8-lane group)
  c += __shfl_xor(c, 1);
  c += __shfl_xor(c, 2);
  c += __shfl_xor(c, 4);
  // wave prefix over 8 groups + single cursor atomic per wave
  int pre = 0, wtot = 0;
  #pragma unroll
  for (int g = 0; g < 8; ++g) {
    int tg = __shfl(c, g * 8);
    if (g < grp) pre += tg;
    wtot += tg;
  }
  int wbase = 0;
  if (lane == 0) wbase = (int)atomicAdd(&ctl->pad, (u32)wtot);
  wbase = __shfl(wbase, 0);
  int w = wbase + pre;
  if (kp < K_KEEP) {
    if (l8 == 0) {
      rowstart2[kp] = w;
      len2[kp] = c;
      float ddv = rsqrtf(1.0f + (float)c);
      dis2[kp] = ddv;
      cvec[kp] = ddv;                          // self term (plain store; unique index)
    }
    // ballot-rank compaction fill
    for (int ib = i0; ib < i1; ib += 8) {
      int i = ib + l8;
      int ns = (i < i1) ? new_idx[csr1[i]] : -1;
      u64 bal = __ballot(ns >= 0);
      u32 m8 = (u32)((bal >> (grp * 8)) & 0xFFull);
      if (ns >= 0) {
        int rank = __popc(m8 & ((1u << l8) - 1u));
        csr2[w + rank] = ns;
      }
      w += __popc(m8);
    }
  }
}

// ---------------- launch ----------------

extern "C" void kernel_launch(void* const* d_in, const int* in_sizes, int n_in,
                              void* d_out, int out_size, void* d_ws, size_t ws_size,
                              hipStream_t stream)
{
  const void* x  = d_in[0];
  const int*  ei = (const int*)d_in[1];
  const void* W1 = d_in[3];
  const void* b1 = d_in[4];
  const void* pw = d_in[5];
  const void* W2 = d_in[6];
  const void* b2 = d_in[7];
  const void* W3 = d_in[8];
  const void* b3 = d_in[9];
  const void* W4 = d_in[10];
  const void* b4 = d_in[11];

  const int* src = ei;
  const int* dst = ei + N_EDGES;

  float* F = (float*)d_ws;
  bf16*  A16       = (bf16*)F;               // N x 128 bf16 (conv2 output)
  bf16*  B16       = (bf16*)(F + 3200000);   // N x 128 bf16
  bf16*  C16       = (bf16*)(F + 6400000);   // K x 128 bf16
  u32*   xbf       = (u32*)(F + 9000000);    // N x 32 u32 (xbf = dis1*x as bf16 pairs)
  float* dis1      = F + 10600000;           // 50000
  float* dis2      = F + 10650000;           // 40000
  float* score     = F + 10690000;           // 50000
  u64*   keys      = (u64*)(F + 10740000);   // 50000 u64
  int*   new_idx   = (int*)(F + 10840000);   // 50000
  int*   kept      = (int*)(F + 10890000);   // 40000
  int*   len2      = (int*)(F + 10930000);   // 40000
  int*   rowstart1 = (int*)(F + 10970000);   // 50001
  int*   rowstart2 = (int*)(F + 11020004);   // 40000
  int*   csr1      = (int*)(F + 11060008);   // 800000
  int*   csr2      = (int*)(F + 11860008);   // 800000
  Ctl*   ctl       = (Ctl*)(F + 12660008);   // ~1.1 KB
  int*   detcnt    = (int*)(F + 12660856);   // 64
  int*   bucket_cur= (int*)(F + 12660920);   // 196
  float* cvec      = F + 12665216;           // 40000 (reverse weights)
  u32*   bucketbuf = (u32*)(F + 12726908);   // 196*6144
  float* partial   = F + 13931132;           // 128 x 128

  const int NB1 = (N_NODES + 255) / 256;     // 196
  const int EB2 = (N_EDGES + 2047) / 2048;   // 391
  const int GB1 = (N_NODES + 63) / 64;       // 782
  const int WBK = K_KEEP / 4;                // 10000 (wave-per-node)
  const int CB8 = K_KEEP * 8 / 256;          // 1250 (8 lanes/row)
  const int NWS = 128;                       // weighted-sum blocks

  init_kernel<<<NB1, 256, 0, stream>>>((const unsigned short*)x, bucket_cur, detcnt, ctl, cvec);

  // CSR graph 1 via bucket sort (+fused dtype/norm)
  bucket_scatter_kernel<<<EB2, 256, 0, stream>>>(src, dst, bucket_cur, bucketbuf,
                                                 detcnt, pw, ctl);
  // CSR1 build + fused xbf = dis1*x prescale-convert
  csr_from_buckets_kernel<<<BKT, 256, 0, stream>>>(bucketbuf, bucket_cur, rowstart1, dis1, csr1,
                                                   x, (ushort8*)xbf, ctl);

  // conv1 FUSED: gather(xbf) -> LDS -> h1 = G @ W1 + b1 (+fused score/keys)
  gemm_in_kernel<<<GB1, 256, 0, stream>>>((const ushort8*)xbf, rowstart1, csr1, dis1,
                                          W1, b1, pw, B16, ctl, score, keys);

  // top-K select (6 x 8-bit radix; early-exit; first post-resolution pass marks)
  for (int p = 0; p < 6; ++p)
    histpick_kernel<<<NB1, 256, 0, stream>>>(keys, ctl, 40 - 8 * p, p, NB1, new_idx, kept);
  mark_kernel<<<NB1, 256, 0, stream>>>(keys, ctl, new_idx, kept);

  // CSR graph 2 (8 lanes/row; cvec self-term; reverse weights fused into gather_h2)
  csr2_build_kernel<<<CB8, 256, 0, stream>>>(kept, rowstart1, csr1, new_idx, ctl,
                                             rowstart2, len2, dis2, csr2, cvec);

  // conv2: A = dis2*(hp @ W2) ; P2 = dis2*relu(dd*sum(A) + b2)  [+fused cvec scatter]
  gemm_128_64_kernel<<<K_KEEP / 64, 256, 0, stream>>>(B16, W2, A16, ctl, K_KEEP, 0, kept, score, dis2);
  gather_h2_kernel<<<WBK, 256, 0, stream>>>(A16, rowstart2, len2, csr2, dis2, b2, ctl, C16, cvec, K_KEEP);

  // conv3 FUSED: gather(P2) -> LDS -> h3 = G @ W3 + b3
  gemm_64_128_kernel<<<K_KEEP / 64, 256, 0, stream>>>(C16, rowstart2, len2, csr2, dis2,
                                                      W3, b3, B16, ctl, K_KEEP);

  // conv4 ALGEBRAIC: S = Σ c'_s·relu(h3_s) ; out = S@W4/K + b4 (parallel reduce)
  weighted_sum_kernel<<<NWS, 256, 0, stream>>>(B16, cvec, dis2, partial, K_KEEP, NWS);
  final_out_kernel<<<1, 512, 0, stream>>>(partial, W4, b4, ctl, d_out, NWS);
}

// Round 19
// 277.036 us; speedup vs baseline: 1.3931x; 1.1838x over previous
//
#include <hip/hip_runtime.h>
#include <hip/hip_bf16.h>
#include <stdint.h>

#define N_NODES 50000
#define N_EDGES 800000
#define K_KEEP  40000
#define BKT     196        // ceil(N_NODES/256) dst-range buckets
#define BCAP    6144       // per-bucket capacity (mean 4081, +32 sigma)

typedef unsigned long long u64;
typedef unsigned int u32;
typedef unsigned short u16;
typedef __hip_bfloat16 bf16;
typedef __hip_bfloat162 bf16x2;
typedef __attribute__((ext_vector_type(8))) short short8;
typedef __attribute__((ext_vector_type(8))) unsigned short ushort8;
typedef __attribute__((ext_vector_type(4))) float f32x4;

struct Ctl {
  u64 prefix;
  u32 kremain;
  u32 cnt;
  float inv_norm;
  u32 isfp32;
  u32 done;         // radix pass arrival counter (reset by picker each pass)
  u32 pad;          // csr2 edge cursor
  u32 gen;          // 0 = unresolved; else (resolution pass + 1); pass==gen does marking
  u32 done2;        // (unused; layout keep)
  u32 hist[256];    // radix histogram (LDS-aggregated flushes only)
};

__device__ __forceinline__ float bf2f(bf16 v) { return __bfloat162float(v); }
__device__ __forceinline__ float bfbits2f(unsigned short u) {
  return __uint_as_float(((u32)u) << 16);
}
__device__ __forceinline__ float loadF(const void* p, size_t i, bool f32) {
  return f32 ? ((const float*)p)[i] : bf2f(((const bf16*)p)[i]);
}
__device__ __forceinline__ short f2bf_bits(float f) {
  bf16 t = __float2bfloat16(f);
  return *(const short*)&t;
}

// Prescaled gather (R9) with ILP-8 (R11), 8-lanes/node layout (used inside fused GEMMs)
__device__ __forceinline__ void gather_row8_pre(const ushort8* __restrict__ H, int d, int lane,
                                                const int* __restrict__ rowstart,
                                                const int* __restrict__ len,
                                                const int* __restrict__ csr,
                                                float* acc)
{
  ushort8 v = H[(size_t)d * 8 + lane];
  #pragma unroll
  for (int c = 0; c < 8; ++c) acc[c] = bfbits2f(v[c]);
  int i = rowstart[d];
  int i1 = len ? (i + len[d]) : rowstart[d + 1];
  for (; i + 8 <= i1; i += 8) {
    int s0 = csr[i],     s1 = csr[i + 1], s2 = csr[i + 2], s3 = csr[i + 3];
    int s4 = csr[i + 4], s5 = csr[i + 5], s6 = csr[i + 6], s7 = csr[i + 7];
    ushort8 v0 = H[(size_t)s0 * 8 + lane];
    ushort8 v1 = H[(size_t)s1 * 8 + lane];
    ushort8 v2 = H[(size_t)s2 * 8 + lane];
    ushort8 v3 = H[(size_t)s3 * 8 + lane];
    ushort8 v4 = H[(size_t)s4 * 8 + lane];
    ushort8 v5 = H[(size_t)s5 * 8 + lane];
    ushort8 v6 = H[(size_t)s6 * 8 + lane];
    ushort8 v7 = H[(size_t)s7 * 8 + lane];
    #pragma unroll
    for (int c = 0; c < 8; ++c) {
      acc[c] += (bfbits2f(v0[c]) + bfbits2f(v1[c]))
              + (bfbits2f(v2[c]) + bfbits2f(v3[c]));
      acc[c] += (bfbits2f(v4[c]) + bfbits2f(v5[c]))
              + (bfbits2f(v6[c]) + bfbits2f(v7[c]));
    }
  }
  for (; i + 4 <= i1; i += 4) {
    int s0 = csr[i], s1 = csr[i + 1], s2 = csr[i + 2], s3 = csr[i + 3];
    ushort8 v0 = H[(size_t)s0 * 8 + lane];
    ushort8 v1 = H[(size_t)s1 * 8 + lane];
    ushort8 v2 = H[(size_t)s2 * 8 + lane];
    ushort8 v3 = H[(size_t)s3 * 8 + lane];
    #pragma unroll
    for (int c = 0; c < 8; ++c) {
      acc[c] += (bfbits2f(v0[c]) + bfbits2f(v1[c]))
              + (bfbits2f(v2[c]) + bfbits2f(v3[c]));
    }
  }
  for (; i < i1; ++i) {
    int s = csr[i];
    ushort8 vv = H[(size_t)s * 8 + lane];
    #pragma unroll
    for (int c = 0; c < 8; ++c) acc[c] += bfbits2f(vv[c]);
  }
}

// R12 wave-per-node gather core with optional reverse-weight scatter (R16):
// slot = lane>>3 walks edges stride-8; unit = lane&7 reads contiguous 128B rows.
// cvec!=null: unit==0 lane fires atomicAdd(&cvec[s], dd) per edge (hidden under load latency).
__device__ __forceinline__ void gather_wave_partial(const ushort8* __restrict__ H, int d,
                                                    int slot, int unit,
                                                    const int* __restrict__ rowstart,
                                                    const int* __restrict__ len,
                                                    const int* __restrict__ csr,
                                                    float* acc,
                                                    float* __restrict__ cvec, float dd)
{
  #pragma unroll
  for (int c = 0; c < 8; ++c) acc[c] = 0.f;
  if (slot == 0) {
    ushort8 v = H[(size_t)d * 8 + unit];
    #pragma unroll
    for (int c = 0; c < 8; ++c) acc[c] = bfbits2f(v[c]);
  }
  int i0 = rowstart[d];
  int i1 = i0 + len[d];
  int i = i0 + slot;
  for (; i + 8 < i1; i += 16) {
    int sa = csr[i], sb = csr[i + 8];
    if (cvec && unit == 0) {
      atomicAdd(&cvec[sa], dd);
      atomicAdd(&cvec[sb], dd);
    }
    ushort8 va = H[(size_t)sa * 8 + unit];
    ushort8 vb = H[(size_t)sb * 8 + unit];
    #pragma unroll
    for (int c = 0; c < 8; ++c) acc[c] += bfbits2f(va[c]) + bfbits2f(vb[c]);
  }
  if (i < i1) {
    int s = csr[i];
    if (cvec && unit == 0) atomicAdd(&cvec[s], dd);
    ushort8 vv = H[(size_t)s * 8 + unit];
    #pragma unroll
    for (int c = 0; c < 8; ++c) acc[c] += bfbits2f(vv[c]);
  }
}

// ---------------- init (+parallel dtype detect, proven R5-R8) ----------------

__global__ void init_kernel(const unsigned short* __restrict__ x16,
                            int* __restrict__ bucket_cur, int* __restrict__ detcnt,
                            Ctl* ctl, float* __restrict__ cvec, float* __restrict__ partial) {
  __shared__ u32 dsh[256];
  int i = blockIdx.x * 256 + threadIdx.x;
  if (i < BKT) bucket_cur[i] = i * BCAP;
  if (i < K_KEEP) cvec[i] = 0.f;
  if (i < 128 * 128) partial[i] = 0.f;
  if (blockIdx.x == 0) {
    ctl->hist[threadIdx.x] = 0u;
    if (threadIdx.x == 0) {
      ctl->prefix = 0ull; ctl->kremain = K_KEEP; ctl->cnt = 0u;
      ctl->done = 0u; ctl->pad = 0u; ctl->gen = 0u; ctl->done2 = 0u;
    }
  }
  if (blockIdx.x < 64) {
    int base = blockIdx.x * 2048;
    u32 c = 0;
    for (int j = threadIdx.x; j < 2048; j += 256) {
      u32 h = x16[base + j];
      if ((h & 0x7F80u) == 0x7F80u) c++;
    }
    dsh[threadIdx.x] = c;
    __syncthreads();
    for (int s = 128; s > 0; s >>= 1) {
      if (threadIdx.x < s) dsh[threadIdx.x] += dsh[threadIdx.x + s];
      __syncthreads();
    }
    if (threadIdx.x == 0) detcnt[blockIdx.x] = (int)dsh[0];
  }
}

// ------- CSR1 bucket scatter (int4 edge loads, R13) + fused dtype/norm -------

__global__ void bucket_scatter_kernel(const int* __restrict__ src, const int* __restrict__ dst,
                                      int* __restrict__ bucket_cur, u32* __restrict__ bucketbuf,
                                      const int* __restrict__ detcnt, const void* __restrict__ pw,
                                      Ctl* ctl)
{
  __shared__ u32 hist[BKT];
  __shared__ u32 base[BKT];
  __shared__ int f32sh;
  __shared__ float ns[128];
  const int tid = threadIdx.x;
  const int e0 = blockIdx.x * 2048;

  // dtype detect from detcnt (written by init, prior dispatch)
  if (tid < 64) {
    int dc = detcnt[tid];
    for (int off = 32; off; off >>= 1) dc += __shfl_down(dc, off);
    if (tid == 0) f32sh = (dc >= 16) ? 1 : 0;
  }
  for (int t = tid; t < BKT; t += 256) hist[t] = 0;
  __syncthreads();
  const bool f32in = f32sh != 0;

  // 8 contiguous edges/thread via int4 loads (fast path when block fully in range)
  int dreg[8], sreg[8];
  const int eb = e0 + tid * 8;
  if (e0 + 2048 <= N_EDGES) {
    const int4* d4 = (const int4*)(dst + eb);
    const int4* s4 = (const int4*)(src + eb);
    int4 da = d4[0], db = d4[1];
    int4 sa = s4[0], sb = s4[1];
    dreg[0] = da.x; dreg[1] = da.y; dreg[2] = da.z; dreg[3] = da.w;
    dreg[4] = db.x; dreg[5] = db.y; dreg[6] = db.z; dreg[7] = db.w;
    sreg[0] = sa.x; sreg[1] = sa.y; sreg[2] = sa.z; sreg[3] = sa.w;
    sreg[4] = sb.x; sreg[5] = sb.y; sreg[6] = sb.z; sreg[7] = sb.w;
  } else {
    #pragma unroll
    for (int j = 0; j < 8; ++j) {
      int e = eb + j;
      if (e < N_EDGES) { dreg[j] = dst[e]; sreg[j] = src[e]; }
      else             { dreg[j] = -1;     sreg[j] = 0;      }
    }
  }
  #pragma unroll
  for (int j = 0; j < 8; ++j)
    if (dreg[j] >= 0) atomicAdd(&hist[dreg[j] >> 8], 1u);
  __syncthreads();
  for (int t = tid; t < BKT; t += 256) {
    u32 c = hist[t];
    base[t] = c ? (u32)atomicAdd(&bucket_cur[t], (int)c) : 0u;
    hist[t] = 0;
  }
  __syncthreads();
  #pragma unroll
  for (int j = 0; j < 8; ++j) {
    if (dreg[j] >= 0) {
      int d = dreg[j];
      int b = d >> 8;
      u32 pos = base[b] + atomicAdd(&hist[b], 1u);
      bucketbuf[pos] = ((u32)sreg[j] << 8) | (u32)(d & 255);
    }
  }
  // fused norm: block 0 computes inv_norm + publishes isfp32
  if (blockIdx.x == 0) {
    if (tid < 128) { float v = loadF(pw, tid, f32in); ns[tid] = v * v; }
    __syncthreads();
    for (int s = 64; s > 0; s >>= 1) {
      if (tid < s) ns[tid] += ns[tid + s];
      __syncthreads();
    }
    if (tid == 0) {
      ctl->inv_norm = 1.0f / sqrtf(ns[0]);
      ctl->isfp32 = f32in ? 1u : 0u;
    }
  }
}

// ------- CSR1 from buckets (inline bucket scan) + fused x -> xbf = dis1*x (bf16) -------

__global__ void csr_from_buckets_kernel(const u32* __restrict__ bucketbuf, const int* __restrict__ bucket_cur,
                                        int* __restrict__ rowstart, float* __restrict__ dis,
                                        int* __restrict__ csr,
                                        const void* __restrict__ x, ushort8* __restrict__ xbf,
                                        const Ctl* __restrict__ ctl)
{
  __shared__ u32 cnt[256];
  __shared__ u32 loc[256];
  __shared__ u32 cur[256];
  __shared__ float disS[256];
  const int b = blockIdx.x;
  const int tid = threadIdx.x;

  // inline scan of all bucket sizes -> off0 for this bucket
  int v = (tid < BKT) ? (bucket_cur[tid] - tid * BCAP) : 0;
  loc[tid] = (u32)v;
  __syncthreads();
  for (int off = 1; off < 256; off <<= 1) {
    u32 t = (tid >= off) ? loc[tid - off] : 0;
    __syncthreads();
    loc[tid] += t;
    __syncthreads();
  }
  const int bc = bucket_cur[b] - b * BCAP;
  const int off0 = (int)loc[b] - bc;
  if (b == BKT - 1 && tid == 0) rowstart[N_NODES] = (int)loc[BKT - 1];
  __syncthreads();

  const u32* buf = bucketbuf + (size_t)b * BCAP;
  cnt[tid] = 0;
  __syncthreads();
  for (int i = tid; i < bc; i += 256) atomicAdd(&cnt[buf[i] & 255u], 1u);
  __syncthreads();
  u32 c = cnt[tid];
  loc[tid] = c;
  __syncthreads();
  for (int off = 1; off < 256; off <<= 1) {
    u32 t = (tid >= off) ? loc[tid - off] : 0;
    __syncthreads();
    loc[tid] += t;
    __syncthreads();
  }
  int node = b * 256 + tid;
  u32 excl = loc[tid] - c;
  float ddv = rsqrtf(1.0f + (float)c);
  disS[tid] = ddv;
  if (node < N_NODES) {
    rowstart[node] = off0 + (int)excl;
    dis[node] = ddv;
  }
  cur[tid] = off0 + excl;
  __syncthreads();
  for (int i = tid; i < bc; i += 256) {
    u32 p = buf[i];
    u32 pos = atomicAdd(&cur[p & 255u], 1u);
    csr[pos] = (int)(p >> 8);
  }
  // fused prescaled conversion: xbf[node] = bf16(dis1[node] * x[node]), 64 ch
  {
    const bool f32in = ctl->isfp32 != 0;
    if (f32in) {
      const float* xf = (const float*)x;
      for (int u = tid; u < 2048; u += 256) {
        int r = u >> 3, lane = u & 7;
        int d = b * 256 + r;
        if (d < N_NODES) {
          float sc = disS[r];
          ushort8 o;
          #pragma unroll
          for (int c2 = 0; c2 < 8; ++c2)
            o[c2] = (u16)f2bf_bits(xf[(size_t)d * 64 + lane * 8 + c2] * sc);
          xbf[(size_t)d * 8 + lane] = o;
        }
      }
    } else {
      const ushort8* xi = (const ushort8*)x;
      for (int u = tid; u < 2048; u += 256) {
        int r = u >> 3, lane = u & 7;
        int d = b * 256 + r;
        if (d < N_NODES) {
          float sc = disS[r];
          ushort8 vv = xi[(size_t)d * 8 + lane];
          ushort8 o;
          #pragma unroll
          for (int c2 = 0; c2 < 8; ++c2)
            o[c2] = (u16)f2bf_bits(bfbits2f(vv[c2]) * sc);
          xbf[(size_t)d * 8 + lane] = o;
        }
      }
    }
  }
}

// ------- conv2 gather (R12 wave-per-node) + R16 fused cvec reverse-weight scatter -------

__global__ void gather_h2_kernel(const bf16* __restrict__ P, const int* __restrict__ rowstart,
                                 const int* __restrict__ len, const int* __restrict__ csr,
                                 const float* __restrict__ dis,
                                 const void* __restrict__ b, const Ctl* __restrict__ ctl,
                                 bf16* __restrict__ P2, float* __restrict__ cvec, int M)
{
  const bool f32 = ctl->isfp32 != 0;
  const int tid = threadIdx.x;
  const int d = blockIdx.x * 4 + (tid >> 6);   // one wave per node; grid = M/4 exactly
  const int lane = tid & 63;
  const int slot = lane >> 3, unit = lane & 7;
  const ushort8* H = (const ushort8*)P;
  const float dd = dis[d];
  float acc[8];
  gather_wave_partial(H, d, slot, unit, rowstart, len, csr, acc, cvec, dd);
  // butterfly reduce across slots (same unit): xor 8,16,32
  #pragma unroll
  for (int m = 8; m < 64; m <<= 1)
    #pragma unroll
    for (int c = 0; c < 8; ++c) acc[c] += __shfl_xor(acc[c], m);
  if (slot == 0) {
    ushort8 outv;
    #pragma unroll
    for (int c = 0; c < 8; ++c) {
      float h = acc[c] * dd + loadF(b, 8 * unit + c, f32);
      outv[c] = (u16)f2bf_bits(fmaxf(h, 0.f) * dd);
    }
    ((ushort8*)P2)[(size_t)d * 8 + unit] = outv;
  }
}

// ---------------- MFMA GEMMs (16x16x32 bf16, fp32 acc) ----------------

// conv1 FUSED: gather(xbf prescaled, graph1) -> LDS, then Y = G @ W1 + b1 (+score/keys)
__global__ void gemm_in_kernel(const ushort8* __restrict__ xbf,
                               const int* __restrict__ rowstart, const int* __restrict__ csr,
                               const float* __restrict__ dis,
                               const void* __restrict__ W, const void* __restrict__ b,
                               const void* __restrict__ pw,
                               bf16* __restrict__ Y, const Ctl* __restrict__ ctl,
                               float* __restrict__ score, u64* __restrict__ keys)
{
  __shared__ short Xs[64 * 72];
  __shared__ short Wt[128 * 72];
  __shared__ float bs[128];
  __shared__ float ps[128];
  const bool f32 = ctl->isfp32 != 0;
  const int tid = threadIdx.x;
  const int row0 = blockIdx.x * 64;

  if (!f32) {
    const short8* W8 = (const short8*)W;
    for (int i = tid; i < 1024; i += 256) {       // 64x128 shorts = 1024 short8
      int k = i >> 4, nb = i & 15;
      short8 v = W8[i];
      #pragma unroll
      for (int j = 0; j < 8; ++j) Wt[(nb * 8 + j) * 72 + k] = v[j];
    }
  } else {
    for (int i = tid; i < 64 * 128; i += 256) {
      int k = i >> 7, n = i & 127;
      Wt[n * 72 + k] = f2bf_bits(((const float*)W)[i]);
    }
  }
  // fused gather: 64 rows x 8 lane-units, 2 units/thread, straight into Xs
  for (int u = tid; u < 512; u += 256) {
    int r = u >> 3, lane = u & 7;
    int d = row0 + r;
    float acc[8];
    short8 outv;
    if (d < N_NODES) {
      gather_row8_pre(xbf, d, lane, rowstart, nullptr, csr, acc);
      float dd = dis[d];
      #pragma unroll
      for (int c = 0; c < 8; ++c) outv[c] = f2bf_bits(acc[c] * dd);
    } else {
      #pragma unroll
      for (int c = 0; c < 8; ++c) outv[c] = 0;
    }
    *(short8*)&Xs[r * 72 + lane * 8] = outv;
  }
  for (int i = tid; i < 128; i += 256) { bs[i] = loadF(b, i, f32); ps[i] = loadF(pw, i, f32); }
  __syncthreads();

  const int lane = tid & 63;
  const int w = tid >> 6;
  const int l16 = lane & 15;
  const int quad = lane >> 4;
  f32x4 acc[8];
  #pragma unroll
  for (int ct = 0; ct < 8; ++ct) acc[ct] = (f32x4){0.f, 0.f, 0.f, 0.f};
  const int arow = w * 16 + l16;
  #pragma unroll
  for (int kc = 0; kc < 2; ++kc) {
    short8 a = *(short8*)&Xs[arow * 72 + kc * 32 + quad * 8];
    #pragma unroll
    for (int ct = 0; ct < 8; ++ct) {
      short8 bb = *(short8*)&Wt[(ct * 16 + l16) * 72 + kc * 32 + quad * 8];
      acc[ct] = __builtin_amdgcn_mfma_f32_16x16x32_bf16(a, bb, acc[ct], 0, 0, 0);
    }
  }
  float inv_norm = ctl->inv_norm;
  #pragma unroll
  for (int r = 0; r < 4; ++r) {
    int gr = row0 + w * 16 + quad * 4 + r;
    float p = 0.f;
    #pragma unroll
    for (int ct = 0; ct < 8; ++ct) {
      int col = ct * 16 + l16;
      float h = acc[ct][r] + bs[col];
      if (gr < N_NODES) Y[(size_t)gr * 128 + col] = __float2bfloat16(h);
      p += fmaxf(h, 0.f) * ps[col];
    }
    p += __shfl_down(p, 8, 16);
    p += __shfl_down(p, 4, 16);
    p += __shfl_down(p, 2, 16);
    p += __shfl_down(p, 1, 16);
    if (l16 == 0 && gr < N_NODES) {
      float sc = tanhf(p * inv_norm);
      score[gr] = sc;
      u32 u = __float_as_uint(sc);
      u = (u & 0x80000000u) ? ~u : (u | 0x80000000u);
      keys[gr] = (((u64)u) << 16) | (u64)(0xFFFFu - (u32)gr);
    }
  }
}

// Y[M,64] = (relu?)X[M,128] @ W[128,64]; M multiple of 64
// kept!=null: X row = kept[row], apply relu*score[kept[row]] (fused TopK hp)
// prescale!=null: Y row *= prescale[row] (dis2, for gather-consumed outputs)
__global__ void gemm_128_64_kernel(const bf16* __restrict__ X, const void* __restrict__ W,
                                   bf16* __restrict__ Y, const Ctl* __restrict__ ctl,
                                   int M, int relu_x,
                                   const int* __restrict__ kept, const float* __restrict__ score,
                                   const float* __restrict__ prescale)
{
  __shared__ short Xs[64 * 136];
  __shared__ short Wt[64 * 136];
  __shared__ int keptS[64];
  __shared__ float scS[64];
  const bool f32 = ctl->isfp32 != 0;
  const int tid = threadIdx.x;
  const int row0 = blockIdx.x * 64;

  if (kept) {
    for (int i = tid; i < 64; i += 256) {
      int o = kept[row0 + i];
      keptS[i] = o;
      scS[i] = score[o];
    }
  }
  __syncthreads();

  if (!f32) {
    const short8* W8 = (const short8*)W;
    for (int i = tid; i < 1024; i += 256) {       // 128x64 shorts = 1024 short8
      int k = i >> 3, nb = i & 7;
      short8 v = W8[i];
      #pragma unroll
      for (int j = 0; j < 8; ++j) Wt[(nb * 8 + j) * 136 + k] = v[j];
    }
  } else {
    for (int i = tid; i < 128 * 64; i += 256) {
      int k = i >> 6, n = i & 63;
      Wt[n * 136 + k] = f2bf_bits(((const float*)W)[i]);
    }
  }
  const u32* X2 = (const u32*)X;
  for (int p = tid; p < 64 * 64; p += 256) {
    int r = p >> 6, kp = p & 63;
    int srow = kept ? keptS[r] : (row0 + r);
    u32 v = X2[(size_t)srow * 64 + kp];
    if (relu_x) {
      if (v & 0x8000u) v &= 0xFFFF0000u;
      if (v & 0x80000000u) v &= 0x0000FFFFu;
    }
    if (kept) {
      bf16x2 h = *(bf16x2*)&v;
      float s = scS[r];
      bf16x2 o;
      o.x = __float2bfloat16(fmaxf(bf2f(h.x), 0.f) * s);
      o.y = __float2bfloat16(fmaxf(bf2f(h.y), 0.f) * s);
      v = *(u32*)&o;
    }
    *(u32*)&Xs[r * 136 + 2 * kp] = v;
  }
  __syncthreads();

  const int lane = tid & 63;
  const int w = tid >> 6;
  const int l16 = lane & 15;
  const int quad = lane >> 4;
  f32x4 acc[4];
  #pragma unroll
  for (int ct = 0; ct < 4; ++ct) acc[ct] = (f32x4){0.f, 0.f, 0.f, 0.f};
  const int arow = w * 16 + l16;
  #pragma unroll
  for (int kc = 0; kc < 4; ++kc) {
    short8 a = *(short8*)&Xs[arow * 136 + kc * 32 + quad * 8];
    #pragma unroll
    for (int ct = 0; ct < 4; ++ct) {
      short8 bb = *(short8*)&Wt[(ct * 16 + l16) * 136 + kc * 32 + quad * 8];
      acc[ct] = __builtin_amdgcn_mfma_f32_16x16x32_bf16(a, bb, acc[ct], 0, 0, 0);
    }
  }
  #pragma unroll
  for (int ct = 0; ct < 4; ++ct)
    #pragma unroll
    for (int r = 0; r < 4; ++r) {
      int gr = row0 + w * 16 + quad * 4 + r;
      float val = acc[ct][r];
      if (prescale) val *= prescale[gr];
      Y[(size_t)gr * 64 + ct * 16 + l16] = __float2bfloat16(val);
    }
}

// conv3 FUSED (R19): gather(P2, graph2) -> LDS -> h3 = G @ W3 + b3, then
// weighted-sum epilogue into partial[ch][bid&127] via per-channel global atomicAdd.
// h3 never hits global memory; wgt = dis2·cvec.
__global__ void gemm_64_128_kernel(const bf16* __restrict__ P2,
                                   const int* __restrict__ rowstart, const int* __restrict__ len,
                                   const int* __restrict__ csr, const float* __restrict__ dis,
                                   const void* __restrict__ W, const void* __restrict__ b,
                                   const float* __restrict__ cvec,
                                   float* __restrict__ partial,
                                   const Ctl* __restrict__ ctl, int M)
{
  __shared__ short Xs[64 * 72];
  __shared__ short Wt[128 * 72];
  __shared__ float bs[128];
  __shared__ float wgtS[64];
  __shared__ float cs[128];
  const bool f32 = ctl->isfp32 != 0;
  const int tid = threadIdx.x;
  const int row0 = blockIdx.x * 64;

  if (tid < 128) cs[tid] = 0.f;
  if (tid < 64) {
    int gr = row0 + tid;
    wgtS[tid] = dis[gr] * cvec[gr];
  }
  if (!f32) {
    const short8* W8 = (const short8*)W;
    for (int i = tid; i < 1024; i += 256) {       // 64x128 shorts = 1024 short8
      int k = i >> 4, nb = i & 15;
      short8 v = W8[i];
      #pragma unroll
      for (int j = 0; j < 8; ++j) Wt[(nb * 8 + j) * 72 + k] = v[j];
    }
  } else {
    for (int i = tid; i < 64 * 128; i += 256) {
      int k = i >> 7, n = i & 127;
      Wt[n * 72 + k] = f2bf_bits(((const float*)W)[i]);
    }
  }
  // fused gather (relu baked into P2 at conv2 write)
  {
    const ushort8* H = (const ushort8*)P2;
    for (int u = tid; u < 512; u += 256) {
      int r = u >> 3, lane = u & 7;
      int d = row0 + r;           // M multiple of 64 -> always < M
      float acc[8];
      gather_row8_pre(H, d, lane, rowstart, len, csr, acc);
      float dd = dis[d];
      short8 outv;
      #pragma unroll
      for (int c = 0; c < 8; ++c) outv[c] = f2bf_bits(acc[c] * dd);
      *(short8*)&Xs[r * 72 + lane * 8] = outv;
    }
  }
  for (int i = tid; i < 128; i += 256) bs[i] = loadF(b, i, f32);
  __syncthreads();

  const int lane = tid & 63;
  const int w = tid >> 6;
  const int l16 = lane & 15;
  const int quad = lane >> 4;
  f32x4 acc[8];
  #pragma unroll
  for (int ct = 0; ct < 8; ++ct) acc[ct] = (f32x4){0.f, 0.f, 0.f, 0.f};
  const int arow = w * 16 + l16;
  #pragma unroll
  for (int kc = 0; kc < 2; ++kc) {
    short8 a = *(short8*)&Xs[arow * 72 + kc * 32 + quad * 8];
    #pragma unroll
    for (int ct = 0; ct < 8; ++ct) {
      short8 bb = *(short8*)&Wt[(ct * 16 + l16) * 72 + kc * 32 + quad * 8];
      acc[ct] = __builtin_amdgcn_mfma_f32_16x16x32_bf16(a, bb, acc[ct], 0, 0, 0);
    }
  }
  // weighted-sum epilogue: per thread 8 cols x 4 rows; row-sum then one LDS atomic/col
  #pragma unroll
  for (int ct = 0; ct < 8; ++ct) {
    int col = ct * 16 + l16;
    float s = 0.f;
    #pragma unroll
    for (int r = 0; r < 4; ++r) {
      int lr = w * 16 + quad * 4 + r;
      float h = acc[ct][r] + bs[col];
      float hb = bfbits2f((u16)f2bf_bits(h));   // keep R16 numerics (bf16 round)
      s += fmaxf(hb, 0.f) * wgtS[lr];
    }
    atomicAdd(&cs[col], s);
  }
  __syncthreads();
  if (tid < 128)
    atomicAdd(&partial[(size_t)tid * 128 + (blockIdx.x & 127)], cs[tid]);
}

// R15-proven final reduce (nblk=128) + matvec (512 threads, LDS trees)
__global__ void final_out_kernel(const float* __restrict__ partial, const void* __restrict__ W4,
                                 const void* __restrict__ b4, const Ctl* __restrict__ ctl,
                                 void* __restrict__ out)
{
  __shared__ float red[512];
  __shared__ float S[128];
  const int tid = threadIdx.x;
  // stage 1: sum partials; 4 threads/channel, 32 entries each (nblk = 128)
  {
    const int ch = tid >> 2, chunk = tid & 3;
    float s = 0.f;
    const float* p = partial + (size_t)ch * 128 + chunk * 32;
    for (int j = 0; j < 32; j += 4)
      s += (p[j] + p[j + 1]) + (p[j + 2] + p[j + 3]);
    red[tid] = s;
  }
  __syncthreads();
  if (tid < 128) S[tid] = (red[4 * tid] + red[4 * tid + 1]) + (red[4 * tid + 2] + red[4 * tid + 3]);
  __syncthreads();
  // stage 2: matvec out[c] = sum_k S[k]*W4[k][c]; 8 threads/output, 16 k each
  {
    const bool f32 = ctl->isfp32 != 0;
    const int c = tid >> 3, chunk = tid & 7;
    float o = 0.f;
    #pragma unroll
    for (int j = 0; j < 16; ++j) {
      int k = chunk * 16 + j;
      o += S[k] * loadF(W4, (size_t)k * 64 + c, f32);
    }
    red[tid] = o;
    __syncthreads();
    if (tid < 64) {
      float acc = 0.f;
      #pragma unroll
      for (int j = 0; j < 8; ++j) acc += red[tid * 8 + j];
      float val = acc / (float)K_KEEP + loadF(b4, tid, f32);
      if (f32) ((float*)out)[tid] = val;
      else     ((bf16*)out)[tid] = __float2bfloat16(val);
    }
  }
}

// ------- TopK select: 8-bit x 6 radix hist+pick (R12-proven); fused mark on pass==gen -------

__device__ __forceinline__ void mark_slice(const u64* __restrict__ keys, Ctl* ctl,
                                           int* __restrict__ new_idx, int* __restrict__ kept,
                                           int i)
{
  if (i >= N_NODES) return;
  if (keys[i] >= ctl->prefix) {
    int pos = (int)atomicAdd(&ctl->cnt, 1u);
    new_idx[i] = pos;
    kept[pos] = i;
  } else {
    new_idx[i] = -1;
  }
}

__global__ void histpick_kernel(const u64* __restrict__ keys, Ctl* ctl, int shift, int pass,
                                int nblocks, int* __restrict__ new_idx, int* __restrict__ kept) {
  __shared__ u32 lh[256];
  __shared__ u32 sfx[256];
  __shared__ int lastflag;
  __shared__ int selsh;
  const int tid = threadIdx.x;
  const u32 g = ctl->gen;
  if (g != 0u) {
    // resolved at pass (g-1); pass q==g performs the fused marking, later passes no-op
    if ((u32)pass == g)
      mark_slice(keys, ctl, new_idx, kept, blockIdx.x * 256 + tid);
    return;
  }
  lh[tid] = 0;
  __syncthreads();
  u64 prefix = ctl->prefix;
  int i = blockIdx.x * 256 + tid;
  if (i < N_NODES) {
    u64 key = keys[i];
    if ((key >> (shift + 8)) == (prefix >> (shift + 8)))
      atomicAdd(&lh[(u32)((key >> shift) & 0xFF)], 1u);
  }
  __syncthreads();
  u32 c = lh[tid];
  if (c) atomicAdd(&ctl->hist[tid], c);
  __syncthreads();
  if (tid == 0) {
    __threadfence();
    u32 old = atomicAdd(&ctl->done, 1u);
    lastflag = (old == (u32)(nblocks - 1));
  }
  __syncthreads();
  if (!lastflag) return;
  // last block: parallel pick via suffix scan
  u32 cc = atomicExch(&ctl->hist[tid], 0u);   // coherent read + zero for next pass
  sfx[tid] = cc;
  __syncthreads();
  for (int off = 1; off < 256; off <<= 1) {
    u32 t = (tid + off < 256) ? sfx[tid + off] : 0u;
    __syncthreads();
    sfx[tid] += t;
    __syncthreads();
  }
  u32 kr = ctl->kremain;
  u32 above = (tid < 255) ? sfx[tid + 1] : 0u;
  if (sfx[tid] >= kr && above < kr) selsh = tid;   // unique (sfx non-increasing)
  __syncthreads();
  if (tid == 0) {
    int sel = selsh;
    u32 ab = (sel < 255) ? sfx[sel + 1] : 0u;
    u32 newkr = kr - ab;
    u32 bucketcnt = sfx[sel] - ab;
    ctl->kremain = newkr;
    ctl->prefix = prefix | (((u64)(u32)sel) << shift);
    if (newkr == bucketcnt) ctl->gen = (u32)(pass + 1);  // resolved; pass+1 marks
    ctl->done = 0u;
  }
}

// fallback mark: only runs if not already marked by a fused pass (gen==0 or gen==6)
__global__ void mark_kernel(const u64* __restrict__ keys, Ctl* ctl,
                            int* __restrict__ new_idx, int* __restrict__ kept)
{
  u32 g = ctl->gen;
  if (g >= 1u && g <= 5u) return;   // marked by histpick pass q==g
  mark_slice(keys, ctl, new_idx, kept, blockIdx.x * 256 + (int)threadIdx.x);
}

// ------- CSR2 (R16-proven): one thread/row; ILP-8 count, ILP-4 fill; cvec self term -------

__global__ void csr2_build_kernel(const int* __restrict__ kept, const int* __restrict__ rowstart1,
                                  const int* __restrict__ csr1, const int* __restrict__ new_idx,
                                  Ctl* ctl, int* __restrict__ rowstart2, int* __restrict__ len2,
                                  float* __restrict__ dis2, int* __restrict__ csr2,
                                  float* __restrict__ cvec)
{
  int kp = blockIdx.x * 256 + threadIdx.x;
  int lane = threadIdx.x & 63;
  int c = 0;
  int i0 = 0, i1 = 0;
  if (kp < K_KEEP) {
    int o = kept[kp];
    i0 = rowstart1[o]; i1 = rowstart1[o + 1];
    int i = i0;
    for (; i + 8 <= i1; i += 8) {
      int s0 = csr1[i],     s1 = csr1[i + 1], s2 = csr1[i + 2], s3 = csr1[i + 3];
      int s4 = csr1[i + 4], s5 = csr1[i + 5], s6 = csr1[i + 6], s7 = csr1[i + 7];
      c += (new_idx[s0] >= 0) + (new_idx[s1] >= 0) + (new_idx[s2] >= 0) + (new_idx[s3] >= 0)
         + (new_idx[s4] >= 0) + (new_idx[s5] >= 0) + (new_idx[s6] >= 0) + (new_idx[s7] >= 0);
    }
    for (; i < i1; ++i) c += (new_idx[csr1[i]] >= 0);
  }
  // wave inclusive scan of c
  int pre = c;
  #pragma unroll
  for (int off = 1; off < 64; off <<= 1) {
    int t = __shfl_up(pre, off);
    if (lane >= off) pre += t;
  }
  int wtot = __shfl(pre, 63);
  int wbase = 0;
  if (lane == 0) wbase = (int)atomicAdd(&ctl->pad, (u32)wtot);
  wbase = __shfl(wbase, 0);
  int base = wbase + pre - c;
  if (kp < K_KEEP) {
    rowstart2[kp] = base;
    len2[kp] = c;
    float ddv = rsqrtf(1.0f + (float)c);
    dis2[kp] = ddv;
    cvec[kp] = ddv;                            // self term (plain store; unique index)
    int w = base;
    int i = i0;
    for (; i + 4 <= i1; i += 4) {              // ILP-4 fill
      int n0 = new_idx[csr1[i]];
      int n1 = new_idx[csr1[i + 1]];
      int n2 = new_idx[csr1[i + 2]];
      int n3 = new_idx[csr1[i + 3]];
      if (n0 >= 0) csr2[w++] = n0;
      if (n1 >= 0) csr2[w++] = n1;
      if (n2 >= 0) csr2[w++] = n2;
      if (n3 >= 0) csr2[w++] = n3;
    }
    for (; i < i1; ++i) {
      int ns = new_idx[csr1[i]];
      if (ns >= 0) csr2[w++] = ns;
    }
  }
}

// ---------------- launch ----------------

extern "C" void kernel_launch(void* const* d_in, const int* in_sizes, int n_in,
                              void* d_out, int out_size, void* d_ws, size_t ws_size,
                              hipStream_t stream)
{
  const void* x  = d_in[0];
  const int*  ei = (const int*)d_in[1];
  const void* W1 = d_in[3];
  const void* b1 = d_in[4];
  const void* pw = d_in[5];
  const void* W2 = d_in[6];
  const void* b2 = d_in[7];
  const void* W3 = d_in[8];
  const void* b3 = d_in[9];
  const void* W4 = d_in[10];
  const void* b4 = d_in[11];

  const int* src = ei;
  const int* dst = ei + N_EDGES;

  float* F = (float*)d_ws;
  bf16*  A16       = (bf16*)F;               // N x 128 bf16 (conv2 output)
  bf16*  B16       = (bf16*)(F + 3200000);   // N x 128 bf16
  bf16*  C16       = (bf16*)(F + 6400000);   // K x 128 bf16
  u32*   xbf       = (u32*)(F + 9000000);    // N x 32 u32 (xbf = dis1*x as bf16 pairs)
  float* dis1      = F + 10600000;           // 50000
  float* dis2      = F + 10650000;           // 40000
  float* score     = F + 10690000;           // 50000
  u64*   keys      = (u64*)(F + 10740000);   // 50000 u64
  int*   new_idx   = (int*)(F + 10840000);   // 50000
  int*   kept      = (int*)(F + 10890000);   // 40000
  int*   len2      = (int*)(F + 10930000);   // 40000
  int*   rowstart1 = (int*)(F + 10970000);   // 50001
  int*   rowstart2 = (int*)(F + 11020004);   // 40000
  int*   csr1      = (int*)(F + 11060008);   // 800000
  int*   csr2      = (int*)(F + 11860008);   // 800000
  Ctl*   ctl       = (Ctl*)(F + 12660008);   // ~1.1 KB
  int*   detcnt    = (int*)(F + 12660856);   // 64
  int*   bucket_cur= (int*)(F + 12660920);   // 196
  float* cvec      = F + 12665216;           // 40000 (reverse weights)
  u32*   bucketbuf = (u32*)(F + 12726908);   // 196*6144
  float* partial   = F + 13931132;           // 128 x 128

  const int NB1 = (N_NODES + 255) / 256;     // 196
  const int EB2 = (N_EDGES + 2047) / 2048;   // 391
  const int GB1 = (N_NODES + 63) / 64;       // 782
  const int WBK = K_KEEP / 4;                // 10000 (wave-per-node)
  const int CB2 = (K_KEEP + 255) / 256;      // 157
  const int GB3 = K_KEEP / 64;               // 625 (conv3 blocks)

  init_kernel<<<NB1, 256, 0, stream>>>((const unsigned short*)x, bucket_cur, detcnt, ctl,
                                       cvec, partial);

  // CSR graph 1 via bucket sort (+fused dtype/norm)
  bucket_scatter_kernel<<<EB2, 256, 0, stream>>>(src, dst, bucket_cur, bucketbuf,
                                                 detcnt, pw, ctl);
  // CSR1 build + fused xbf = dis1*x prescale-convert
  csr_from_buckets_kernel<<<BKT, 256, 0, stream>>>(bucketbuf, bucket_cur, rowstart1, dis1, csr1,
                                                   x, (ushort8*)xbf, ctl);

  // conv1 FUSED: gather(xbf) -> LDS -> h1 = G @ W1 + b1 (+fused score/keys)
  gemm_in_kernel<<<GB1, 256, 0, stream>>>((const ushort8*)xbf, rowstart1, csr1, dis1,
                                          W1, b1, pw, B16, ctl, score, keys);

  // top-K select (6 x 8-bit radix; early-exit; first post-resolution pass marks)
  for (int p = 0; p < 6; ++p)
    histpick_kernel<<<NB1, 256, 0, stream>>>(keys, ctl, 40 - 8 * p, p, NB1, new_idx, kept);
  mark_kernel<<<NB1, 256, 0, stream>>>(keys, ctl, new_idx, kept);

  // CSR graph 2 (R16-proven; cvec self-term; reverse weights fused into gather_h2)
  csr2_build_kernel<<<CB2, 256, 0, stream>>>(kept, rowstart1, csr1, new_idx, ctl,
                                             rowstart2, len2, dis2, csr2, cvec);

  // conv2: A = dis2*(hp @ W2) ; P2 = dis2*relu(dd*sum(A) + b2)  [+fused cvec scatter]
  gemm_128_64_kernel<<<K_KEEP / 64, 256, 0, stream>>>(B16, W2, A16, ctl, K_KEEP, 0, kept, score, dis2);
  gather_h2_kernel<<<WBK, 256, 0, stream>>>(A16, rowstart2, len2, csr2, dis2, b2, ctl, C16, cvec, K_KEEP);

  // conv3 FUSED + weighted-sum epilogue (h3 never materialized; partial[128x128])
  gemm_64_128_kernel<<<GB3, 256, 0, stream>>>(C16, rowstart2, len2, csr2, dis2,
                                              W3, b3, cvec, partial, ctl, K_KEEP);

  // out = S@W4/K + b4 (proven nblk=128 parallel reduce)
  final_out_kernel<<<1, 512, 0, stream>>>(partial, W4, b4, ctl, d_out);
}

// Round 20
// 270.172 us; speedup vs baseline: 1.4285x; 1.0254x over previous
//
#include <hip/hip_runtime.h>
#include <hip/hip_bf16.h>
#include <stdint.h>

#define N_NODES 50000
#define N_EDGES 800000
#define K_KEEP  40000
#define BKT     196        // ceil(N_NODES/256) dst-range buckets
#define BCAP    6144       // per-bucket capacity (mean 4081, +32 sigma)
#define RSTRIDE 128        // per-row csr2 slot stride (Poisson(16) deg>128 ~ 1e-60)

typedef unsigned long long u64;
typedef unsigned int u32;
typedef unsigned short u16;
typedef __hip_bfloat16 bf16;
typedef __hip_bfloat162 bf16x2;
typedef __attribute__((ext_vector_type(8))) short short8;
typedef __attribute__((ext_vector_type(8))) unsigned short ushort8;
typedef __attribute__((ext_vector_type(4))) float f32x4;

struct Ctl {
  u64 prefix;
  u32 kremain;
  u32 cnt;
  float inv_norm;
  u32 isfp32;
  u32 done;         // radix pass arrival counter (reset by picker each pass)
  u32 pad;          // (unused; layout keep)
  u32 gen;          // 0 = unresolved; else (resolution pass + 1); pass==gen does marking
  u32 done2;        // (unused; layout keep)
  u32 hist[256];    // radix histogram (LDS-aggregated flushes only)
};

__device__ __forceinline__ float bf2f(bf16 v) { return __bfloat162float(v); }
__device__ __forceinline__ float bfbits2f(unsigned short u) {
  return __uint_as_float(((u32)u) << 16);
}
__device__ __forceinline__ float loadF(const void* p, size_t i, bool f32) {
  return f32 ? ((const float*)p)[i] : bf2f(((const bf16*)p)[i]);
}
__device__ __forceinline__ short f2bf_bits(float f) {
  bf16 t = __float2bfloat16(f);
  return *(const short*)&t;
}

// Prescaled gather (R9) with ILP-8 (R11), 8-lanes/node layout (used inside fused GEMMs)
__device__ __forceinline__ void gather_row8_pre(const ushort8* __restrict__ H, int d, int lane,
                                                const int* __restrict__ rowstart,
                                                const int* __restrict__ len,
                                                const int* __restrict__ csr,
                                                float* acc)
{
  ushort8 v = H[(size_t)d * 8 + lane];
  #pragma unroll
  for (int c = 0; c < 8; ++c) acc[c] = bfbits2f(v[c]);
  int i = rowstart[d];
  int i1 = len ? (i + len[d]) : rowstart[d + 1];
  for (; i + 8 <= i1; i += 8) {
    int s0 = csr[i],     s1 = csr[i + 1], s2 = csr[i + 2], s3 = csr[i + 3];
    int s4 = csr[i + 4], s5 = csr[i + 5], s6 = csr[i + 6], s7 = csr[i + 7];
    ushort8 v0 = H[(size_t)s0 * 8 + lane];
    ushort8 v1 = H[(size_t)s1 * 8 + lane];
    ushort8 v2 = H[(size_t)s2 * 8 + lane];
    ushort8 v3 = H[(size_t)s3 * 8 + lane];
    ushort8 v4 = H[(size_t)s4 * 8 + lane];
    ushort8 v5 = H[(size_t)s5 * 8 + lane];
    ushort8 v6 = H[(size_t)s6 * 8 + lane];
    ushort8 v7 = H[(size_t)s7 * 8 + lane];
    #pragma unroll
    for (int c = 0; c < 8; ++c) {
      acc[c] += (bfbits2f(v0[c]) + bfbits2f(v1[c]))
              + (bfbits2f(v2[c]) + bfbits2f(v3[c]));
      acc[c] += (bfbits2f(v4[c]) + bfbits2f(v5[c]))
              + (bfbits2f(v6[c]) + bfbits2f(v7[c]));
    }
  }
  for (; i + 4 <= i1; i += 4) {
    int s0 = csr[i], s1 = csr[i + 1], s2 = csr[i + 2], s3 = csr[i + 3];
    ushort8 v0 = H[(size_t)s0 * 8 + lane];
    ushort8 v1 = H[(size_t)s1 * 8 + lane];
    ushort8 v2 = H[(size_t)s2 * 8 + lane];
    ushort8 v3 = H[(size_t)s3 * 8 + lane];
    #pragma unroll
    for (int c = 0; c < 8; ++c) {
      acc[c] += (bfbits2f(v0[c]) + bfbits2f(v1[c]))
              + (bfbits2f(v2[c]) + bfbits2f(v3[c]));
    }
  }
  for (; i < i1; ++i) {
    int s = csr[i];
    ushort8 vv = H[(size_t)s * 8 + lane];
    #pragma unroll
    for (int c = 0; c < 8; ++c) acc[c] += bfbits2f(vv[c]);
  }
}

// R12 wave-per-node gather core with optional reverse-weight scatter (R16):
// slot = lane>>3 walks edges stride-8; unit = lane&7 reads contiguous 128B rows.
// cvec!=null: unit==0 lane fires atomicAdd(&cvec[s], dd) per edge (hidden under load latency).
__device__ __forceinline__ void gather_wave_partial(const ushort8* __restrict__ H, int d,
                                                    int slot, int unit,
                                                    const int* __restrict__ rowstart,
                                                    const int* __restrict__ len,
                                                    const int* __restrict__ csr,
                                                    float* acc,
                                                    float* __restrict__ cvec, float dd)
{
  #pragma unroll
  for (int c = 0; c < 8; ++c) acc[c] = 0.f;
  if (slot == 0) {
    ushort8 v = H[(size_t)d * 8 + unit];
    #pragma unroll
    for (int c = 0; c < 8; ++c) acc[c] = bfbits2f(v[c]);
  }
  int i0 = rowstart[d];
  int i1 = i0 + len[d];
  int i = i0 + slot;
  for (; i + 8 < i1; i += 16) {
    int sa = csr[i], sb = csr[i + 8];
    if (cvec && unit == 0) {
      atomicAdd(&cvec[sa], dd);
      atomicAdd(&cvec[sb], dd);
    }
    ushort8 va = H[(size_t)sa * 8 + unit];
    ushort8 vb = H[(size_t)sb * 8 + unit];
    #pragma unroll
    for (int c = 0; c < 8; ++c) acc[c] += bfbits2f(va[c]) + bfbits2f(vb[c]);
  }
  if (i < i1) {
    int s = csr[i];
    if (cvec && unit == 0) atomicAdd(&cvec[s], dd);
    ushort8 vv = H[(size_t)s * 8 + unit];
    #pragma unroll
    for (int c = 0; c < 8; ++c) acc[c] += bfbits2f(vv[c]);
  }
}

// ---------------- init (+parallel dtype detect, proven R5-R8) ----------------

__global__ void init_kernel(const unsigned short* __restrict__ x16,
                            int* __restrict__ bucket_cur, int* __restrict__ detcnt,
                            Ctl* ctl, float* __restrict__ cvec, float* __restrict__ partial) {
  __shared__ u32 dsh[256];
  int i = blockIdx.x * 256 + threadIdx.x;
  if (i < BKT) bucket_cur[i] = i * BCAP;
  if (i < K_KEEP) cvec[i] = 0.f;
  if (i < 128 * 128) partial[i] = 0.f;
  if (blockIdx.x == 0) {
    ctl->hist[threadIdx.x] = 0u;
    if (threadIdx.x == 0) {
      ctl->prefix = 0ull; ctl->kremain = K_KEEP; ctl->cnt = 0u;
      ctl->done = 0u; ctl->pad = 0u; ctl->gen = 0u; ctl->done2 = 0u;
    }
  }
  if (blockIdx.x < 64) {
    int base = blockIdx.x * 2048;
    u32 c = 0;
    for (int j = threadIdx.x; j < 2048; j += 256) {
      u32 h = x16[base + j];
      if ((h & 0x7F80u) == 0x7F80u) c++;
    }
    dsh[threadIdx.x] = c;
    __syncthreads();
    for (int s = 128; s > 0; s >>= 1) {
      if (threadIdx.x < s) dsh[threadIdx.x] += dsh[threadIdx.x + s];
      __syncthreads();
    }
    if (threadIdx.x == 0) detcnt[blockIdx.x] = (int)dsh[0];
  }
}

// ------- CSR1 bucket scatter (int4 edge loads, R13) + fused dtype/norm -------

__global__ void bucket_scatter_kernel(const int* __restrict__ src, const int* __restrict__ dst,
                                      int* __restrict__ bucket_cur, u32* __restrict__ bucketbuf,
                                      const int* __restrict__ detcnt, const void* __restrict__ pw,
                                      Ctl* ctl)
{
  __shared__ u32 hist[BKT];
  __shared__ u32 base[BKT];
  __shared__ int f32sh;
  __shared__ float ns[128];
  const int tid = threadIdx.x;
  const int e0 = blockIdx.x * 2048;

  // dtype detect from detcnt (written by init, prior dispatch)
  if (tid < 64) {
    int dc = detcnt[tid];
    for (int off = 32; off; off >>= 1) dc += __shfl_down(dc, off);
    if (tid == 0) f32sh = (dc >= 16) ? 1 : 0;
  }
  for (int t = tid; t < BKT; t += 256) hist[t] = 0;
  __syncthreads();
  const bool f32in = f32sh != 0;

  // 8 contiguous edges/thread via int4 loads (fast path when block fully in range)
  int dreg[8], sreg[8];
  const int eb = e0 + tid * 8;
  if (e0 + 2048 <= N_EDGES) {
    const int4* d4 = (const int4*)(dst + eb);
    const int4* s4 = (const int4*)(src + eb);
    int4 da = d4[0], db = d4[1];
    int4 sa = s4[0], sb = s4[1];
    dreg[0] = da.x; dreg[1] = da.y; dreg[2] = da.z; dreg[3] = da.w;
    dreg[4] = db.x; dreg[5] = db.y; dreg[6] = db.z; dreg[7] = db.w;
    sreg[0] = sa.x; sreg[1] = sa.y; sreg[2] = sa.z; sreg[3] = sa.w;
    sreg[4] = sb.x; sreg[5] = sb.y; sreg[6] = sb.z; sreg[7] = sb.w;
  } else {
    #pragma unroll
    for (int j = 0; j < 8; ++j) {
      int e = eb + j;
      if (e < N_EDGES) { dreg[j] = dst[e]; sreg[j] = src[e]; }
      else             { dreg[j] = -1;     sreg[j] = 0;      }
    }
  }
  #pragma unroll
  for (int j = 0; j < 8; ++j)
    if (dreg[j] >= 0) atomicAdd(&hist[dreg[j] >> 8], 1u);
  __syncthreads();
  for (int t = tid; t < BKT; t += 256) {
    u32 c = hist[t];
    base[t] = c ? (u32)atomicAdd(&bucket_cur[t], (int)c) : 0u;
    hist[t] = 0;
  }
  __syncthreads();
  #pragma unroll
  for (int j = 0; j < 8; ++j) {
    if (dreg[j] >= 0) {
      int d = dreg[j];
      int b = d >> 8;
      u32 pos = base[b] + atomicAdd(&hist[b], 1u);
      bucketbuf[pos] = ((u32)sreg[j] << 8) | (u32)(d & 255);
    }
  }
  // fused norm: block 0 computes inv_norm + publishes isfp32
  if (blockIdx.x == 0) {
    if (tid < 128) { float v = loadF(pw, tid, f32in); ns[tid] = v * v; }
    __syncthreads();
    for (int s = 64; s > 0; s >>= 1) {
      if (tid < s) ns[tid] += ns[tid + s];
      __syncthreads();
    }
    if (tid == 0) {
      ctl->inv_norm = 1.0f / sqrtf(ns[0]);
      ctl->isfp32 = f32in ? 1u : 0u;
    }
  }
}

// ------- CSR1 from buckets (inline bucket scan) + fused x -> xbf = dis1*x (bf16) -------

__global__ void csr_from_buckets_kernel(const u32* __restrict__ bucketbuf, const int* __restrict__ bucket_cur,
                                        int* __restrict__ rowstart, float* __restrict__ dis,
                                        int* __restrict__ csr,
                                        const void* __restrict__ x, ushort8* __restrict__ xbf,
                                        const Ctl* __restrict__ ctl)
{
  __shared__ u32 cnt[256];
  __shared__ u32 loc[256];
  __shared__ u32 cur[256];
  __shared__ float disS[256];
  const int b = blockIdx.x;
  const int tid = threadIdx.x;

  // inline scan of all bucket sizes -> off0 for this bucket
  int v = (tid < BKT) ? (bucket_cur[tid] - tid * BCAP) : 0;
  loc[tid] = (u32)v;
  __syncthreads();
  for (int off = 1; off < 256; off <<= 1) {
    u32 t = (tid >= off) ? loc[tid - off] : 0;
    __syncthreads();
    loc[tid] += t;
    __syncthreads();
  }
  const int bc = bucket_cur[b] - b * BCAP;
  const int off0 = (int)loc[b] - bc;
  if (b == BKT - 1 && tid == 0) rowstart[N_NODES] = (int)loc[BKT - 1];
  __syncthreads();

  const u32* buf = bucketbuf + (size_t)b * BCAP;
  cnt[tid] = 0;
  __syncthreads();
  for (int i = tid; i < bc; i += 256) atomicAdd(&cnt[buf[i] & 255u], 1u);
  __syncthreads();
  u32 c = cnt[tid];
  loc[tid] = c;
  __syncthreads();
  for (int off = 1; off < 256; off <<= 1) {
    u32 t = (tid >= off) ? loc[tid - off] : 0;
    __syncthreads();
    loc[tid] += t;
    __syncthreads();
  }
  int node = b * 256 + tid;
  u32 excl = loc[tid] - c;
  float ddv = rsqrtf(1.0f + (float)c);
  disS[tid] = ddv;
  if (node < N_NODES) {
    rowstart[node] = off0 + (int)excl;
    dis[node] = ddv;
  }
  cur[tid] = off0 + excl;
  __syncthreads();
  for (int i = tid; i < bc; i += 256) {
    u32 p = buf[i];
    u32 pos = atomicAdd(&cur[p & 255u], 1u);
    csr[pos] = (int)(p >> 8);
  }
  // fused prescaled conversion: xbf[node] = bf16(dis1[node] * x[node]), 64 ch
  {
    const bool f32in = ctl->isfp32 != 0;
    if (f32in) {
      const float* xf = (const float*)x;
      for (int u = tid; u < 2048; u += 256) {
        int r = u >> 3, lane = u & 7;
        int d = b * 256 + r;
        if (d < N_NODES) {
          float sc = disS[r];
          ushort8 o;
          #pragma unroll
          for (int c2 = 0; c2 < 8; ++c2)
            o[c2] = (u16)f2bf_bits(xf[(size_t)d * 64 + lane * 8 + c2] * sc);
          xbf[(size_t)d * 8 + lane] = o;
        }
      }
    } else {
      const ushort8* xi = (const ushort8*)x;
      for (int u = tid; u < 2048; u += 256) {
        int r = u >> 3, lane = u & 7;
        int d = b * 256 + r;
        if (d < N_NODES) {
          float sc = disS[r];
          ushort8 vv = xi[(size_t)d * 8 + lane];
          ushort8 o;
          #pragma unroll
          for (int c2 = 0; c2 < 8; ++c2)
            o[c2] = (u16)f2bf_bits(bfbits2f(vv[c2]) * sc);
          xbf[(size_t)d * 8 + lane] = o;
        }
      }
    }
  }
}

// ------- conv2 gather (R12 wave-per-node) + R16 fused cvec reverse-weight scatter -------

__global__ void gather_h2_kernel(const bf16* __restrict__ P, const int* __restrict__ rowstart,
                                 const int* __restrict__ len, const int* __restrict__ csr,
                                 const float* __restrict__ dis,
                                 const void* __restrict__ b, const Ctl* __restrict__ ctl,
                                 bf16* __restrict__ P2, float* __restrict__ cvec, int M)
{
  const bool f32 = ctl->isfp32 != 0;
  const int tid = threadIdx.x;
  const int d = blockIdx.x * 4 + (tid >> 6);   // one wave per node; grid = M/4 exactly
  const int lane = tid & 63;
  const int slot = lane >> 3, unit = lane & 7;
  const ushort8* H = (const ushort8*)P;
  const float dd = dis[d];
  float acc[8];
  gather_wave_partial(H, d, slot, unit, rowstart, len, csr, acc, cvec, dd);
  // butterfly reduce across slots (same unit): xor 8,16,32
  #pragma unroll
  for (int m = 8; m < 64; m <<= 1)
    #pragma unroll
    for (int c = 0; c < 8; ++c) acc[c] += __shfl_xor(acc[c], m);
  if (slot == 0) {
    ushort8 outv;
    #pragma unroll
    for (int c = 0; c < 8; ++c) {
      float h = acc[c] * dd + loadF(b, 8 * unit + c, f32);
      outv[c] = (u16)f2bf_bits(fmaxf(h, 0.f) * dd);
    }
    ((ushort8*)P2)[(size_t)d * 8 + unit] = outv;
  }
}

// ---------------- MFMA GEMMs (16x16x32 bf16, fp32 acc) ----------------

// conv1 FUSED: gather(xbf prescaled, graph1) -> LDS, then Y = G @ W1 + b1 (+score/keys)
__global__ void gemm_in_kernel(const ushort8* __restrict__ xbf,
                               const int* __restrict__ rowstart, const int* __restrict__ csr,
                               const float* __restrict__ dis,
                               const void* __restrict__ W, const void* __restrict__ b,
                               const void* __restrict__ pw,
                               bf16* __restrict__ Y, const Ctl* __restrict__ ctl,
                               float* __restrict__ score, u64* __restrict__ keys)
{
  __shared__ short Xs[64 * 72];
  __shared__ short Wt[128 * 72];
  __shared__ float bs[128];
  __shared__ float ps[128];
  const bool f32 = ctl->isfp32 != 0;
  const int tid = threadIdx.x;
  const int row0 = blockIdx.x * 64;

  if (!f32) {
    const short8* W8 = (const short8*)W;
    for (int i = tid; i < 1024; i += 256) {       // 64x128 shorts = 1024 short8
      int k = i >> 4, nb = i & 15;
      short8 v = W8[i];
      #pragma unroll
      for (int j = 0; j < 8; ++j) Wt[(nb * 8 + j) * 72 + k] = v[j];
    }
  } else {
    for (int i = tid; i < 64 * 128; i += 256) {
      int k = i >> 7, n = i & 127;
      Wt[n * 72 + k] = f2bf_bits(((const float*)W)[i]);
    }
  }
  // fused gather: 64 rows x 8 lane-units, 2 units/thread, straight into Xs
  for (int u = tid; u < 512; u += 256) {
    int r = u >> 3, lane = u & 7;
    int d = row0 + r;
    float acc[8];
    short8 outv;
    if (d < N_NODES) {
      gather_row8_pre(xbf, d, lane, rowstart, nullptr, csr, acc);
      float dd = dis[d];
      #pragma unroll
      for (int c = 0; c < 8; ++c) outv[c] = f2bf_bits(acc[c] * dd);
    } else {
      #pragma unroll
      for (int c = 0; c < 8; ++c) outv[c] = 0;
    }
    *(short8*)&Xs[r * 72 + lane * 8] = outv;
  }
  for (int i = tid; i < 128; i += 256) { bs[i] = loadF(b, i, f32); ps[i] = loadF(pw, i, f32); }
  __syncthreads();

  const int lane = tid & 63;
  const int w = tid >> 6;
  const int l16 = lane & 15;
  const int quad = lane >> 4;
  f32x4 acc[8];
  #pragma unroll
  for (int ct = 0; ct < 8; ++ct) acc[ct] = (f32x4){0.f, 0.f, 0.f, 0.f};
  const int arow = w * 16 + l16;
  #pragma unroll
  for (int kc = 0; kc < 2; ++kc) {
    short8 a = *(short8*)&Xs[arow * 72 + kc * 32 + quad * 8];
    #pragma unroll
    for (int ct = 0; ct < 8; ++ct) {
      short8 bb = *(short8*)&Wt[(ct * 16 + l16) * 72 + kc * 32 + quad * 8];
      acc[ct] = __builtin_amdgcn_mfma_f32_16x16x32_bf16(a, bb, acc[ct], 0, 0, 0);
    }
  }
  float inv_norm = ctl->inv_norm;
  #pragma unroll
  for (int r = 0; r < 4; ++r) {
    int gr = row0 + w * 16 + quad * 4 + r;
    float p = 0.f;
    #pragma unroll
    for (int ct = 0; ct < 8; ++ct) {
      int col = ct * 16 + l16;
      float h = acc[ct][r] + bs[col];
      if (gr < N_NODES) Y[(size_t)gr * 128 + col] = __float2bfloat16(h);
      p += fmaxf(h, 0.f) * ps[col];
    }
    p += __shfl_down(p, 8, 16);
    p += __shfl_down(p, 4, 16);
    p += __shfl_down(p, 2, 16);
    p += __shfl_down(p, 1, 16);
    if (l16 == 0 && gr < N_NODES) {
      float sc = tanhf(p * inv_norm);
      score[gr] = sc;
      u32 u = __float_as_uint(sc);
      u = (u & 0x80000000u) ? ~u : (u | 0x80000000u);
      keys[gr] = (((u64)u) << 16) | (u64)(0xFFFFu - (u32)gr);
    }
  }
}

// Y[M,64] = (relu?)X[M,128] @ W[128,64]; M multiple of 64
// kept!=null: X row = kept[row], apply relu*score[kept[row]] (fused TopK hp)
// prescale!=null: Y row *= prescale[row] (dis2, for gather-consumed outputs)
__global__ void gemm_128_64_kernel(const bf16* __restrict__ X, const void* __restrict__ W,
                                   bf16* __restrict__ Y, const Ctl* __restrict__ ctl,
                                   int M, int relu_x,
                                   const int* __restrict__ kept, const float* __restrict__ score,
                                   const float* __restrict__ prescale)
{
  __shared__ short Xs[64 * 136];
  __shared__ short Wt[64 * 136];
  __shared__ int keptS[64];
  __shared__ float scS[64];
  const bool f32 = ctl->isfp32 != 0;
  const int tid = threadIdx.x;
  const int row0 = blockIdx.x * 64;

  if (kept) {
    for (int i = tid; i < 64; i += 256) {
      int o = kept[row0 + i];
      keptS[i] = o;
      scS[i] = score[o];
    }
  }
  __syncthreads();

  if (!f32) {
    const short8* W8 = (const short8*)W;
    for (int i = tid; i < 1024; i += 256) {       // 128x64 shorts = 1024 short8
      int k = i >> 3, nb = i & 7;
      short8 v = W8[i];
      #pragma unroll
      for (int j = 0; j < 8; ++j) Wt[(nb * 8 + j) * 136 + k] = v[j];
    }
  } else {
    for (int i = tid; i < 128 * 64; i += 256) {
      int k = i >> 6, n = i & 63;
      Wt[n * 136 + k] = f2bf_bits(((const float*)W)[i]);
    }
  }
  const u32* X2 = (const u32*)X;
  for (int p = tid; p < 64 * 64; p += 256) {
    int r = p >> 6, kp = p & 63;
    int srow = kept ? keptS[r] : (row0 + r);
    u32 v = X2[(size_t)srow * 64 + kp];
    if (relu_x) {
      if (v & 0x8000u) v &= 0xFFFF0000u;
      if (v & 0x80000000u) v &= 0x0000FFFFu;
    }
    if (kept) {
      bf16x2 h = *(bf16x2*)&v;
      float s = scS[r];
      bf16x2 o;
      o.x = __float2bfloat16(fmaxf(bf2f(h.x), 0.f) * s);
      o.y = __float2bfloat16(fmaxf(bf2f(h.y), 0.f) * s);
      v = *(u32*)&o;
    }
    *(u32*)&Xs[r * 136 + 2 * kp] = v;
  }
  __syncthreads();

  const int lane = tid & 63;
  const int w = tid >> 6;
  const int l16 = lane & 15;
  const int quad = lane >> 4;
  f32x4 acc[4];
  #pragma unroll
  for (int ct = 0; ct < 4; ++ct) acc[ct] = (f32x4){0.f, 0.f, 0.f, 0.f};
  const int arow = w * 16 + l16;
  #pragma unroll
  for (int kc = 0; kc < 4; ++kc) {
    short8 a = *(short8*)&Xs[arow * 136 + kc * 32 + quad * 8];
    #pragma unroll
    for (int ct = 0; ct < 4; ++ct) {
      short8 bb = *(short8*)&Wt[(ct * 16 + l16) * 136 + kc * 32 + quad * 8];
      acc[ct] = __builtin_amdgcn_mfma_f32_16x16x32_bf16(a, bb, acc[ct], 0, 0, 0);
    }
  }
  #pragma unroll
  for (int ct = 0; ct < 4; ++ct)
    #pragma unroll
    for (int r = 0; r < 4; ++r) {
      int gr = row0 + w * 16 + quad * 4 + r;
      float val = acc[ct][r];
      if (prescale) val *= prescale[gr];
      Y[(size_t)gr * 64 + ct * 16 + l16] = __float2bfloat16(val);
    }
}

// conv3 FUSED (R19): gather(P2, graph2) -> LDS -> h3 = G @ W3 + b3, then
// weighted-sum epilogue into partial[ch][bid&127] via per-channel global atomicAdd.
// h3 never hits global memory; wgt = dis2·cvec.
__global__ void gemm_64_128_kernel(const bf16* __restrict__ P2,
                                   const int* __restrict__ rowstart, const int* __restrict__ len,
                                   const int* __restrict__ csr, const float* __restrict__ dis,
                                   const void* __restrict__ W, const void* __restrict__ b,
                                   const float* __restrict__ cvec,
                                   float* __restrict__ partial,
                                   const Ctl* __restrict__ ctl, int M)
{
  __shared__ short Xs[64 * 72];
  __shared__ short Wt[128 * 72];
  __shared__ float bs[128];
  __shared__ float wgtS[64];
  __shared__ float cs[128];
  const bool f32 = ctl->isfp32 != 0;
  const int tid = threadIdx.x;
  const int row0 = blockIdx.x * 64;

  if (tid < 128) cs[tid] = 0.f;
  if (tid < 64) {
    int gr = row0 + tid;
    wgtS[tid] = dis[gr] * cvec[gr];
  }
  if (!f32) {
    const short8* W8 = (const short8*)W;
    for (int i = tid; i < 1024; i += 256) {       // 64x128 shorts = 1024 short8
      int k = i >> 4, nb = i & 15;
      short8 v = W8[i];
      #pragma unroll
      for (int j = 0; j < 8; ++j) Wt[(nb * 8 + j) * 72 + k] = v[j];
    }
  } else {
    for (int i = tid; i < 64 * 128; i += 256) {
      int k = i >> 7, n = i & 127;
      Wt[n * 72 + k] = f2bf_bits(((const float*)W)[i]);
    }
  }
  // fused gather (relu baked into P2 at conv2 write)
  {
    const ushort8* H = (const ushort8*)P2;
    for (int u = tid; u < 512; u += 256) {
      int r = u >> 3, lane = u & 7;
      int d = row0 + r;           // M multiple of 64 -> always < M
      float acc[8];
      gather_row8_pre(H, d, lane, rowstart, len, csr, acc);
      float dd = dis[d];
      short8 outv;
      #pragma unroll
      for (int c = 0; c < 8; ++c) outv[c] = f2bf_bits(acc[c] * dd);
      *(short8*)&Xs[r * 72 + lane * 8] = outv;
    }
  }
  for (int i = tid; i < 128; i += 256) bs[i] = loadF(b, i, f32);
  __syncthreads();

  const int lane = tid & 63;
  const int w = tid >> 6;
  const int l16 = lane & 15;
  const int quad = lane >> 4;
  f32x4 acc[8];
  #pragma unroll
  for (int ct = 0; ct < 8; ++ct) acc[ct] = (f32x4){0.f, 0.f, 0.f, 0.f};
  const int arow = w * 16 + l16;
  #pragma unroll
  for (int kc = 0; kc < 2; ++kc) {
    short8 a = *(short8*)&Xs[arow * 72 + kc * 32 + quad * 8];
    #pragma unroll
    for (int ct = 0; ct < 8; ++ct) {
      short8 bb = *(short8*)&Wt[(ct * 16 + l16) * 72 + kc * 32 + quad * 8];
      acc[ct] = __builtin_amdgcn_mfma_f32_16x16x32_bf16(a, bb, acc[ct], 0, 0, 0);
    }
  }
  // weighted-sum epilogue: per thread 8 cols x 4 rows; row-sum then one LDS atomic/col
  #pragma unroll
  for (int ct = 0; ct < 8; ++ct) {
    int col = ct * 16 + l16;
    float s = 0.f;
    #pragma unroll
    for (int r = 0; r < 4; ++r) {
      int lr = w * 16 + quad * 4 + r;
      float h = acc[ct][r] + bs[col];
      float hb = bfbits2f((u16)f2bf_bits(h));   // keep R16 numerics (bf16 round)
      s += fmaxf(hb, 0.f) * wgtS[lr];
    }
    atomicAdd(&cs[col], s);
  }
  __syncthreads();
  if (tid < 128)
    atomicAdd(&partial[(size_t)tid * 128 + (blockIdx.x & 127)], cs[tid]);
}

// R15-proven final reduce (nblk=128) + matvec (512 threads, LDS trees)
__global__ void final_out_kernel(const float* __restrict__ partial, const void* __restrict__ W4,
                                 const void* __restrict__ b4, const Ctl* __restrict__ ctl,
                                 void* __restrict__ out)
{
  __shared__ float red[512];
  __shared__ float S[128];
  const int tid = threadIdx.x;
  // stage 1: sum partials; 4 threads/channel, 32 entries each (nblk = 128)
  {
    const int ch = tid >> 2, chunk = tid & 3;
    float s = 0.f;
    const float* p = partial + (size_t)ch * 128 + chunk * 32;
    for (int j = 0; j < 32; j += 4)
      s += (p[j] + p[j + 1]) + (p[j + 2] + p[j + 3]);
    red[tid] = s;
  }
  __syncthreads();
  if (tid < 128) S[tid] = (red[4 * tid] + red[4 * tid + 1]) + (red[4 * tid + 2] + red[4 * tid + 3]);
  __syncthreads();
  // stage 2: matvec out[c] = sum_k S[k]*W4[k][c]; 8 threads/output, 16 k each
  {
    const bool f32 = ctl->isfp32 != 0;
    const int c = tid >> 3, chunk = tid & 7;
    float o = 0.f;
    #pragma unroll
    for (int j = 0; j < 16; ++j) {
      int k = chunk * 16 + j;
      o += S[k] * loadF(W4, (size_t)k * 64 + c, f32);
    }
    red[tid] = o;
    __syncthreads();
    if (tid < 64) {
      float acc = 0.f;
      #pragma unroll
      for (int j = 0; j < 8; ++j) acc += red[tid * 8 + j];
      float val = acc / (float)K_KEEP + loadF(b4, tid, f32);
      if (f32) ((float*)out)[tid] = val;
      else     ((bf16*)out)[tid] = __float2bfloat16(val);
    }
  }
}

// ------- TopK select: 8-bit x 6 radix hist+pick (R12-proven); fused mark on pass==gen -------

__device__ __forceinline__ void mark_slice(const u64* __restrict__ keys, Ctl* ctl,
                                           int* __restrict__ new_idx, int* __restrict__ kept,
                                           int i)
{
  if (i >= N_NODES) return;
  if (keys[i] >= ctl->prefix) {
    int pos = (int)atomicAdd(&ctl->cnt, 1u);
    new_idx[i] = pos;
    kept[pos] = i;
  } else {
    new_idx[i] = -1;
  }
}

__global__ void histpick_kernel(const u64* __restrict__ keys, Ctl* ctl, int shift, int pass,
                                int nblocks, int* __restrict__ new_idx, int* __restrict__ kept) {
  __shared__ u32 lh[256];
  __shared__ u32 sfx[256];
  __shared__ int lastflag;
  __shared__ int selsh;
  const int tid = threadIdx.x;
  const u32 g = ctl->gen;
  if (g != 0u) {
    // resolved at pass (g-1); pass q==g performs the fused marking, later passes no-op
    if ((u32)pass == g)
      mark_slice(keys, ctl, new_idx, kept, blockIdx.x * 256 + tid);
    return;
  }
  lh[tid] = 0;
  __syncthreads();
  u64 prefix = ctl->prefix;
  int i = blockIdx.x * 256 + tid;
  if (i < N_NODES) {
    u64 key = keys[i];
    if ((key >> (shift + 8)) == (prefix >> (shift + 8)))
      atomicAdd(&lh[(u32)((key >> shift) & 0xFF)], 1u);
  }
  __syncthreads();
  u32 c = lh[tid];
  if (c) atomicAdd(&ctl->hist[tid], c);
  __syncthreads();
  if (tid == 0) {
    __threadfence();
    u32 old = atomicAdd(&ctl->done, 1u);
    lastflag = (old == (u32)(nblocks - 1));
  }
  __syncthreads();
  if (!lastflag) return;
  // last block: parallel pick via suffix scan
  u32 cc = atomicExch(&ctl->hist[tid], 0u);   // coherent read + zero for next pass
  sfx[tid] = cc;
  __syncthreads();
  for (int off = 1; off < 256; off <<= 1) {
    u32 t = (tid + off < 256) ? sfx[tid + off] : 0u;
    __syncthreads();
    sfx[tid] += t;
    __syncthreads();
  }
  u32 kr = ctl->kremain;
  u32 above = (tid < 255) ? sfx[tid + 1] : 0u;
  if (sfx[tid] >= kr && above < kr) selsh = tid;   // unique (sfx non-increasing)
  __syncthreads();
  if (tid == 0) {
    int sel = selsh;
    u32 ab = (sel < 255) ? sfx[sel + 1] : 0u;
    u32 newkr = kr - ab;
    u32 bucketcnt = sfx[sel] - ab;
    ctl->kremain = newkr;
    ctl->prefix = prefix | (((u64)(u32)sel) << shift);
    if (newkr == bucketcnt) ctl->gen = (u32)(pass + 1);  // resolved; pass+1 marks
    ctl->done = 0u;
  }
}

// fallback mark: only runs if not already marked by a fused pass (gen==0 or gen==6)
__global__ void mark_kernel(const u64* __restrict__ keys, Ctl* ctl,
                            int* __restrict__ new_idx, int* __restrict__ kept)
{
  u32 g = ctl->gen;
  if (g >= 1u && g <= 5u) return;   // marked by histpick pass q==g
  mark_slice(keys, ctl, new_idx, kept, blockIdx.x * 256 + (int)threadIdx.x);
}

// ------- CSR2 (R20): SINGLE-PASS strided fill — one thread/row, base = kp*RSTRIDE -------
// No count pass, no wave scan, no cursor atomic; gathers use rowstart2+len2 (gaps ok).

__global__ void csr2_build_kernel(const int* __restrict__ kept, const int* __restrict__ rowstart1,
                                  const int* __restrict__ csr1, const int* __restrict__ new_idx,
                                  int* __restrict__ rowstart2, int* __restrict__ len2,
                                  float* __restrict__ dis2, int* __restrict__ csr2,
                                  float* __restrict__ cvec)
{
  int kp = blockIdx.x * 256 + threadIdx.x;
  if (kp >= K_KEEP) return;
  int o = kept[kp];
  int i0 = rowstart1[o], i1 = rowstart1[o + 1];
  const int base = kp * RSTRIDE;
  int w = base;
  int i = i0;
  for (; i + 4 <= i1; i += 4) {              // ILP-4 single-pass fill
    int n0 = new_idx[csr1[i]];
    int n1 = new_idx[csr1[i + 1]];
    int n2 = new_idx[csr1[i + 2]];
    int n3 = new_idx[csr1[i + 3]];
    if (n0 >= 0) csr2[w++] = n0;
    if (n1 >= 0) csr2[w++] = n1;
    if (n2 >= 0) csr2[w++] = n2;
    if (n3 >= 0) csr2[w++] = n3;
  }
  for (; i < i1; ++i) {
    int ns = new_idx[csr1[i]];
    if (ns >= 0) csr2[w++] = ns;
  }
  int c = w - base;
  rowstart2[kp] = base;
  len2[kp] = c;
  float ddv = rsqrtf(1.0f + (float)c);
  dis2[kp] = ddv;
  cvec[kp] = ddv;                            // self term (plain store; unique index)
}

// ---------------- launch ----------------

extern "C" void kernel_launch(void* const* d_in, const int* in_sizes, int n_in,
                              void* d_out, int out_size, void* d_ws, size_t ws_size,
                              hipStream_t stream)
{
  const void* x  = d_in[0];
  const int*  ei = (const int*)d_in[1];
  const void* W1 = d_in[3];
  const void* b1 = d_in[4];
  const void* pw = d_in[5];
  const void* W2 = d_in[6];
  const void* b2 = d_in[7];
  const void* W3 = d_in[8];
  const void* b3 = d_in[9];
  const void* W4 = d_in[10];
  const void* b4 = d_in[11];

  const int* src = ei;
  const int* dst = ei + N_EDGES;

  float* F = (float*)d_ws;
  bf16*  A16       = (bf16*)F;               // N x 128 bf16 (conv2 output)
  bf16*  B16       = (bf16*)(F + 3200000);   // N x 128 bf16
  bf16*  C16       = (bf16*)(F + 6400000);   // K x 128 bf16
  u32*   xbf       = (u32*)(F + 9000000);    // N x 32 u32 (xbf = dis1*x as bf16 pairs)
  float* dis1      = F + 10600000;           // 50000
  float* dis2      = F + 10650000;           // 40000
  float* score     = F + 10690000;           // 50000
  u64*   keys      = (u64*)(F + 10740000);   // 50000 u64
  int*   new_idx   = (int*)(F + 10840000);   // 50000
  int*   kept      = (int*)(F + 10890000);   // 40000
  int*   len2      = (int*)(F + 10930000);   // 40000
  int*   rowstart1 = (int*)(F + 10970000);   // 50001
  int*   rowstart2 = (int*)(F + 11020004);   // 40000
  int*   csr1      = (int*)(F + 11060008);   // 800000
  Ctl*   ctl       = (Ctl*)(F + 12660008);   // ~1.1 KB
  int*   detcnt    = (int*)(F + 12660856);   // 64
  int*   bucket_cur= (int*)(F + 12660920);   // 196
  float* cvec      = F + 12665216;           // 40000 (reverse weights)
  u32*   bucketbuf = (u32*)(F + 12726908);   // 196*6144
  float* partial   = F + 13931132;           // 128 x 128
  int*   csr2      = (int*)(F + 14200000);   // 40000 x RSTRIDE strided slots (5.12M ints)

  const int NB1 = (N_NODES + 255) / 256;     // 196
  const int EB2 = (N_EDGES + 2047) / 2048;   // 391
  const int GB1 = (N_NODES + 63) / 64;       // 782
  const int WBK = K_KEEP / 4;                // 10000 (wave-per-node)
  const int CB2 = (K_KEEP + 255) / 256;      // 157
  const int GB3 = K_KEEP / 64;               // 625 (conv3 blocks)

  init_kernel<<<NB1, 256, 0, stream>>>((const unsigned short*)x, bucket_cur, detcnt, ctl,
                                       cvec, partial);

  // CSR graph 1 via bucket sort (+fused dtype/norm)
  bucket_scatter_kernel<<<EB2, 256, 0, stream>>>(src, dst, bucket_cur, bucketbuf,
                                                 detcnt, pw, ctl);
  // CSR1 build + fused xbf = dis1*x prescale-convert
  csr_from_buckets_kernel<<<BKT, 256, 0, stream>>>(bucketbuf, bucket_cur, rowstart1, dis1, csr1,
                                                   x, (ushort8*)xbf, ctl);

  // conv1 FUSED: gather(xbf) -> LDS -> h1 = G @ W1 + b1 (+fused score/keys)
  gemm_in_kernel<<<GB1, 256, 0, stream>>>((const ushort8*)xbf, rowstart1, csr1, dis1,
                                          W1, b1, pw, B16, ctl, score, keys);

  // top-K select (6 x 8-bit radix; early-exit; first post-resolution pass marks)
  for (int p = 0; p < 6; ++p)
    histpick_kernel<<<NB1, 256, 0, stream>>>(keys, ctl, 40 - 8 * p, p, NB1, new_idx, kept);
  mark_kernel<<<NB1, 256, 0, stream>>>(keys, ctl, new_idx, kept);

  // CSR graph 2: SINGLE-PASS strided fill (cvec self-term; reverse weights in gather_h2)
  csr2_build_kernel<<<CB2, 256, 0, stream>>>(kept, rowstart1, csr1, new_idx,
                                             rowstart2, len2, dis2, csr2, cvec);

  // conv2: A = dis2*(hp @ W2) ; P2 = dis2*relu(dd*sum(A) + b2)  [+fused cvec scatter]
  gemm_128_64_kernel<<<K_KEEP / 64, 256, 0, stream>>>(B16, W2, A16, ctl, K_KEEP, 0, kept, score, dis2);
  gather_h2_kernel<<<WBK, 256, 0, stream>>>(A16, rowstart2, len2, csr2, dis2, b2, ctl, C16, cvec, K_KEEP);

  // conv3 FUSED + weighted-sum epilogue (h3 never materialized; partial[128x128])
  gemm_64_128_kernel<<<GB3, 256, 0, stream>>>(C16, rowstart2, len2, csr2, dis2,
                                              W3, b3, cvec, partial, ctl, K_KEEP);

  // out = S@W4/K + b4 (proven nblk=128 parallel reduce)
  final_out_kernel<<<1, 512, 0, stream>>>(partial, W4, b4, ctl, d_out);
}

// Round 21
// 269.389 us; speedup vs baseline: 1.4327x; 1.0029x over previous
//
#include <hip/hip_runtime.h>
#include <hip/hip_bf16.h>
#include <stdint.h>

#define N_NODES 50000
#define N_EDGES 800000
#define K_KEEP  40000
#define BKT     196        // ceil(N_NODES/256) dst-range buckets
#define BCAP    6144       // per-bucket capacity (mean 4081, +32 sigma)
#define RSTRIDE 128        // per-row csr2 slot stride (Poisson(16) deg>128 ~ 1e-60)

typedef unsigned long long u64;
typedef unsigned int u32;
typedef unsigned short u16;
typedef __hip_bfloat16 bf16;
typedef __hip_bfloat162 bf16x2;
typedef __attribute__((ext_vector_type(8))) short short8;
typedef __attribute__((ext_vector_type(8))) unsigned short ushort8;
typedef __attribute__((ext_vector_type(4))) float f32x4;

struct Ctl {
  u64 prefix;
  u32 kremain;
  u32 cnt;
  float inv_norm;
  u32 isfp32;
  u32 done;         // radix pass arrival counter (reset by picker each pass)
  u32 pad;          // (unused; layout keep)
  u32 gen;          // 0 = unresolved; else (resolution pass + 1); pass==gen does marking
  u32 done2;        // (unused; layout keep)
  u32 hist[256];    // radix histogram (LDS-aggregated flushes only)
};

__device__ __forceinline__ float bf2f(bf16 v) { return __bfloat162float(v); }
__device__ __forceinline__ float bfbits2f(unsigned short u) {
  return __uint_as_float(((u32)u) << 16);
}
__device__ __forceinline__ float loadF(const void* p, size_t i, bool f32) {
  return f32 ? ((const float*)p)[i] : bf2f(((const bf16*)p)[i]);
}
__device__ __forceinline__ short f2bf_bits(float f) {
  bf16 t = __float2bfloat16(f);
  return *(const short*)&t;
}

// Prescaled gather (R9) with ILP-8 (R11), 8-lanes/node layout (used inside fused GEMMs)
__device__ __forceinline__ void gather_row8_pre(const ushort8* __restrict__ H, int d, int lane,
                                                const int* __restrict__ rowstart,
                                                const int* __restrict__ len,
                                                const int* __restrict__ csr,
                                                float* acc)
{
  ushort8 v = H[(size_t)d * 8 + lane];
  #pragma unroll
  for (int c = 0; c < 8; ++c) acc[c] = bfbits2f(v[c]);
  int i = rowstart[d];
  int i1 = len ? (i + len[d]) : rowstart[d + 1];
  for (; i + 8 <= i1; i += 8) {
    int s0 = csr[i],     s1 = csr[i + 1], s2 = csr[i + 2], s3 = csr[i + 3];
    int s4 = csr[i + 4], s5 = csr[i + 5], s6 = csr[i + 6], s7 = csr[i + 7];
    ushort8 v0 = H[(size_t)s0 * 8 + lane];
    ushort8 v1 = H[(size_t)s1 * 8 + lane];
    ushort8 v2 = H[(size_t)s2 * 8 + lane];
    ushort8 v3 = H[(size_t)s3 * 8 + lane];
    ushort8 v4 = H[(size_t)s4 * 8 + lane];
    ushort8 v5 = H[(size_t)s5 * 8 + lane];
    ushort8 v6 = H[(size_t)s6 * 8 + lane];
    ushort8 v7 = H[(size_t)s7 * 8 + lane];
    #pragma unroll
    for (int c = 0; c < 8; ++c) {
      acc[c] += (bfbits2f(v0[c]) + bfbits2f(v1[c]))
              + (bfbits2f(v2[c]) + bfbits2f(v3[c]));
      acc[c] += (bfbits2f(v4[c]) + bfbits2f(v5[c]))
              + (bfbits2f(v6[c]) + bfbits2f(v7[c]));
    }
  }
  for (; i + 4 <= i1; i += 4) {
    int s0 = csr[i], s1 = csr[i + 1], s2 = csr[i + 2], s3 = csr[i + 3];
    ushort8 v0 = H[(size_t)s0 * 8 + lane];
    ushort8 v1 = H[(size_t)s1 * 8 + lane];
    ushort8 v2 = H[(size_t)s2 * 8 + lane];
    ushort8 v3 = H[(size_t)s3 * 8 + lane];
    #pragma unroll
    for (int c = 0; c < 8; ++c) {
      acc[c] += (bfbits2f(v0[c]) + bfbits2f(v1[c]))
              + (bfbits2f(v2[c]) + bfbits2f(v3[c]));
    }
  }
  for (; i < i1; ++i) {
    int s = csr[i];
    ushort8 vv = H[(size_t)s * 8 + lane];
    #pragma unroll
    for (int c = 0; c < 8; ++c) acc[c] += bfbits2f(vv[c]);
  }
}

// R12 wave-per-node gather core with optional reverse-weight scatter (R16):
// slot = lane>>3 walks edges stride-8; unit = lane&7 reads contiguous 128B rows.
// cvec!=null: unit==0 lane fires atomicAdd(&cvec[s], dd) per edge (hidden under load latency).
__device__ __forceinline__ void gather_wave_partial(const ushort8* __restrict__ H, int d,
                                                    int slot, int unit,
                                                    const int* __restrict__ rowstart,
                                                    const int* __restrict__ len,
                                                    const int* __restrict__ csr,
                                                    float* acc,
                                                    float* __restrict__ cvec, float dd)
{
  #pragma unroll
  for (int c = 0; c < 8; ++c) acc[c] = 0.f;
  if (slot == 0) {
    ushort8 v = H[(size_t)d * 8 + unit];
    #pragma unroll
    for (int c = 0; c < 8; ++c) acc[c] = bfbits2f(v[c]);
  }
  int i0 = rowstart[d];
  int i1 = i0 + len[d];
  int i = i0 + slot;
  for (; i + 8 < i1; i += 16) {
    int sa = csr[i], sb = csr[i + 8];
    if (cvec && unit == 0) {
      atomicAdd(&cvec[sa], dd);
      atomicAdd(&cvec[sb], dd);
    }
    ushort8 va = H[(size_t)sa * 8 + unit];
    ushort8 vb = H[(size_t)sb * 8 + unit];
    #pragma unroll
    for (int c = 0; c < 8; ++c) acc[c] += bfbits2f(va[c]) + bfbits2f(vb[c]);
  }
  if (i < i1) {
    int s = csr[i];
    if (cvec && unit == 0) atomicAdd(&cvec[s], dd);
    ushort8 vv = H[(size_t)s * 8 + unit];
    #pragma unroll
    for (int c = 0; c < 8; ++c) acc[c] += bfbits2f(vv[c]);
  }
}

// ---------------- init (+parallel dtype detect, proven R5-R8) ----------------

__global__ void init_kernel(const unsigned short* __restrict__ x16,
                            int* __restrict__ bucket_cur, int* __restrict__ detcnt,
                            Ctl* ctl, float* __restrict__ cvec, float* __restrict__ partial) {
  __shared__ u32 dsh[256];
  int i = blockIdx.x * 256 + threadIdx.x;
  if (i < BKT) bucket_cur[i] = i * BCAP;
  if (i < K_KEEP) cvec[i] = 0.f;
  if (i < 128 * 128) partial[i] = 0.f;
  if (blockIdx.x == 0) {
    ctl->hist[threadIdx.x] = 0u;
    if (threadIdx.x == 0) {
      ctl->prefix = 0ull; ctl->kremain = K_KEEP; ctl->cnt = 0u;
      ctl->done = 0u; ctl->pad = 0u; ctl->gen = 0u; ctl->done2 = 0u;
    }
  }
  if (blockIdx.x < 64) {
    int base = blockIdx.x * 2048;
    u32 c = 0;
    for (int j = threadIdx.x; j < 2048; j += 256) {
      u32 h = x16[base + j];
      if ((h & 0x7F80u) == 0x7F80u) c++;
    }
    dsh[threadIdx.x] = c;
    __syncthreads();
    for (int s = 128; s > 0; s >>= 1) {
      if (threadIdx.x < s) dsh[threadIdx.x] += dsh[threadIdx.x + s];
      __syncthreads();
    }
    if (threadIdx.x == 0) detcnt[blockIdx.x] = (int)dsh[0];
  }
}

// ------- CSR1 bucket scatter (int4 edge loads, R13) + fused dtype/norm -------

__global__ void bucket_scatter_kernel(const int* __restrict__ src, const int* __restrict__ dst,
                                      int* __restrict__ bucket_cur, u32* __restrict__ bucketbuf,
                                      const int* __restrict__ detcnt, const void* __restrict__ pw,
                                      Ctl* ctl)
{
  __shared__ u32 hist[BKT];
  __shared__ u32 base[BKT];
  __shared__ int f32sh;
  __shared__ float ns[128];
  const int tid = threadIdx.x;
  const int e0 = blockIdx.x * 2048;

  // dtype detect from detcnt (written by init, prior dispatch)
  if (tid < 64) {
    int dc = detcnt[tid];
    for (int off = 32; off; off >>= 1) dc += __shfl_down(dc, off);
    if (tid == 0) f32sh = (dc >= 16) ? 1 : 0;
  }
  for (int t = tid; t < BKT; t += 256) hist[t] = 0;
  __syncthreads();
  const bool f32in = f32sh != 0;

  // 8 contiguous edges/thread via int4 loads (fast path when block fully in range)
  int dreg[8], sreg[8];
  const int eb = e0 + tid * 8;
  if (e0 + 2048 <= N_EDGES) {
    const int4* d4 = (const int4*)(dst + eb);
    const int4* s4 = (const int4*)(src + eb);
    int4 da = d4[0], db = d4[1];
    int4 sa = s4[0], sb = s4[1];
    dreg[0] = da.x; dreg[1] = da.y; dreg[2] = da.z; dreg[3] = da.w;
    dreg[4] = db.x; dreg[5] = db.y; dreg[6] = db.z; dreg[7] = db.w;
    sreg[0] = sa.x; sreg[1] = sa.y; sreg[2] = sa.z; sreg[3] = sa.w;
    sreg[4] = sb.x; sreg[5] = sb.y; sreg[6] = sb.z; sreg[7] = sb.w;
  } else {
    #pragma unroll
    for (int j = 0; j < 8; ++j) {
      int e = eb + j;
      if (e < N_EDGES) { dreg[j] = dst[e]; sreg[j] = src[e]; }
      else             { dreg[j] = -1;     sreg[j] = 0;      }
    }
  }
  #pragma unroll
  for (int j = 0; j < 8; ++j)
    if (dreg[j] >= 0) atomicAdd(&hist[dreg[j] >> 8], 1u);
  __syncthreads();
  for (int t = tid; t < BKT; t += 256) {
    u32 c = hist[t];
    base[t] = c ? (u32)atomicAdd(&bucket_cur[t], (int)c) : 0u;
    hist[t] = 0;
  }
  __syncthreads();
  #pragma unroll
  for (int j = 0; j < 8; ++j) {
    if (dreg[j] >= 0) {
      int d = dreg[j];
      int b = d >> 8;
      u32 pos = base[b] + atomicAdd(&hist[b], 1u);
      bucketbuf[pos] = ((u32)sreg[j] << 8) | (u32)(d & 255);
    }
  }
  // fused norm: block 0 computes inv_norm + publishes isfp32
  if (blockIdx.x == 0) {
    if (tid < 128) { float v = loadF(pw, tid, f32in); ns[tid] = v * v; }
    __syncthreads();
    for (int s = 64; s > 0; s >>= 1) {
      if (tid < s) ns[tid] += ns[tid + s];
      __syncthreads();
    }
    if (tid == 0) {
      ctl->inv_norm = 1.0f / sqrtf(ns[0]);
      ctl->isfp32 = f32in ? 1u : 0u;
    }
  }
}

// ------- CSR1 from buckets (inline bucket scan) + fused x -> xbf = dis1*x (bf16) -------

__global__ void csr_from_buckets_kernel(const u32* __restrict__ bucketbuf, const int* __restrict__ bucket_cur,
                                        int* __restrict__ rowstart, float* __restrict__ dis,
                                        int* __restrict__ csr,
                                        const void* __restrict__ x, ushort8* __restrict__ xbf,
                                        const Ctl* __restrict__ ctl)
{
  __shared__ u32 cnt[256];
  __shared__ u32 loc[256];
  __shared__ u32 cur[256];
  __shared__ float disS[256];
  const int b = blockIdx.x;
  const int tid = threadIdx.x;

  // inline scan of all bucket sizes -> off0 for this bucket
  int v = (tid < BKT) ? (bucket_cur[tid] - tid * BCAP) : 0;
  loc[tid] = (u32)v;
  __syncthreads();
  for (int off = 1; off < 256; off <<= 1) {
    u32 t = (tid >= off) ? loc[tid - off] : 0;
    __syncthreads();
    loc[tid] += t;
    __syncthreads();
  }
  const int bc = bucket_cur[b] - b * BCAP;
  const int off0 = (int)loc[b] - bc;
  if (b == BKT - 1 && tid == 0) rowstart[N_NODES] = (int)loc[BKT - 1];
  __syncthreads();

  const u32* buf = bucketbuf + (size_t)b * BCAP;
  cnt[tid] = 0;
  __syncthreads();
  for (int i = tid; i < bc; i += 256) atomicAdd(&cnt[buf[i] & 255u], 1u);
  __syncthreads();
  u32 c = cnt[tid];
  loc[tid] = c;
  __syncthreads();
  for (int off = 1; off < 256; off <<= 1) {
    u32 t = (tid >= off) ? loc[tid - off] : 0;
    __syncthreads();
    loc[tid] += t;
    __syncthreads();
  }
  int node = b * 256 + tid;
  u32 excl = loc[tid] - c;
  float ddv = rsqrtf(1.0f + (float)c);
  disS[tid] = ddv;
  if (node < N_NODES) {
    rowstart[node] = off0 + (int)excl;
    dis[node] = ddv;
  }
  cur[tid] = off0 + excl;
  __syncthreads();
  for (int i = tid; i < bc; i += 256) {
    u32 p = buf[i];
    u32 pos = atomicAdd(&cur[p & 255u], 1u);
    csr[pos] = (int)(p >> 8);
  }
  // fused prescaled conversion: xbf[node] = bf16(dis1[node] * x[node]), 64 ch
  {
    const bool f32in = ctl->isfp32 != 0;
    if (f32in) {
      const float* xf = (const float*)x;
      for (int u = tid; u < 2048; u += 256) {
        int r = u >> 3, lane = u & 7;
        int d = b * 256 + r;
        if (d < N_NODES) {
          float sc = disS[r];
          ushort8 o;
          #pragma unroll
          for (int c2 = 0; c2 < 8; ++c2)
            o[c2] = (u16)f2bf_bits(xf[(size_t)d * 64 + lane * 8 + c2] * sc);
          xbf[(size_t)d * 8 + lane] = o;
        }
      }
    } else {
      const ushort8* xi = (const ushort8*)x;
      for (int u = tid; u < 2048; u += 256) {
        int r = u >> 3, lane = u & 7;
        int d = b * 256 + r;
        if (d < N_NODES) {
          float sc = disS[r];
          ushort8 vv = xi[(size_t)d * 8 + lane];
          ushort8 o;
          #pragma unroll
          for (int c2 = 0; c2 < 8; ++c2)
            o[c2] = (u16)f2bf_bits(bfbits2f(vv[c2]) * sc);
          xbf[(size_t)d * 8 + lane] = o;
        }
      }
    }
  }
}

// ------- conv2 gather (R12 wave-per-node) + R16 fused cvec reverse-weight scatter -------

__global__ void gather_h2_kernel(const bf16* __restrict__ P, const int* __restrict__ rowstart,
                                 const int* __restrict__ len, const int* __restrict__ csr,
                                 const float* __restrict__ dis,
                                 const void* __restrict__ b, const Ctl* __restrict__ ctl,
                                 bf16* __restrict__ P2, float* __restrict__ cvec, int M)
{
  const bool f32 = ctl->isfp32 != 0;
  const int tid = threadIdx.x;
  const int d = blockIdx.x * 4 + (tid >> 6);   // one wave per node; grid = M/4 exactly
  const int lane = tid & 63;
  const int slot = lane >> 3, unit = lane & 7;
  const ushort8* H = (const ushort8*)P;
  const float dd = dis[d];
  float acc[8];
  gather_wave_partial(H, d, slot, unit, rowstart, len, csr, acc, cvec, dd);
  // butterfly reduce across slots (same unit): xor 8,16,32
  #pragma unroll
  for (int m = 8; m < 64; m <<= 1)
    #pragma unroll
    for (int c = 0; c < 8; ++c) acc[c] += __shfl_xor(acc[c], m);
  if (slot == 0) {
    ushort8 outv;
    #pragma unroll
    for (int c = 0; c < 8; ++c) {
      float h = acc[c] * dd + loadF(b, 8 * unit + c, f32);
      outv[c] = (u16)f2bf_bits(fmaxf(h, 0.f) * dd);
    }
    ((ushort8*)P2)[(size_t)d * 8 + unit] = outv;
  }
}

// ---------------- MFMA GEMMs (16x16x32 bf16, fp32 acc) ----------------

// conv1 FUSED (R21: 512 threads, 1 gather unit/thread): gather(xbf, graph1) -> LDS,
// then Y = G @ W1 + b1 (+score/keys) on waves 0-3.
__global__ void gemm_in_kernel(const ushort8* __restrict__ xbf,
                               const int* __restrict__ rowstart, const int* __restrict__ csr,
                               const float* __restrict__ dis,
                               const void* __restrict__ W, const void* __restrict__ b,
                               const void* __restrict__ pw,
                               bf16* __restrict__ Y, const Ctl* __restrict__ ctl,
                               float* __restrict__ score, u64* __restrict__ keys)
{
  __shared__ short Xs[64 * 72];
  __shared__ short Wt[128 * 72];
  __shared__ float bs[128];
  __shared__ float ps[128];
  const bool f32 = ctl->isfp32 != 0;
  const int tid = threadIdx.x;
  const int row0 = blockIdx.x * 64;

  if (!f32) {
    const short8* W8 = (const short8*)W;
    for (int i = tid; i < 1024; i += 512) {       // 64x128 shorts = 1024 short8
      int k = i >> 4, nb = i & 15;
      short8 v = W8[i];
      #pragma unroll
      for (int j = 0; j < 8; ++j) Wt[(nb * 8 + j) * 72 + k] = v[j];
    }
  } else {
    for (int i = tid; i < 64 * 128; i += 512) {
      int k = i >> 7, n = i & 127;
      Wt[n * 72 + k] = f2bf_bits(((const float*)W)[i]);
    }
  }
  // fused gather: 64 rows x 8 lane-units = 512 units, exactly 1 per thread
  {
    int r = tid >> 3, lane = tid & 7;
    int d = row0 + r;
    float acc[8];
    short8 outv;
    if (d < N_NODES) {
      gather_row8_pre(xbf, d, lane, rowstart, nullptr, csr, acc);
      float dd = dis[d];
      #pragma unroll
      for (int c = 0; c < 8; ++c) outv[c] = f2bf_bits(acc[c] * dd);
    } else {
      #pragma unroll
      for (int c = 0; c < 8; ++c) outv[c] = 0;
    }
    *(short8*)&Xs[r * 72 + lane * 8] = outv;
  }
  if (tid < 128) { bs[tid] = loadF(b, tid, f32); ps[tid] = loadF(pw, tid, f32); }
  __syncthreads();

  if (tid < 256) {
    const int lane = tid & 63;
    const int w = tid >> 6;
    const int l16 = lane & 15;
    const int quad = lane >> 4;
    f32x4 acc[8];
    #pragma unroll
    for (int ct = 0; ct < 8; ++ct) acc[ct] = (f32x4){0.f, 0.f, 0.f, 0.f};
    const int arow = w * 16 + l16;
    #pragma unroll
    for (int kc = 0; kc < 2; ++kc) {
      short8 a = *(short8*)&Xs[arow * 72 + kc * 32 + quad * 8];
      #pragma unroll
      for (int ct = 0; ct < 8; ++ct) {
        short8 bb = *(short8*)&Wt[(ct * 16 + l16) * 72 + kc * 32 + quad * 8];
        acc[ct] = __builtin_amdgcn_mfma_f32_16x16x32_bf16(a, bb, acc[ct], 0, 0, 0);
      }
    }
    float inv_norm = ctl->inv_norm;
    #pragma unroll
    for (int r = 0; r < 4; ++r) {
      int gr = row0 + w * 16 + quad * 4 + r;
      float p = 0.f;
      #pragma unroll
      for (int ct = 0; ct < 8; ++ct) {
        int col = ct * 16 + l16;
        float h = acc[ct][r] + bs[col];
        if (gr < N_NODES) Y[(size_t)gr * 128 + col] = __float2bfloat16(h);
        p += fmaxf(h, 0.f) * ps[col];
      }
      p += __shfl_down(p, 8, 16);
      p += __shfl_down(p, 4, 16);
      p += __shfl_down(p, 2, 16);
      p += __shfl_down(p, 1, 16);
      if (l16 == 0 && gr < N_NODES) {
        float sc = tanhf(p * inv_norm);
        score[gr] = sc;
        u32 u = __float_as_uint(sc);
        u = (u & 0x80000000u) ? ~u : (u | 0x80000000u);
        keys[gr] = (((u64)u) << 16) | (u64)(0xFFFFu - (u32)gr);
      }
    }
  }
}

// Y[M,64] = (relu?)X[M,128] @ W[128,64]; M multiple of 64
// kept!=null: X row = kept[row], apply relu*score[kept[row]] (fused TopK hp)
// prescale!=null: Y row *= prescale[row] (dis2, for gather-consumed outputs)
__global__ void gemm_128_64_kernel(const bf16* __restrict__ X, const void* __restrict__ W,
                                   bf16* __restrict__ Y, const Ctl* __restrict__ ctl,
                                   int M, int relu_x,
                                   const int* __restrict__ kept, const float* __restrict__ score,
                                   const float* __restrict__ prescale)
{
  __shared__ short Xs[64 * 136];
  __shared__ short Wt[64 * 136];
  __shared__ int keptS[64];
  __shared__ float scS[64];
  const bool f32 = ctl->isfp32 != 0;
  const int tid = threadIdx.x;
  const int row0 = blockIdx.x * 64;

  if (kept) {
    for (int i = tid; i < 64; i += 256) {
      int o = kept[row0 + i];
      keptS[i] = o;
      scS[i] = score[o];
    }
  }
  __syncthreads();

  if (!f32) {
    const short8* W8 = (const short8*)W;
    for (int i = tid; i < 1024; i += 256) {       // 128x64 shorts = 1024 short8
      int k = i >> 3, nb = i & 7;
      short8 v = W8[i];
      #pragma unroll
      for (int j = 0; j < 8; ++j) Wt[(nb * 8 + j) * 136 + k] = v[j];
    }
  } else {
    for (int i = tid; i < 128 * 64; i += 256) {
      int k = i >> 6, n = i & 63;
      Wt[n * 136 + k] = f2bf_bits(((const float*)W)[i]);
    }
  }
  const u32* X2 = (const u32*)X;
  for (int p = tid; p < 64 * 64; p += 256) {
    int r = p >> 6, kp = p & 63;
    int srow = kept ? keptS[r] : (row0 + r);
    u32 v = X2[(size_t)srow * 64 + kp];
    if (relu_x) {
      if (v & 0x8000u) v &= 0xFFFF0000u;
      if (v & 0x80000000u) v &= 0x0000FFFFu;
    }
    if (kept) {
      bf16x2 h = *(bf16x2*)&v;
      float s = scS[r];
      bf16x2 o;
      o.x = __float2bfloat16(fmaxf(bf2f(h.x), 0.f) * s);
      o.y = __float2bfloat16(fmaxf(bf2f(h.y), 0.f) * s);
      v = *(u32*)&o;
    }
    *(u32*)&Xs[r * 136 + 2 * kp] = v;
  }
  __syncthreads();

  const int lane = tid & 63;
  const int w = tid >> 6;
  const int l16 = lane & 15;
  const int quad = lane >> 4;
  f32x4 acc[4];
  #pragma unroll
  for (int ct = 0; ct < 4; ++ct) acc[ct] = (f32x4){0.f, 0.f, 0.f, 0.f};
  const int arow = w * 16 + l16;
  #pragma unroll
  for (int kc = 0; kc < 4; ++kc) {
    short8 a = *(short8*)&Xs[arow * 136 + kc * 32 + quad * 8];
    #pragma unroll
    for (int ct = 0; ct < 4; ++ct) {
      short8 bb = *(short8*)&Wt[(ct * 16 + l16) * 136 + kc * 32 + quad * 8];
      acc[ct] = __builtin_amdgcn_mfma_f32_16x16x32_bf16(a, bb, acc[ct], 0, 0, 0);
    }
  }
  #pragma unroll
  for (int ct = 0; ct < 4; ++ct)
    #pragma unroll
    for (int r = 0; r < 4; ++r) {
      int gr = row0 + w * 16 + quad * 4 + r;
      float val = acc[ct][r];
      if (prescale) val *= prescale[gr];
      Y[(size_t)gr * 64 + ct * 16 + l16] = __float2bfloat16(val);
    }
}

// conv3 FUSED (R19 + R21 512 threads): gather(P2, graph2) -> LDS -> h3 = G @ W3 + b3,
// then weighted-sum epilogue into partial[ch][bid&127] via per-channel global atomicAdd.
__global__ void gemm_64_128_kernel(const bf16* __restrict__ P2,
                                   const int* __restrict__ rowstart, const int* __restrict__ len,
                                   const int* __restrict__ csr, const float* __restrict__ dis,
                                   const void* __restrict__ W, const void* __restrict__ b,
                                   const float* __restrict__ cvec,
                                   float* __restrict__ partial,
                                   const Ctl* __restrict__ ctl, int M)
{
  __shared__ short Xs[64 * 72];
  __shared__ short Wt[128 * 72];
  __shared__ float bs[128];
  __shared__ float wgtS[64];
  __shared__ float cs[128];
  const bool f32 = ctl->isfp32 != 0;
  const int tid = threadIdx.x;
  const int row0 = blockIdx.x * 64;

  if (tid < 128) cs[tid] = 0.f;
  if (tid >= 128 && tid < 192) {
    int gr = row0 + (tid - 128);
    wgtS[tid - 128] = dis[gr] * cvec[gr];
  }
  if (!f32) {
    const short8* W8 = (const short8*)W;
    for (int i = tid; i < 1024; i += 512) {       // 64x128 shorts = 1024 short8
      int k = i >> 4, nb = i & 15;
      short8 v = W8[i];
      #pragma unroll
      for (int j = 0; j < 8; ++j) Wt[(nb * 8 + j) * 72 + k] = v[j];
    }
  } else {
    for (int i = tid; i < 64 * 128; i += 512) {
      int k = i >> 7, n = i & 127;
      Wt[n * 72 + k] = f2bf_bits(((const float*)W)[i]);
    }
  }
  // fused gather (relu baked into P2 at conv2 write): 512 units, 1 per thread
  {
    const ushort8* H = (const ushort8*)P2;
    int r = tid >> 3, lane = tid & 7;
    int d = row0 + r;             // M multiple of 64 -> always < M
    float acc[8];
    gather_row8_pre(H, d, lane, rowstart, len, csr, acc);
    float dd = dis[d];
    short8 outv;
    #pragma unroll
    for (int c = 0; c < 8; ++c) outv[c] = f2bf_bits(acc[c] * dd);
    *(short8*)&Xs[r * 72 + lane * 8] = outv;
  }
  if (tid >= 192 && tid < 320) bs[tid - 192] = loadF(b, tid - 192, f32);
  __syncthreads();

  if (tid < 256) {
    const int lane = tid & 63;
    const int w = tid >> 6;
    const int l16 = lane & 15;
    const int quad = lane >> 4;
    f32x4 acc[8];
    #pragma unroll
    for (int ct = 0; ct < 8; ++ct) acc[ct] = (f32x4){0.f, 0.f, 0.f, 0.f};
    const int arow = w * 16 + l16;
    #pragma unroll
    for (int kc = 0; kc < 2; ++kc) {
      short8 a = *(short8*)&Xs[arow * 72 + kc * 32 + quad * 8];
      #pragma unroll
      for (int ct = 0; ct < 8; ++ct) {
        short8 bb = *(short8*)&Wt[(ct * 16 + l16) * 72 + kc * 32 + quad * 8];
        acc[ct] = __builtin_amdgcn_mfma_f32_16x16x32_bf16(a, bb, acc[ct], 0, 0, 0);
      }
    }
    // weighted-sum epilogue: per thread 8 cols x 4 rows; row-sum then one LDS atomic/col
    #pragma unroll
    for (int ct = 0; ct < 8; ++ct) {
      int col = ct * 16 + l16;
      float s = 0.f;
      #pragma unroll
      for (int r = 0; r < 4; ++r) {
        int lr = w * 16 + quad * 4 + r;
        float h = acc[ct][r] + bs[col];
        float hb = bfbits2f((u16)f2bf_bits(h));   // keep R16 numerics (bf16 round)
        s += fmaxf(hb, 0.f) * wgtS[lr];
      }
      atomicAdd(&cs[col], s);
    }
  }
  __syncthreads();
  if (tid < 128)
    atomicAdd(&partial[(size_t)tid * 128 + (blockIdx.x & 127)], cs[tid]);
}

// R15-proven final reduce (nblk=128) + matvec (512 threads, LDS trees)
__global__ void final_out_kernel(const float* __restrict__ partial, const void* __restrict__ W4,
                                 const void* __restrict__ b4, const Ctl* __restrict__ ctl,
                                 void* __restrict__ out)
{
  __shared__ float red[512];
  __shared__ float S[128];
  const int tid = threadIdx.x;
  // stage 1: sum partials; 4 threads/channel, 32 entries each (nblk = 128)
  {
    const int ch = tid >> 2, chunk = tid & 3;
    float s = 0.f;
    const float* p = partial + (size_t)ch * 128 + chunk * 32;
    for (int j = 0; j < 32; j += 4)
      s += (p[j] + p[j + 1]) + (p[j + 2] + p[j + 3]);
    red[tid] = s;
  }
  __syncthreads();
  if (tid < 128) S[tid] = (red[4 * tid] + red[4 * tid + 1]) + (red[4 * tid + 2] + red[4 * tid + 3]);
  __syncthreads();
  // stage 2: matvec out[c] = sum_k S[k]*W4[k][c]; 8 threads/output, 16 k each
  {
    const bool f32 = ctl->isfp32 != 0;
    const int c = tid >> 3, chunk = tid & 7;
    float o = 0.f;
    #pragma unroll
    for (int j = 0; j < 16; ++j) {
      int k = chunk * 16 + j;
      o += S[k] * loadF(W4, (size_t)k * 64 + c, f32);
    }
    red[tid] = o;
    __syncthreads();
    if (tid < 64) {
      float acc = 0.f;
      #pragma unroll
      for (int j = 0; j < 8; ++j) acc += red[tid * 8 + j];
      float val = acc / (float)K_KEEP + loadF(b4, tid, f32);
      if (f32) ((float*)out)[tid] = val;
      else     ((bf16*)out)[tid] = __float2bfloat16(val);
    }
  }
}

// ------- TopK select: 8-bit x 6 radix hist+pick (R12-proven); fused mark on pass==gen -------

__device__ __forceinline__ void mark_slice(const u64* __restrict__ keys, Ctl* ctl,
                                           int* __restrict__ new_idx, int* __restrict__ kept,
                                           int i)
{
  if (i >= N_NODES) return;
  if (keys[i] >= ctl->prefix) {
    int pos = (int)atomicAdd(&ctl->cnt, 1u);
    new_idx[i] = pos;
    kept[pos] = i;
  } else {
    new_idx[i] = -1;
  }
}

__global__ void histpick_kernel(const u64* __restrict__ keys, Ctl* ctl, int shift, int pass,
                                int nblocks, int* __restrict__ new_idx, int* __restrict__ kept) {
  __shared__ u32 lh[256];
  __shared__ u32 sfx[256];
  __shared__ int lastflag;
  __shared__ int selsh;
  const int tid = threadIdx.x;
  const u32 g = ctl->gen;
  if (g != 0u) {
    // resolved at pass (g-1); pass q==g performs the fused marking, later passes no-op
    if ((u32)pass == g)
      mark_slice(keys, ctl, new_idx, kept, blockIdx.x * 256 + tid);
    return;
  }
  lh[tid] = 0;
  __syncthreads();
  u64 prefix = ctl->prefix;
  int i = blockIdx.x * 256 + tid;
  if (i < N_NODES) {
    u64 key = keys[i];
    if ((key >> (shift + 8)) == (prefix >> (shift + 8)))
      atomicAdd(&lh[(u32)((key >> shift) & 0xFF)], 1u);
  }
  __syncthreads();
  u32 c = lh[tid];
  if (c) atomicAdd(&ctl->hist[tid], c);
  __syncthreads();
  if (tid == 0) {
    __threadfence();
    u32 old = atomicAdd(&ctl->done, 1u);
    lastflag = (old == (u32)(nblocks - 1));
  }
  __syncthreads();
  if (!lastflag) return;
  // last block: parallel pick via suffix scan
  u32 cc = atomicExch(&ctl->hist[tid], 0u);   // coherent read + zero for next pass
  sfx[tid] = cc;
  __syncthreads();
  for (int off = 1; off < 256; off <<= 1) {
    u32 t = (tid + off < 256) ? sfx[tid + off] : 0u;
    __syncthreads();
    sfx[tid] += t;
    __syncthreads();
  }
  u32 kr = ctl->kremain;
  u32 above = (tid < 255) ? sfx[tid + 1] : 0u;
  if (sfx[tid] >= kr && above < kr) selsh = tid;   // unique (sfx non-increasing)
  __syncthreads();
  if (tid == 0) {
    int sel = selsh;
    u32 ab = (sel < 255) ? sfx[sel + 1] : 0u;
    u32 newkr = kr - ab;
    u32 bucketcnt = sfx[sel] - ab;
    ctl->kremain = newkr;
    ctl->prefix = prefix | (((u64)(u32)sel) << shift);
    if (newkr == bucketcnt) ctl->gen = (u32)(pass + 1);  // resolved; pass+1 marks
    ctl->done = 0u;
  }
}

// fallback mark: only runs if not already marked by a fused pass (gen==0 or gen==6)
__global__ void mark_kernel(const u64* __restrict__ keys, Ctl* ctl,
                            int* __restrict__ new_idx, int* __restrict__ kept)
{
  u32 g = ctl->gen;
  if (g >= 1u && g <= 5u) return;   // marked by histpick pass q==g
  mark_slice(keys, ctl, new_idx, kept, blockIdx.x * 256 + (int)threadIdx.x);
}

// ------- CSR2 (R20): SINGLE-PASS strided fill — one thread/row, base = kp*RSTRIDE -------

__global__ void csr2_build_kernel(const int* __restrict__ kept, const int* __restrict__ rowstart1,
                                  const int* __restrict__ csr1, const int* __restrict__ new_idx,
                                  int* __restrict__ rowstart2, int* __restrict__ len2,
                                  float* __restrict__ dis2, int* __restrict__ csr2,
                                  float* __restrict__ cvec)
{
  int kp = blockIdx.x * 256 + threadIdx.x;
  if (kp >= K_KEEP) return;
  int o = kept[kp];
  int i0 = rowstart1[o], i1 = rowstart1[o + 1];
  const int base = kp * RSTRIDE;
  int w = base;
  int i = i0;
  for (; i + 4 <= i1; i += 4) {              // ILP-4 single-pass fill
    int n0 = new_idx[csr1[i]];
    int n1 = new_idx[csr1[i + 1]];
    int n2 = new_idx[csr1[i + 2]];
    int n3 = new_idx[csr1[i + 3]];
    if (n0 >= 0) csr2[w++] = n0;
    if (n1 >= 0) csr2[w++] = n1;
    if (n2 >= 0) csr2[w++] = n2;
    if (n3 >= 0) csr2[w++] = n3;
  }
  for (; i < i1; ++i) {
    int ns = new_idx[csr1[i]];
    if (ns >= 0) csr2[w++] = ns;
  }
  int c = w - base;
  rowstart2[kp] = base;
  len2[kp] = c;
  float ddv = rsqrtf(1.0f + (float)c);
  dis2[kp] = ddv;
  cvec[kp] = ddv;                            // self term (plain store; unique index)
}

// ---------------- launch ----------------

extern "C" void kernel_launch(void* const* d_in, const int* in_sizes, int n_in,
                              void* d_out, int out_size, void* d_ws, size_t ws_size,
                              hipStream_t stream)
{
  const void* x  = d_in[0];
  const int*  ei = (const int*)d_in[1];
  const void* W1 = d_in[3];
  const void* b1 = d_in[4];
  const void* pw = d_in[5];
  const void* W2 = d_in[6];
  const void* b2 = d_in[7];
  const void* W3 = d_in[8];
  const void* b3 = d_in[9];
  const void* W4 = d_in[10];
  const void* b4 = d_in[11];

  const int* src = ei;
  const int* dst = ei + N_EDGES;

  float* F = (float*)d_ws;
  bf16*  A16       = (bf16*)F;               // N x 128 bf16 (conv2 output)
  bf16*  B16       = (bf16*)(F + 3200000);   // N x 128 bf16
  bf16*  C16       = (bf16*)(F + 6400000);   // K x 128 bf16
  u32*   xbf       = (u32*)(F + 9000000);    // N x 32 u32 (xbf = dis1*x as bf16 pairs)
  float* dis1      = F + 10600000;           // 50000
  float* dis2      = F + 10650000;           // 40000
  float* score     = F + 10690000;           // 50000
  u64*   keys      = (u64*)(F + 10740000);   // 50000 u64
  int*   new_idx   = (int*)(F + 10840000);   // 50000
  int*   kept      = (int*)(F + 10890000);   // 40000
  int*   len2      = (int*)(F + 10930000);   // 40000
  int*   rowstart1 = (int*)(F + 10970000);   // 50001
  int*   rowstart2 = (int*)(F + 11020004);   // 40000
  int*   csr1      = (int*)(F + 11060008);   // 800000
  Ctl*   ctl       = (Ctl*)(F + 12660008);   // ~1.1 KB
  int*   detcnt    = (int*)(F + 12660856);   // 64
  int*   bucket_cur= (int*)(F + 12660920);   // 196
  float* cvec      = F + 12665216;           // 40000 (reverse weights)
  u32*   bucketbuf = (u32*)(F + 12726908);   // 196*6144
  float* partial   = F + 13931132;           // 128 x 128
  int*   csr2      = (int*)(F + 14200000);   // 40000 x RSTRIDE strided slots (5.12M ints)

  const int NB1 = (N_NODES + 255) / 256;     // 196
  const int EB2 = (N_EDGES + 2047) / 2048;   // 391
  const int GB1 = (N_NODES + 63) / 64;       // 782
  const int WBK = K_KEEP / 4;                // 10000 (wave-per-node)
  const int CB2 = (K_KEEP + 255) / 256;      // 157
  const int GB3 = K_KEEP / 64;               // 625 (conv3 blocks)

  init_kernel<<<NB1, 256, 0, stream>>>((const unsigned short*)x, bucket_cur, detcnt, ctl,
                                       cvec, partial);

  // CSR graph 1 via bucket sort (+fused dtype/norm)
  bucket_scatter_kernel<<<EB2, 256, 0, stream>>>(src, dst, bucket_cur, bucketbuf,
                                                 detcnt, pw, ctl);
  // CSR1 build + fused xbf = dis1*x prescale-convert
  csr_from_buckets_kernel<<<BKT, 256, 0, stream>>>(bucketbuf, bucket_cur, rowstart1, dis1, csr1,
                                                   x, (ushort8*)xbf, ctl);

  // conv1 FUSED (512 threads): gather(xbf) -> LDS -> h1 = G @ W1 + b1 (+score/keys)
  gemm_in_kernel<<<GB1, 512, 0, stream>>>((const ushort8*)xbf, rowstart1, csr1, dis1,
                                          W1, b1, pw, B16, ctl, score, keys);

  // top-K select (6 x 8-bit radix; early-exit; first post-resolution pass marks)
  for (int p = 0; p < 6; ++p)
    histpick_kernel<<<NB1, 256, 0, stream>>>(keys, ctl, 40 - 8 * p, p, NB1, new_idx, kept);
  mark_kernel<<<NB1, 256, 0, stream>>>(keys, ctl, new_idx, kept);

  // CSR graph 2: SINGLE-PASS strided fill (cvec self-term; reverse weights in gather_h2)
  csr2_build_kernel<<<CB2, 256, 0, stream>>>(kept, rowstart1, csr1, new_idx,
                                             rowstart2, len2, dis2, csr2, cvec);

  // conv2: A = dis2*(hp @ W2) ; P2 = dis2*relu(dd*sum(A) + b2)  [+fused cvec scatter]
  gemm_128_64_kernel<<<K_KEEP / 64, 256, 0, stream>>>(B16, W2, A16, ctl, K_KEEP, 0, kept, score, dis2);
  gather_h2_kernel<<<WBK, 256, 0, stream>>>(A16, rowstart2, len2, csr2, dis2, b2, ctl, C16, cvec, K_KEEP);

  // conv3 FUSED (512 threads) + weighted-sum epilogue (h3 never materialized)
  gemm_64_128_kernel<<<GB3, 512, 0, stream>>>(C16, rowstart2, len2, csr2, dis2,
                                              W3, b3, cvec, partial, ctl, K_KEEP);

  // out = S@W4/K + b4 (proven nblk=128 parallel reduce)
  final_out_kernel<<<1, 512, 0, stream>>>(partial, W4, b4, ctl, d_out);
}